// Round 14
// baseline (7067.643 us; speedup 1.0000x reference)
//
#include <hip/hip_runtime.h>
#include <math.h>
#include <float.h>

#define N_TOT 8192
#define KNB 16
#define ALPHA 0.5f
#define PROWS 2048           // d2 panel rows
#define NCH 8                // split-K chunks for A = H^T H
#define KS 8                 // split-K slabs for adj @ P

typedef short bf16x8 __attribute__((ext_vector_type(8)));
typedef float f32x4 __attribute__((ext_vector_type(4)));

__device__ inline unsigned short f2bf(float f) {
    unsigned u = __float_as_uint(f);
    u += 0x7fffu + ((u >> 16) & 1u);
    return (unsigned short)(u >> 16);
}
__device__ inline float bf2f(unsigned short h) {
    return __uint_as_float(((unsigned)h) << 16);
}

// ---------------------------------------------------------------------------
// Apart[ch] = H[ch-slice]^T H[ch-slice]  (f64 partials, f32 32-row inner)
__global__ __launch_bounds__(256)
void k_ata2(const float* __restrict__ H, double* __restrict__ Apart, int d) {
    __shared__ float Ha[32][33], Hb[32][33];
    int tid = threadIdx.x, tx = tid&15, ty = tid>>4;
    int a0 = blockIdx.y*32, b0 = blockIdx.x*32;
    int n0b = blockIdx.z*(N_TOT/NCH);
    int lrow = tid>>3, lseg = tid&7;
    double acc[2][2];
    acc[0][0]=acc[0][1]=acc[1][0]=acc[1][1]=0.0;
    for (int n0 = n0b; n0 < n0b + N_TOT/NCH; n0 += 32) {
        float4 va = *(const float4*)&H[(long)(n0+lrow)*d + a0 + lseg*4];
        float4 vb = *(const float4*)&H[(long)(n0+lrow)*d + b0 + lseg*4];
        __syncthreads();
        Ha[lrow][lseg*4+0]=va.x; Ha[lrow][lseg*4+1]=va.y;
        Ha[lrow][lseg*4+2]=va.z; Ha[lrow][lseg*4+3]=va.w;
        Hb[lrow][lseg*4+0]=vb.x; Hb[lrow][lseg*4+1]=vb.y;
        Hb[lrow][lseg*4+2]=vb.z; Hb[lrow][lseg*4+3]=vb.w;
        __syncthreads();
        float f00=0.f,f01=0.f,f10=0.f,f11=0.f;
        #pragma unroll
        for (int nn = 0; nn < 32; ++nn) {
            float a0v = Ha[nn][ty*2], a1v = Ha[nn][ty*2+1];
            float b0v = Hb[nn][tx*2], b1v = Hb[nn][tx*2+1];
            f00 = fmaf(a0v,b0v,f00); f01 = fmaf(a0v,b1v,f01);
            f10 = fmaf(a1v,b0v,f10); f11 = fmaf(a1v,b1v,f11);
        }
        acc[0][0]+= (double)f00; acc[0][1]+= (double)f01;
        acc[1][0]+= (double)f10; acc[1][1]+= (double)f11;
    }
    long base = (long)blockIdx.z*d*d;
    #pragma unroll
    for (int i=0;i<2;++i)
        #pragma unroll
        for (int j=0;j<2;++j)
            Apart[base + (long)(a0+ty*2+i)*d + b0+tx*2+j] = acc[i][j];
}

// A = beta*I + sum_ch Apart[ch]   (deterministic in-order reduce)
__global__ __launch_bounds__(256)
void k_atared(const double* __restrict__ Apart, double* __restrict__ A,
              int d, double beta) {
    long idx = (long)blockIdx.x*256 + threadIdx.x;
    long dd = (long)d*d;
    double s = 0.0;
    for (int ch = 0; ch < NCH; ++ch) s += Apart[ch*dd + idx];
    int r = (int)(idx / d), c = (int)(idx % d);
    A[idx] = s + ((r==c) ? beta : 0.0);
}

// ---------------------------------------------------------------------------
// Single-wave Cholesky of the 64x64 diagonal panel.
__global__ __launch_bounds__(64)
void k_chol_diag(double* __restrict__ A, int d, int p0) {
    __shared__ double Ad[64][65];
    int r = threadIdx.x;
    for (int idx = r; idx < 64*64; idx += 64)
        Ad[idx>>6][idx&63] = A[(long)(p0+(idx>>6))*d + p0+(idx&63)];
    __syncthreads();
    for (int j = 0; j < 64; ++j) {
        double pj = sqrt(Ad[j][j]);
        double lrj = Ad[r][j] / pj;
        __syncthreads();
        if (r > j) Ad[r][j] = lrj;
        else if (r == j) Ad[j][j] = pj;
        __syncthreads();
        if (r > j)
            for (int k = j+1; k <= r; ++k)
                Ad[r][k] -= lrj * Ad[k][j];
        __syncthreads();
    }
    for (int idx = r; idx < 64*64; idx += 64) {
        int i = idx>>6, c = idx&63;
        A[(long)(p0+i)*d + p0+c] = (c <= i) ? Ad[i][c] : 0.0;
    }
}

__global__ __launch_bounds__(256)
void k_trsm(double* __restrict__ A, int d, int p0) {
    __shared__ double Lp[64][65];
    __shared__ double dg[64];
    int tid = threadIdx.x;
    for (int idx = tid; idx < 64*64; idx += 256) {
        int j = idx>>6, k = idx&63;
        double v = A[(long)(p0+j)*d + p0+k];
        Lp[j][k] = (j > k) ? v : 0.0;
        if (j == k) dg[j] = v;
    }
    __syncthreads();
    int r = p0 + 64 + blockIdx.x*256 + tid;
    if (r >= d) return;
    double* Ar = &A[(long)r*d + p0];
    double v[64];
    #pragma unroll
    for (int j = 0; j < 64; ++j) v[j] = Ar[j];
    #pragma unroll
    for (int k = 0; k < 64; ++k) {
        double lr = v[k] / dg[k];
        Ar[k] = lr;
        #pragma unroll
        for (int j = 0; j < 64; ++j) v[j] -= lr * Lp[j][k];
    }
}

__global__ __launch_bounds__(256)
void k_syrk(double* __restrict__ A, int d, int p0) {
    int t0 = p0 + 64;
    int r0 = t0 + blockIdx.y*64, c0 = t0 + blockIdx.x*64;
    __shared__ double Lr[64][33], Lc[64][33];
    int tid = threadIdx.x, tx = tid&15, ty = tid>>4;
    double acc[16];
    #pragma unroll
    for (int i=0;i<16;++i) acc[i]=0.0;
    for (int kc = 0; kc < 64; kc += 32) {
        for (int idx = tid; idx < 64*32; idx += 256) {
            int i = idx>>5, k = idx&31;
            Lr[i][k] = A[(long)(r0+i)*d + p0+kc+k];
            Lc[i][k] = A[(long)(c0+i)*d + p0+kc+k];
        }
        __syncthreads();
        for (int k = 0; k < 32; ++k) {
            double a[4], b[4];
            #pragma unroll
            for (int i=0;i<4;++i){ a[i]=Lr[ty*4+i][k]; b[i]=Lc[tx*4+i][k]; }
            #pragma unroll
            for (int i=0;i<4;++i)
                #pragma unroll
                for (int j=0;j<4;++j) acc[i*4+j] += a[i]*b[j];
        }
        __syncthreads();
    }
    #pragma unroll
    for (int i=0;i<4;++i)
        #pragma unroll
        for (int j=0;j<4;++j)
            A[(long)(r0+ty*4+i)*d + (c0+tx*4+j)] -= acc[i*4+j];
}

// ---------------------------------------------------------------------------
__global__ __launch_bounds__(64)
void k_dinv(const double* __restrict__ A, double* __restrict__ X, int d) {
    __shared__ double Lb[64][65];
    __shared__ double Yb[64][65];
    int b = blockIdx.x, c = threadIdx.x;
    for (int r = 0; r < 64; ++r) Lb[r][c] = A[(long)(b*64+r)*d + b*64+c];
    for (int r = 0; r < 64; ++r) Yb[r][c] = 0.0;
    __syncthreads();
    for (int i = 0; i < 64; ++i) {
        double s = (i==c) ? 1.0 : 0.0;
        for (int k = 0; k < i; ++k) s -= Lb[i][k]*Yb[k][c];
        Yb[i][c] = s / Lb[i][i];
    }
    __syncthreads();
    for (int r = 0; r < 64; ++r) X[(long)(b*64+r)*d + b*64+c] = Yb[r][c];
}

// X_{ij} = -X_{ii} * sum_{k=j}^{i-1} L_{ik} X_{kj},  i = j + lev.
__global__ __launch_bounds__(256)
void k_xoff(const double* __restrict__ A, double* __restrict__ X, int d, int lev) {
    __shared__ double Lb[64][65];
    __shared__ double Xb[64][65];
    __shared__ double Sb[64][65];
    int j = blockIdx.x, i = j + lev;
    int tid = threadIdx.x, tx = tid&15, ty = tid>>4;
    double acc[4][4];
    #pragma unroll
    for (int m=0;m<4;++m)
        #pragma unroll
        for (int n=0;n<4;++n) acc[m][n]=0.0;
    for (int k = j; k < i; ++k) {
        __syncthreads();
        for (int idx = tid; idx < 64*64; idx += 256) {
            int r = idx>>6, cc = idx&63;
            Lb[r][cc] = A[(long)(i*64+r)*d + k*64+cc];
            Xb[r][cc] = X[(long)(k*64+r)*d + j*64+cc];
        }
        __syncthreads();
        for (int kk = 0; kk < 64; ++kk) {
            double a_[4], b_[4];
            #pragma unroll
            for (int m=0;m<4;++m) a_[m] = Lb[ty*4+m][kk];
            #pragma unroll
            for (int n=0;n<4;++n) b_[n] = Xb[kk][tx*4+n];
            #pragma unroll
            for (int m=0;m<4;++m)
                #pragma unroll
                for (int n=0;n<4;++n) acc[m][n] += a_[m]*b_[n];
        }
    }
    __syncthreads();
    #pragma unroll
    for (int m=0;m<4;++m)
        #pragma unroll
        for (int n=0;n<4;++n) Sb[ty*4+m][tx*4+n] = acc[m][n];
    for (int idx = tid; idx < 64*64; idx += 256) {
        int r = idx>>6, cc = idx&63;
        Lb[r][cc] = X[(long)(i*64+r)*d + i*64+cc];   // X_{ii}
    }
    __syncthreads();
    #pragma unroll
    for (int m=0;m<4;++m)
        #pragma unroll
        for (int n=0;n<4;++n) acc[m][n]=0.0;
    for (int kk = 0; kk < 64; ++kk) {
        double a_[4], b_[4];
        #pragma unroll
        for (int m=0;m<4;++m) a_[m] = Lb[ty*4+m][kk];
        #pragma unroll
        for (int n=0;n<4;++n) b_[n] = Sb[kk][tx*4+n];
        #pragma unroll
        for (int m=0;m<4;++m)
            #pragma unroll
            for (int n=0;n<4;++n) acc[m][n] += a_[m]*b_[n];
    }
    #pragma unroll
    for (int m=0;m<4;++m)
        #pragma unroll
        for (int n=0;n<4;++n)
            X[(long)(i*64+ty*4+m)*d + j*64+tx*4+n] = -acc[m][n];
}

// W = X^T with upper-of-X forced to zero.
__global__ __launch_bounds__(256)
void k_wtr(const double* __restrict__ X, double* __restrict__ W, int d, int shift) {
    int idx = blockIdx.x*256 + threadIdx.x;
    int k = idx >> shift, c = idx & (d-1);
    W[idx] = (k <= c) ? X[(long)c*d + k] : 0.0;
}

// Z = H @ W  (f32 in, f64 W, f64 accumulate, f32 out)
__global__ __launch_bounds__(256)
void k_hw(const float* __restrict__ H, const double* __restrict__ W,
          float* __restrict__ Z, int d) {
    __shared__ __align__(16) float Ht[32][68];
    __shared__ double Wt[32][66];
    int tid = threadIdx.x, tx = tid&15, ty = tid>>4;
    int r0 = blockIdx.y*64, c0 = blockIdx.x*64;
    double acc[4][4];
    #pragma unroll
    for (int i=0;i<4;++i)
        #pragma unroll
        for (int j=0;j<4;++j) acc[i][j]=0.0;
    for (int k0 = 0; k0 < d; k0 += 32) {
        {
            int row = tid>>2, koff = (tid&3)*8;
            const float* src = &H[(long)(r0+row)*d + k0+koff];
            float4 v0 = *(const float4*)src, v1 = *(const float4*)(src+4);
            Ht[koff+0][row]=v0.x; Ht[koff+1][row]=v0.y; Ht[koff+2][row]=v0.z; Ht[koff+3][row]=v0.w;
            Ht[koff+4][row]=v1.x; Ht[koff+5][row]=v1.y; Ht[koff+6][row]=v1.z; Ht[koff+7][row]=v1.w;
        }
        {
            int k = tid>>3, coff = (tid&7)*8;
            const double* src = &W[(long)(k0+k)*d + c0+coff];
            #pragma unroll
            for (int q=0;q<8;++q) Wt[k][coff+q] = src[q];
        }
        __syncthreads();
        #pragma unroll
        for (int k = 0; k < 32; ++k) {
            float4 av = *(const float4*)&Ht[k][ty*4];
            double a0=av.x, a1=av.y, a2=av.z, a3=av.w;
            double b[4];
            #pragma unroll
            for (int j=0;j<4;++j) b[j] = Wt[k][tx*4+j];
            #pragma unroll
            for (int j=0;j<4;++j) {
                acc[0][j] += a0*b[j]; acc[1][j] += a1*b[j];
                acc[2][j] += a2*b[j]; acc[3][j] += a3*b[j];
            }
        }
        __syncthreads();
    }
    #pragma unroll
    for (int i=0;i<4;++i)
        #pragma unroll
        for (int j=0;j<4;++j)
            Z[(long)(r0+ty*4+i)*d + c0+tx*4+j] = (float)acc[i][j];
}

__global__ __launch_bounds__(256)
void k_sq(const float* __restrict__ Z, float* __restrict__ sq, int d) {
    int row = blockIdx.x*4 + (threadIdx.x>>6);
    int lane = threadIdx.x&63;
    const float* z = &Z[(long)row*d];
    double s = 0.0;
    for (int c = lane; c < d; c += 64) { float v = z[c]; s += (double)v*v; }
    #pragma unroll
    for (int off=32; off>0; off>>=1) s += __shfl_down(s, off);
    if (lane==0) sq[row] = (float)s;
}

// f32 -> bf16 (round-to-nearest), single output
__global__ __launch_bounds__(256)
void k_bf16(const float* __restrict__ Z, unsigned short* __restrict__ Zh, long n) {
    long i = ((long)blockIdx.x*256 + threadIdx.x)*8;
    if (i >= n) return;
    float4 v0 = *(const float4*)&Z[i], v1 = *(const float4*)&Z[i+4];
    float z[8] = {v0.x,v0.y,v0.z,v0.w,v1.x,v1.y,v1.z,v1.w};
    __align__(16) unsigned short h[8];
    #pragma unroll
    for (int j=0;j<8;++j) h[j] = f2bf(z[j]);
    *(uint4*)&Zh[i] = *(const uint4*)h;
}

// f32 -> bf16 h + l split (linear layout)
__global__ __launch_bounds__(256)
void k_split(const float* __restrict__ in, unsigned short* __restrict__ ho,
             unsigned short* __restrict__ lo, long n) {
    long i = ((long)blockIdx.x*256 + threadIdx.x)*8;
    if (i >= n) return;
    float4 v0 = *(const float4*)&in[i], v1 = *(const float4*)&in[i+4];
    float z[8] = {v0.x,v0.y,v0.z,v0.w,v1.x,v1.y,v1.z,v1.w};
    __align__(16) unsigned short h[8], l[8];
    #pragma unroll
    for (int j=0;j<8;++j) {
        h[j] = f2bf(z[j]);
        l[j] = f2bf(z[j] - bf2f(h[j]));
    }
    *(uint4*)&ho[i] = *(const uint4*)h;
    *(uint4*)&lo[i] = *(const uint4*)l;
}

// ---------------------------------------------------------------------------
// d2 panel GEMM: d2[r - prow0][c] = sq_r + sq_c - 2*(Zh_r . Zh_c), bf16 MFMA.
__global__ __launch_bounds__(256)
void k_gram(const unsigned short* __restrict__ Zh, const float* __restrict__ sq,
            float* __restrict__ d2, int d, int prow0) {
    __shared__ unsigned short At[128*64], Bt[128*64];
    int tid = threadIdx.x, w = tid>>6, lane = tid&63;
    int lr = lane&15, kg = lane>>4;
    int wr = w>>1, wc = w&1;
    int r0 = prow0 + blockIdx.y*128;
    int c0 = blockIdx.x*128;
    f32x4 acc[4][4];
    #pragma unroll
    for (int m=0;m<4;++m)
        #pragma unroll
        for (int n=0;n<4;++n) acc[m][n] = (f32x4){0.f,0.f,0.f,0.f};

    for (int k0 = 0; k0 < d; k0 += 64) {
        __syncthreads();
        #pragma unroll
        for (int ii=0; ii<4; ++ii) {
            int rbase = w*32 + ii*8;
            int grow = rbase + (lane>>3);
            int gg = (lane&7) ^ (grow&7);
            __builtin_amdgcn_global_load_lds((const void*)&Zh[(long)(r0+grow)*d + k0 + gg*8],
                                             (void*)&At[rbase*64], 16, 0, 0);
            __builtin_amdgcn_global_load_lds((const void*)&Zh[(long)(c0+grow)*d + k0 + gg*8],
                                             (void*)&Bt[rbase*64], 16, 0, 0);
        }
        __syncthreads();
        #pragma unroll
        for (int ks=0; ks<2; ++ks) {
            int gsw = ((ks<<2)|kg) ^ (lr&7);
            bf16x8 a_[4];
            #pragma unroll
            for (int m=0;m<4;++m) a_[m] = *(const bf16x8*)&At[(wr*64+m*16+lr)*64 + gsw*8];
            #pragma unroll
            for (int n=0;n<4;++n) {
                bf16x8 b_ = *(const bf16x8*)&Bt[(wc*64+n*16+lr)*64 + gsw*8];
                #pragma unroll
                for (int m=0;m<4;++m)
                    acc[m][n] = __builtin_amdgcn_mfma_f32_16x16x32_bf16(a_[m], b_, acc[m][n], 0,0,0);
            }
        }
    }
    float sr[4][4];
    #pragma unroll
    for (int m=0;m<4;++m)
        #pragma unroll
        for (int q=0;q<4;++q) sr[m][q] = sq[r0 + wr*64 + m*16 + kg*4 + q];
    #pragma unroll
    for (int n=0;n<4;++n) {
        int col = c0 + wc*64 + n*16 + lr;
        float sc = sq[col];
        #pragma unroll
        for (int m=0;m<4;++m) {
            int rloc = (r0 - prow0) + wr*64 + m*16 + kg*4;
            #pragma unroll
            for (int q=0;q<4;++q)
                d2[(long)(rloc+q)*N_TOT + col] = sr[m][q] + sc - 2.f*acc[m][n][q];
        }
    }
}

// Per-row exact top-32: per-wave zero-barrier radix select (shfl-only) over
// 1024 register-resident values, then tiny LDS merge. 512 thr/block.
__global__ __launch_bounds__(512)
void k_sel(const float* __restrict__ d2, int* __restrict__ tI32, int prow0) {
    __shared__ int   wcnt[8];
    __shared__ float cbv[8][96];
    __shared__ int   cbi[8][96];
    __shared__ float fD[32];
    __shared__ int   fI[32];
    int tid = threadIdx.x, w = tid>>6, lane = tid&63;
    int row = blockIdx.x;
    const float* rp = &d2[(long)row*N_TOT];
    unsigned u[16];
    #pragma unroll
    for (int j=0;j<4;++j) {
        float4 q = *(const float4*)&rp[j*2048 + tid*4];
        float z[4] = {q.x, q.y, q.z, q.w};
        #pragma unroll
        for (int e=0;e<4;++e) {
            unsigned b = __float_as_uint(z[e]);
            u[j*4+e] = (b & 0x80000000u) ? ~b : (b | 0x80000000u);
        }
    }
    if (lane == 0) wcnt[w] = 0;
    // wave-local radix select: 32nd-smallest among this wave's 1024 values.
    // Zero barriers: counts via shfl_xor reduce only.
    unsigned p = 0;
    for (int b = 31; b >= 0; --b) {
        unsigned t = p | (1u<<b);
        int c = 0;
        #pragma unroll
        for (int i=0;i<16;++i) c += (u[i] < t) ? 1 : 0;
        #pragma unroll
        for (int off=32; off>0; off>>=1) c += __shfl_xor(c, off);
        if (c < 32) p = t;
    }
    // collect wave-local candidates u <= p  (>=32, all of wave's top-32)
    #pragma unroll
    for (int i=0;i<16;++i) {
        if (u[i] <= p) {
            int pos = atomicAdd(&wcnt[w], 1);
            if (pos < 96) {
                unsigned uu = u[i];
                unsigned bb = (uu & 0x80000000u) ? (uu & 0x7fffffffu) : ~uu;
                cbv[w][pos] = __uint_as_float(bb);
                cbi[w][pos] = (i>>2)*2048 + tid*4 + (i&3);
            }
        }
    }
    __syncthreads();
    if (tid == 0) {
        #pragma unroll
        for (int k=0;k<32;++k){ fD[k]=FLT_MAX; fI[k]=k; }
        for (int ww = 0; ww < 8; ++ww) {
            int m = wcnt[ww]; if (m > 96) m = 96;
            for (int t = 0; t < m; ++t) {
                float dv = cbv[ww][t]; int ci = cbi[ww][t];
                float wd = fD[31]; int wi = fI[31];
                if (dv < wd || (dv == wd && ci < wi)) {
                    int pos = 31;
                    while (pos > 0) {
                        float pd_=fD[pos-1]; int pi_=fI[pos-1];
                        if (dv < pd_ || (dv == pd_ && ci < pi_)) { fD[pos]=pd_; fI[pos]=pi_; --pos; }
                        else break;
                    }
                    fD[pos]=dv; fI[pos]=ci;
                }
            }
        }
        long rg = (long)(prow0 + row);
        #pragma unroll
        for (int k=0;k<32;++k) tI32[rg*32 + k] = fI[k];
    }
}

// Phase 2: exact f32 d2 for the 32 global candidates; exact top-16 + sigma.
// 2-way ILP across candidates.
template<int D>
__global__ __launch_bounds__(256)
void k_refine(const float* __restrict__ Z, const float* __restrict__ sq,
              const int* __restrict__ tI32,
              float* __restrict__ tD, int* __restrict__ tI, double* sig_accum) {
    __shared__ float rD[4][32];
    __shared__ int   rI[4][32];
    __shared__ float bD[4][17];
    __shared__ int   bI[4][17];
    int wv = threadIdx.x>>6, lane = threadIdx.x&63;
    long row = (long)blockIdx.x*4 + wv;
    float zi[D/64];
    #pragma unroll
    for (int t=0;t<D/64;++t) zi[t] = Z[row*D + t*64 + lane];
    float sqi = sq[row];
    for (int c = 0; c < 32; c += 2) {
        int j0 = tI32[row*32 + c], j1 = tI32[row*32 + c + 1];
        float dot0 = 0.f, dot1 = 0.f;
        #pragma unroll
        for (int t=0;t<D/64;++t) {
            dot0 = fmaf(zi[t], Z[(long)j0*D + t*64 + lane], dot0);
            dot1 = fmaf(zi[t], Z[(long)j1*D + t*64 + lane], dot1);
        }
        #pragma unroll
        for (int off=32; off>0; off>>=1) {
            dot0 += __shfl_xor(dot0, off);
            dot1 += __shfl_xor(dot1, off);
        }
        if (lane == 0) {
            rD[wv][c]   = sqi + sq[j0] - 2.f*dot0; rI[wv][c]   = j0;
            rD[wv][c+1] = sqi + sq[j1] - 2.f*dot1; rI[wv][c+1] = j1;
        }
    }
    if (lane == 0) {
        #pragma unroll
        for (int k=0;k<16;++k){ bD[wv][k]=FLT_MAX; bI[wv][k]=0x7fffffff; }
        for (int c = 0; c < 32; ++c) {
            float dv = rD[wv][c]; int ci = rI[wv][c];
            float wd = bD[wv][15]; int wi = bI[wv][15];
            if (dv < wd || (dv == wd && ci < wi)) {
                int pos = 15;
                while (pos > 0) {
                    float pd_ = bD[wv][pos-1]; int pi_ = bI[wv][pos-1];
                    if (dv < pd_ || (dv == pd_ && ci < pi_)) {
                        bD[wv][pos]=pd_; bI[wv][pos]=pi_; --pos;
                    } else break;
                }
                bD[wv][pos]=dv; bI[wv][pos]=ci;
            }
        }
        double ps = 0.0;
        #pragma unroll
        for (int k=0;k<16;++k) {
            float dv = bD[wv][k];
            tD[row*16+k] = dv; tI[row*16+k] = bI[wv][k];
            ps += sqrt((double)fmaxf(dv, 0.f));
        }
        atomicAdd(sig_accum, ps);
    }
}

__global__ void k_sigfin(const double* __restrict__ sig_accum, float* __restrict__ inv2s2) {
    double s = sig_accum[0] / (double)(N_TOT*KNB);
    inv2s2[0] = (float)(1.0/(2.0*s*s));
}

__global__ __launch_bounds__(256)
void k_kern(const float* __restrict__ tD, const int* __restrict__ tI,
            const float* __restrict__ inv2s2,
            float* __restrict__ kern, float* __restrict__ deg) {
    int e = blockIdx.x*256 + threadIdx.x;
    int i = e>>4;
    float d2 = fmaxf(tD[e], 0.f);
    float kv = expf(-d2 * inv2s2[0]);
    kern[e] = kv;
    atomicAdd(&deg[i], 0.5f*kv);
    atomicAdd(&deg[tI[e]], 0.5f*kv);
}

__global__ __launch_bounds__(256)
void k_dis(const float* __restrict__ deg, float* __restrict__ dis) {
    int i = blockIdx.x*256 + threadIdx.x;
    float v = deg[i];
    dis[i] = (v > 0.f) ? (1.0f/sqrtf(v)) : 0.f;
}

// wout[e] = 0.5 * kern[e] * dis[tI[e]]
__global__ __launch_bounds__(256)
void k_wedge(const float* __restrict__ kern, const int* __restrict__ tI,
             const float* __restrict__ dis, float* __restrict__ wout) {
    int e = blockIdx.x*256 + threadIdx.x;
    wout[e] = 0.5f * kern[e] * dis[tI[e]];
}

__global__ __launch_bounds__(256)
void k_count(const int* __restrict__ tI, int* __restrict__ cnt) {
    int e = blockIdx.x*256 + threadIdx.x;
    atomicAdd(&cnt[tI[e]], 1);
}

__global__ __launch_bounds__(1024)
void k_scan(const int* __restrict__ cnt, int* __restrict__ rowstart) {
    __shared__ int buf[1024];
    __shared__ int carry;
    int tid = threadIdx.x;
    if (tid==0) carry = 0;
    __syncthreads();
    for (int base = 0; base < N_TOT; base += 1024) {
        int v = cnt[base+tid];
        buf[tid]=v; __syncthreads();
        for (int off=1; off<1024; off<<=1) {
            int t = (tid>=off)? buf[tid-off] : 0; __syncthreads();
            buf[tid]+=t; __syncthreads();
        }
        rowstart[base+tid] = carry + buf[tid] - v;
        __syncthreads();
        if (tid==1023) carry += buf[1023];
        __syncthreads();
    }
    if (tid==0) rowstart[N_TOT] = carry;
}

// in-edge weights premultiplied: in_w[dst] = 0.5*kern[e]*dis[src_row]
__global__ __launch_bounds__(256)
void k_fill(const int* __restrict__ tI, const float* __restrict__ kern,
            const float* __restrict__ dis,
            const int* __restrict__ rowstart, int* __restrict__ c2,
            int* __restrict__ in_src, float* __restrict__ in_w) {
    int e = blockIdx.x*256 + threadIdx.x;
    int i = e>>4;
    int j = tI[e];
    int pos = atomicAdd(&c2[j], 1);
    int dst = rowstart[j] + pos;
    in_src[dst] = i; in_w[dst] = 0.5f*kern[e]*dis[i];
}

// src[rows up to 8192][256] f32 -> Th/Tl [256][outStride] bf16 split,
// transposed AND pre-swizzled within each 64-chunk of the out row.
__global__ __launch_bounds__(256)
void k_prepT(const float* __restrict__ S, unsigned short* __restrict__ Th,
             unsigned short* __restrict__ Tl, int outStride) {
    __shared__ float tile[64][65];
    int r0 = blockIdx.y*64;   // S rows (k-dim), 64-aligned chunk
    int c0 = blockIdx.x*64;   // S cols
    int t = threadIdx.x;
    {
        int row = t>>2, cseg = t&3;
        #pragma unroll
        for (int i=0;i<4;++i) {
            float4 v = *(const float4*)&S[(long)(r0+row)*256 + c0 + cseg*16 + i*4];
            tile[row][cseg*16+i*4+0]=v.x; tile[row][cseg*16+i*4+1]=v.y;
            tile[row][cseg*16+i*4+2]=v.z; tile[row][cseg*16+i*4+3]=v.w;
        }
    }
    __syncthreads();
    {
        int col = t>>2, rseg = t&3;
        int c = c0 + col;
        __align__(16) unsigned short hs[16], ls[16];
        #pragma unroll
        for (int i=0;i<16;++i) {
            float z = tile[rseg*16+i][col];
            hs[i] = f2bf(z);
            ls[i] = f2bf(z - bf2f(hs[i]));
        }
        #pragma unroll
        for (int half=0; half<2; ++half) {
            int gl = rseg*2 + half;
            int gs = gl ^ (c&7);
            long dst = (long)c*outStride + r0 + gs*8;
            *(uint4*)&Th[dst] = *(const uint4*)&hs[half*8];
            *(uint4*)&Tl[dst] = *(const uint4*)&ls[half*8];
        }
    }
}

// P = H @ Bmat via split-bf16 MFMA. A = Hh/Hl [8192][d] linear (source-XOR
// staged); B = BTh/BTl [256][d] pre-swizzled. grid (2, 64), 4 waves.
__global__ __launch_bounds__(256)
void k_hb(const unsigned short* __restrict__ Hh, const unsigned short* __restrict__ Hl,
          const unsigned short* __restrict__ BTh, const unsigned short* __restrict__ BTl,
          float* __restrict__ C, int d) {
    __shared__ unsigned short Ah[128*64], Al[128*64], Bh[128*64], Bl[128*64];
    int tid = threadIdx.x, w = tid>>6, lane = tid&63;
    int lr = lane&15, kg = lane>>4;
    int wr = w>>1, wc = w&1;
    int r0 = blockIdx.y*128;
    int c0 = blockIdx.x*128;
    f32x4 acc[4][4];
    #pragma unroll
    for (int m=0;m<4;++m)
        #pragma unroll
        for (int n=0;n<4;++n) acc[m][n] = (f32x4){0.f,0.f,0.f,0.f};

    for (int k0 = 0; k0 < d; k0 += 64) {
        __syncthreads();
        #pragma unroll
        for (int ii=0; ii<4; ++ii) {
            int rbase = w*32 + ii*8;
            int grow = rbase + (lane>>3);
            int gg = (lane&7) ^ (grow&7);
            long asrc = (long)(r0+grow)*d + k0 + gg*8;
            __builtin_amdgcn_global_load_lds((const void*)&Hh[asrc], (void*)&Ah[rbase*64], 16, 0, 0);
            __builtin_amdgcn_global_load_lds((const void*)&Hl[asrc], (void*)&Al[rbase*64], 16, 0, 0);
            long bsrc = (long)(c0+grow)*d + k0 + (lane&7)*8;
            __builtin_amdgcn_global_load_lds((const void*)&BTh[bsrc], (void*)&Bh[rbase*64], 16, 0, 0);
            __builtin_amdgcn_global_load_lds((const void*)&BTl[bsrc], (void*)&Bl[rbase*64], 16, 0, 0);
        }
        __syncthreads();
        #pragma unroll
        for (int ks=0; ks<2; ++ks) {
            int gsw = ((ks<<2)|kg) ^ (lr&7);
            bf16x8 ah[4], al[4];
            #pragma unroll
            for (int m=0;m<4;++m) {
                ah[m] = *(const bf16x8*)&Ah[(wr*64+m*16+lr)*64 + gsw*8];
                al[m] = *(const bf16x8*)&Al[(wr*64+m*16+lr)*64 + gsw*8];
            }
            #pragma unroll
            for (int n=0;n<4;++n) {
                bf16x8 bh = *(const bf16x8*)&Bh[(wc*64+n*16+lr)*64 + gsw*8];
                bf16x8 bl = *(const bf16x8*)&Bl[(wc*64+n*16+lr)*64 + gsw*8];
                #pragma unroll
                for (int m=0;m<4;++m) {
                    acc[m][n] = __builtin_amdgcn_mfma_f32_16x16x32_bf16(ah[m], bh, acc[m][n], 0,0,0);
                    acc[m][n] = __builtin_amdgcn_mfma_f32_16x16x32_bf16(ah[m], bl, acc[m][n], 0,0,0);
                    acc[m][n] = __builtin_amdgcn_mfma_f32_16x16x32_bf16(al[m], bh, acc[m][n], 0,0,0);
                }
            }
        }
    }
    #pragma unroll
    for (int n=0;n<4;++n) {
        int col = c0 + wc*64 + n*16 + lr;
        #pragma unroll
        for (int m=0;m<4;++m) {
            int rg = r0 + wr*64 + m*16 + kg*4;
            #pragma unroll
            for (int q=0;q<4;++q)
                C[(long)(rg+q)*256 + col] = acc[m][n][q];
        }
    }
}

// part[ks] = adj[:, slab] @ P[slab, :]  (split-bf16 MFMA, K-split, T14
// reg-prefetch of adj). grid (2, 128, KS), block 256 (4 waves x 16 rows).
__global__ __launch_bounds__(256)
void k_adjP3(const float* __restrict__ adj, const unsigned short* __restrict__ PTsh,
             const unsigned short* __restrict__ PTsl, float* __restrict__ part) {
    __shared__ unsigned short Ah[64*64], Al[64*64];
    __shared__ unsigned short Bh[128*64], Bl[128*64];
    int tid = threadIdx.x, w = tid>>6, lane = tid&63;
    int lr = lane&15, kg = lane>>4;
    int r0 = blockIdx.y*64;
    int c0 = blockIdx.x*128;
    int kbeg = blockIdx.z*(N_TOT/KS), kend = kbeg + N_TOT/KS;
    f32x4 acc[8];
    #pragma unroll
    for (int fc=0; fc<8; ++fc) acc[fc] = (f32x4){0.f,0.f,0.f,0.f};

    int arow = tid>>2, aseg = tid&3;
    float4 va[4];
    {
        const float* asrc = &adj[(long)(r0+arow)*N_TOT + kbeg + aseg*16];
        #pragma unroll
        for (int i=0;i<4;++i) va[i] = *(const float4*)&asrc[i*4];
    }
    for (int k0 = kbeg; k0 < kend; k0 += 64) {
        __syncthreads();
        #pragma unroll
        for (int i=0;i<4;++i) {
            float z[4] = {va[i].x, va[i].y, va[i].z, va[i].w};
            __align__(8) unsigned short h[4], l[4];
            #pragma unroll
            for (int j=0;j<4;++j) {
                h[j] = f2bf(z[j]);
                l[j] = f2bf(z[j] - bf2f(h[j]));
            }
            int col = aseg*16 + i*4;
            int g = col>>3, sub = col&7;
            int off = arow*128 + ((g ^ (arow&7))*16) + sub*2;
            *(ushort4*)((char*)Ah + off) = *(const ushort4*)h;
            *(ushort4*)((char*)Al + off) = *(const ushort4*)l;
        }
        #pragma unroll
        for (int ii=0; ii<4; ++ii) {
            int rbase = w*32 + ii*8;
            int grow = rbase + (lane>>3);
            long src = (long)(c0+grow)*N_TOT + k0 + (lane&7)*8;
            __builtin_amdgcn_global_load_lds((const void*)&PTsh[src], (void*)&Bh[rbase*64], 16, 0, 0);
            __builtin_amdgcn_global_load_lds((const void*)&PTsl[src], (void*)&Bl[rbase*64], 16, 0, 0);
        }
        __syncthreads();
        if (k0 + 64 < kend) {
            const float* asrc = &adj[(long)(r0+arow)*N_TOT + k0 + 64 + aseg*16];
            #pragma unroll
            for (int i=0;i<4;++i) va[i] = *(const float4*)&asrc[i*4];
        }
        #pragma unroll
        for (int ks=0; ks<2; ++ks) {
            int gsw = ((ks<<2)|kg) ^ (lr&7);
            bf16x8 ah = *(const bf16x8*)&Ah[(w*16+lr)*64 + gsw*8];
            bf16x8 al = *(const bf16x8*)&Al[(w*16+lr)*64 + gsw*8];
            #pragma unroll
            for (int fc=0; fc<8; ++fc) {
                bf16x8 bh = *(const bf16x8*)&Bh[(fc*16+lr)*64 + gsw*8];
                bf16x8 bl = *(const bf16x8*)&Bl[(fc*16+lr)*64 + gsw*8];
                acc[fc] = __builtin_amdgcn_mfma_f32_16x16x32_bf16(ah, bh, acc[fc], 0,0,0);
                acc[fc] = __builtin_amdgcn_mfma_f32_16x16x32_bf16(ah, bl, acc[fc], 0,0,0);
                acc[fc] = __builtin_amdgcn_mfma_f32_16x16x32_bf16(al, bh, acc[fc], 0,0,0);
            }
        }
    }
    long base = (long)blockIdx.z*N_TOT*256;
    #pragma unroll
    for (int fc=0; fc<8; ++fc)
        #pragma unroll
        for (int q=0; q<4; ++q) {
            int rg = r0 + w*16 + kg*4 + q;
            int cg = c0 + fc*16 + lr;
            part[base + (long)rg*256 + cg] = acc[fc][q];
        }
}

// preS = scale * sum_ks part[ks]  (deterministic order)
__global__ __launch_bounds__(256)
void k_adjred(const float* __restrict__ part, float* __restrict__ preS, float scale) {
    long i4 = ((long)blockIdx.x*256 + threadIdx.x)*4;
    long n = (long)N_TOT*256;
    float sx=0.f, sy=0.f, sz=0.f, sw=0.f;
    for (int ch = 0; ch < KS; ++ch) {
        float4 a = *(const float4*)&part[(long)ch*n + i4];
        sx += a.x; sy += a.y; sz += a.z; sw += a.w;
    }
    float4 o; o.x = scale*sx; o.y = scale*sy; o.z = scale*sz; o.w = scale*sw;
    *(float4*)&preS[i4] = o;
}

__global__ __launch_bounds__(256)
void k_wsym(const float* __restrict__ w2, float* __restrict__ w2s) {
    int i = blockIdx.x, j = threadIdx.x;
    w2s[i*256+j] = 0.5f*(w2[i*256+j] + w2[j*256+i]);
}

// out[i][c] = tanh(preS + dis_i * (sum_out + sum_in)); 4-way ILP gather.
__global__ __launch_bounds__(256)
void k_spmm_tanh(const float* __restrict__ P, const float* __restrict__ preS,
                 const float* __restrict__ wout, const int* __restrict__ tI,
                 const float* __restrict__ dis, const int* __restrict__ rowstart,
                 const int* __restrict__ in_src, const float* __restrict__ in_w,
                 float* __restrict__ out) {
    int i = blockIdx.x, c = threadIdx.x;
    float a0=0.f, a1=0.f, a2=0.f, a3=0.f;
    #pragma unroll
    for (int k = 0; k < 16; k += 4) {
        int e = i*16+k;
        int j0 = tI[e+0], j1 = tI[e+1], j2 = tI[e+2], j3 = tI[e+3];
        float w0 = wout[e+0], w1 = wout[e+1], w2 = wout[e+2], w3 = wout[e+3];
        a0 = fmaf(w0, P[(long)j0*256 + c], a0);
        a1 = fmaf(w1, P[(long)j1*256 + c], a1);
        a2 = fmaf(w2, P[(long)j2*256 + c], a2);
        a3 = fmaf(w3, P[(long)j3*256 + c], a3);
    }
    int s0 = rowstart[i], s1 = rowstart[i+1];
    int t = s0;
    for (; t + 4 <= s1; t += 4) {
        int j0 = in_src[t+0], j1 = in_src[t+1], j2 = in_src[t+2], j3 = in_src[t+3];
        float w0 = in_w[t+0], w1 = in_w[t+1], w2 = in_w[t+2], w3 = in_w[t+3];
        a0 = fmaf(w0, P[(long)j0*256 + c], a0);
        a1 = fmaf(w1, P[(long)j1*256 + c], a1);
        a2 = fmaf(w2, P[(long)j2*256 + c], a2);
        a3 = fmaf(w3, P[(long)j3*256 + c], a3);
    }
    for (; t < s1; ++t)
        a0 = fmaf(in_w[t], P[(long)in_src[t]*256 + c], a0);
    float acc = (a0 + a1) + (a2 + a3);
    float pre = preS[(long)i*256+c] + dis[i]*acc;
    out[(long)i*256+c] = tanhf(pre);
}

// ---------------------------------------------------------------------------
extern "C" void kernel_launch(void* const* d_in, const int* in_sizes, int n_in,
                              void* d_out, int out_size, void* d_ws, size_t ws_size,
                              hipStream_t stream) {
    const float* x   = (const float*)d_in[0];
    const float* adj = (const float*)d_in[1];
    const float* w1  = (const float*)d_in[2];
    const float* w2  = (const float*)d_in[3];

    char* ws = (char*)d_ws;
    size_t off = 0;
    auto alloc = [&](size_t bytes){ size_t o = off; off += (bytes+255)&~(size_t)255; return o; };
    double* A      = (double*)(ws + alloc((size_t)512*512*8));
    double* W      = (double*)(ws + alloc((size_t)512*512*8));
    double* Xb     = (double*)(ws + alloc((size_t)512*512*8));
    double* Apart  = (double*)(ws + alloc((size_t)NCH*512*512*8));
    double* sigacc = (double*)(ws + alloc(256));
    float*  inv2s2 = (float*)(ws + alloc(256));
    float*  bigZ   = (float*)(ws + alloc((size_t)N_TOT*512*4));  // Z, then P/preS
    unsigned short* Zh   = (unsigned short*)(ws + alloc((size_t)N_TOT*512*2));
    unsigned short* Hh   = (unsigned short*)(ws + alloc((size_t)N_TOT*512*2));
    unsigned short* Hl   = (unsigned short*)(ws + alloc((size_t)N_TOT*512*2));
    unsigned short* BTh  = (unsigned short*)(ws + alloc((size_t)256*512*2));
    unsigned short* BTl  = (unsigned short*)(ws + alloc((size_t)256*512*2));
    unsigned short* PTsh = (unsigned short*)(ws + alloc((size_t)256*N_TOT*2));
    unsigned short* PTsl = (unsigned short*)(ws + alloc((size_t)256*N_TOT*2));
    float*  d2buf  = (float*)(ws + alloc((size_t)PROWS*N_TOT*4));   // 64 MB panel
    float*  part   = (float*)(ws + alloc((size_t)KS*N_TOT*256*4));  // 64 MB
    float*  sq     = (float*)(ws + alloc((size_t)N_TOT*4));
    int*    tI32   = (int*)  (ws + alloc((size_t)N_TOT*32*4));
    float*  tD     = (float*)(ws + alloc((size_t)N_TOT*16*4));
    int*    tI     = (int*)  (ws + alloc((size_t)N_TOT*16*4));
    float*  kern   = (float*)(ws + alloc((size_t)N_TOT*16*4));
    float*  wout   = (float*)(ws + alloc((size_t)N_TOT*16*4));
    float*  deg    = (float*)(ws + alloc((size_t)N_TOT*4));
    float*  dis    = (float*)(ws + alloc((size_t)N_TOT*4));
    int*    cnt    = (int*)  (ws + alloc((size_t)N_TOT*4));
    int*    rowstart=(int*)  (ws + alloc((size_t)(N_TOT+1)*4));
    int*    c2     = (int*)  (ws + alloc((size_t)N_TOT*4));
    int*    in_src = (int*)  (ws + alloc((size_t)N_TOT*16*4));
    float*  in_w   = (float*)(ws + alloc((size_t)N_TOT*16*4));
    float*  out1   = (float*)(ws + alloc((size_t)N_TOT*256*4));
    float*  w2s    = (float*)(ws + alloc((size_t)256*256*4));
    float*  P      = bigZ;                       // overlays Z after Z is dead
    float*  preS   = bigZ + (size_t)N_TOT*256;

    auto run_stage = [&](const float* H, int d, const float* Bmat, float* outBuf) {
        int nb = d/64;
        int shift = (d == 512) ? 9 : 8;
        k_ata2<<<dim3(d/32, d/32, NCH), 256, 0, stream>>>(H, Apart, d);
        k_atared<<<d*d/256, 256, 0, stream>>>(Apart, A, d, 1.0);
        for (int p0 = 0; p0 < d; p0 += 64) {
            k_chol_diag<<<1, 64, 0, stream>>>(A, d, p0);
            int rem = d - p0 - 64;
            if (rem > 0) {
                k_trsm<<<(rem+255)/256, 256, 0, stream>>>(A, d, p0);
                k_syrk<<<dim3(rem/64, rem/64), 256, 0, stream>>>(A, d, p0);
            }
        }
        // X = L^{-1} via blocked inversion; W = X^T
        k_dinv<<<nb, 64, 0, stream>>>(A, Xb, d);
        for (int lev = 1; lev < nb; ++lev)
            k_xoff<<<nb - lev, 256, 0, stream>>>(A, Xb, d, lev);
        k_wtr<<<d*d/256, 256, 0, stream>>>(Xb, W, d, shift);
        k_hw<<<dim3(d/64, N_TOT/64), 256, 0, stream>>>(H, W, bigZ, d);
        k_sq<<<N_TOT/4, 256, 0, stream>>>(bigZ, sq, d);
        k_bf16<<<(int)(((long)N_TOT*d)/(256*8)), 256, 0, stream>>>(bigZ, Zh, (long)N_TOT*d);
        for (int pr = 0; pr < N_TOT; pr += PROWS) {
            k_gram<<<dim3(N_TOT/128, PROWS/128), 256, 0, stream>>>(Zh, sq, d2buf, d, pr);
            k_sel<<<PROWS, 512, 0, stream>>>(d2buf, tI32, pr);
        }
        hipMemsetAsync(sigacc, 0, 8, stream);
        if (d == 512)
            k_refine<512><<<N_TOT/4, 256, 0, stream>>>(bigZ, sq, tI32, tD, tI, sigacc);
        else
            k_refine<256><<<N_TOT/4, 256, 0, stream>>>(bigZ, sq, tI32, tD, tI, sigacc);
        k_sigfin<<<1, 1, 0, stream>>>(sigacc, inv2s2);
        hipMemsetAsync(deg, 0, N_TOT*4, stream);
        k_kern<<<N_TOT*16/256, 256, 0, stream>>>(tD, tI, inv2s2, kern, deg);
        k_dis<<<N_TOT/256, 256, 0, stream>>>(deg, dis);
        k_wedge<<<N_TOT*16/256, 256, 0, stream>>>(kern, tI, dis, wout);
        hipMemsetAsync(cnt, 0, N_TOT*4, stream);
        k_count<<<N_TOT*16/256, 256, 0, stream>>>(tI, cnt);
        k_scan<<<1, 1024, 0, stream>>>(cnt, rowstart);
        hipMemsetAsync(c2, 0, N_TOT*4, stream);
        k_fill<<<N_TOT*16/256, 256, 0, stream>>>(tI, kern, dis, rowstart, c2, in_src, in_w);
        // P = H @ Bmat via split-bf16 MFMA (Z dead now; P/preS overlay Z)
        k_split<<<(int)(((long)N_TOT*d)/(256*8)), 256, 0, stream>>>(H, Hh, Hl, (long)N_TOT*d);
        k_prepT<<<dim3(4, d/64), 256, 0, stream>>>(Bmat, BTh, BTl, d);
        k_hb<<<dim3(2, N_TOT/128), 256, 0, stream>>>(Hh, Hl, BTh, BTl, P, d);
        // preS = ALPHA * adj @ P via tiled split-bf16 MFMA (K-split + reduce)
        k_prepT<<<dim3(4, N_TOT/64), 256, 0, stream>>>(P, PTsh, PTsl, N_TOT);
        k_adjP3<<<dim3(2, N_TOT/64, KS), 256, 0, stream>>>(adj, PTsh, PTsl, part);
        k_adjred<<<(N_TOT*256)/(256*4), 256, 0, stream>>>(part, preS, ALPHA);
        k_spmm_tanh<<<N_TOT, 256, 0, stream>>>(P, preS, wout, tI, dis, rowstart,
                                               in_src, in_w, outBuf);
    };

    run_stage(x, 512, w1, out1);
    k_wsym<<<256, 256, 0, stream>>>(w2, w2s);
    run_stage(out1, 256, w2s, (float*)d_out);
}

// Round 15
// 4851.622 us; speedup vs baseline: 1.4568x; 1.4568x over previous
//
#include <hip/hip_runtime.h>
#include <math.h>
#include <float.h>

#define N_TOT 8192
#define KNB 16
#define ALPHA 0.5f
#define PROWS 2048           // d2 panel rows
#define NCH 8                // split-K chunks for A = H^T H
#define KS 8                 // split-K slabs for adj @ P

typedef short bf16x8 __attribute__((ext_vector_type(8)));
typedef float f32x4 __attribute__((ext_vector_type(4)));

__device__ inline unsigned short f2bf(float f) {
    unsigned u = __float_as_uint(f);
    u += 0x7fffu + ((u >> 16) & 1u);
    return (unsigned short)(u >> 16);
}
__device__ inline float bf2f(unsigned short h) {
    return __uint_as_float(((unsigned)h) << 16);
}

// ---------------------------------------------------------------------------
// Apart[ch] = H[ch-slice]^T H[ch-slice]  (f64 partials, f32 32-row inner)
__global__ __launch_bounds__(256)
void k_ata2(const float* __restrict__ H, double* __restrict__ Apart, int d) {
    __shared__ float Ha[32][33], Hb[32][33];
    int tid = threadIdx.x, tx = tid&15, ty = tid>>4;
    int a0 = blockIdx.y*32, b0 = blockIdx.x*32;
    int n0b = blockIdx.z*(N_TOT/NCH);
    int lrow = tid>>3, lseg = tid&7;
    double acc[2][2];
    acc[0][0]=acc[0][1]=acc[1][0]=acc[1][1]=0.0;
    for (int n0 = n0b; n0 < n0b + N_TOT/NCH; n0 += 32) {
        float4 va = *(const float4*)&H[(long)(n0+lrow)*d + a0 + lseg*4];
        float4 vb = *(const float4*)&H[(long)(n0+lrow)*d + b0 + lseg*4];
        __syncthreads();
        Ha[lrow][lseg*4+0]=va.x; Ha[lrow][lseg*4+1]=va.y;
        Ha[lrow][lseg*4+2]=va.z; Ha[lrow][lseg*4+3]=va.w;
        Hb[lrow][lseg*4+0]=vb.x; Hb[lrow][lseg*4+1]=vb.y;
        Hb[lrow][lseg*4+2]=vb.z; Hb[lrow][lseg*4+3]=vb.w;
        __syncthreads();
        float f00=0.f,f01=0.f,f10=0.f,f11=0.f;
        #pragma unroll
        for (int nn = 0; nn < 32; ++nn) {
            float a0v = Ha[nn][ty*2], a1v = Ha[nn][ty*2+1];
            float b0v = Hb[nn][tx*2], b1v = Hb[nn][tx*2+1];
            f00 = fmaf(a0v,b0v,f00); f01 = fmaf(a0v,b1v,f01);
            f10 = fmaf(a1v,b0v,f10); f11 = fmaf(a1v,b1v,f11);
        }
        acc[0][0]+= (double)f00; acc[0][1]+= (double)f01;
        acc[1][0]+= (double)f10; acc[1][1]+= (double)f11;
    }
    long base = (long)blockIdx.z*d*d;
    #pragma unroll
    for (int i=0;i<2;++i)
        #pragma unroll
        for (int j=0;j<2;++j)
            Apart[base + (long)(a0+ty*2+i)*d + b0+tx*2+j] = acc[i][j];
}

// A = beta*I + sum_ch Apart[ch]   (deterministic in-order reduce)
__global__ __launch_bounds__(256)
void k_atared(const double* __restrict__ Apart, double* __restrict__ A,
              int d, double beta) {
    long idx = (long)blockIdx.x*256 + threadIdx.x;
    long dd = (long)d*d;
    double s = 0.0;
    for (int ch = 0; ch < NCH; ++ch) s += Apart[ch*dd + idx];
    int r = (int)(idx / d), c = (int)(idx % d);
    A[idx] = s + ((r==c) ? beta : 0.0);
}

// ---------------------------------------------------------------------------
// Single-wave Cholesky of the 64x64 diagonal panel.
__global__ __launch_bounds__(64)
void k_chol_diag(double* __restrict__ A, int d, int p0) {
    __shared__ double Ad[64][65];
    int r = threadIdx.x;
    for (int idx = r; idx < 64*64; idx += 64)
        Ad[idx>>6][idx&63] = A[(long)(p0+(idx>>6))*d + p0+(idx&63)];
    __syncthreads();
    for (int j = 0; j < 64; ++j) {
        double pj = sqrt(Ad[j][j]);
        double lrj = Ad[r][j] / pj;
        __syncthreads();
        if (r > j) Ad[r][j] = lrj;
        else if (r == j) Ad[j][j] = pj;
        __syncthreads();
        if (r > j)
            for (int k = j+1; k <= r; ++k)
                Ad[r][k] -= lrj * Ad[k][j];
        __syncthreads();
    }
    for (int idx = r; idx < 64*64; idx += 64) {
        int i = idx>>6, c = idx&63;
        A[(long)(p0+i)*d + p0+c] = (c <= i) ? Ad[i][c] : 0.0;
    }
}

__global__ __launch_bounds__(256)
void k_trsm(double* __restrict__ A, int d, int p0) {
    __shared__ double Lp[64][65];
    __shared__ double dg[64];
    int tid = threadIdx.x;
    for (int idx = tid; idx < 64*64; idx += 256) {
        int j = idx>>6, k = idx&63;
        double v = A[(long)(p0+j)*d + p0+k];
        Lp[j][k] = (j > k) ? v : 0.0;
        if (j == k) dg[j] = v;
    }
    __syncthreads();
    int r = p0 + 64 + blockIdx.x*256 + tid;
    if (r >= d) return;
    double* Ar = &A[(long)r*d + p0];
    double v[64];
    #pragma unroll
    for (int j = 0; j < 64; ++j) v[j] = Ar[j];
    #pragma unroll
    for (int k = 0; k < 64; ++k) {
        double lr = v[k] / dg[k];
        Ar[k] = lr;
        #pragma unroll
        for (int j = 0; j < 64; ++j) v[j] -= lr * Lp[j][k];
    }
}

__global__ __launch_bounds__(256)
void k_syrk(double* __restrict__ A, int d, int p0) {
    int t0 = p0 + 64;
    int r0 = t0 + blockIdx.y*64, c0 = t0 + blockIdx.x*64;
    __shared__ double Lr[64][33], Lc[64][33];
    int tid = threadIdx.x, tx = tid&15, ty = tid>>4;
    double acc[16];
    #pragma unroll
    for (int i=0;i<16;++i) acc[i]=0.0;
    for (int kc = 0; kc < 64; kc += 32) {
        for (int idx = tid; idx < 64*32; idx += 256) {
            int i = idx>>5, k = idx&31;
            Lr[i][k] = A[(long)(r0+i)*d + p0+kc+k];
            Lc[i][k] = A[(long)(c0+i)*d + p0+kc+k];
        }
        __syncthreads();
        for (int k = 0; k < 32; ++k) {
            double a[4], b[4];
            #pragma unroll
            for (int i=0;i<4;++i){ a[i]=Lr[ty*4+i][k]; b[i]=Lc[tx*4+i][k]; }
            #pragma unroll
            for (int i=0;i<4;++i)
                #pragma unroll
                for (int j=0;j<4;++j) acc[i*4+j] += a[i]*b[j];
        }
        __syncthreads();
    }
    #pragma unroll
    for (int i=0;i<4;++i)
        #pragma unroll
        for (int j=0;j<4;++j)
            A[(long)(r0+ty*4+i)*d + (c0+tx*4+j)] -= acc[i*4+j];
}

// ---------------------------------------------------------------------------
__global__ __launch_bounds__(64)
void k_dinv(const double* __restrict__ A, double* __restrict__ X, int d) {
    __shared__ double Lb[64][65];
    __shared__ double Yb[64][65];
    int b = blockIdx.x, c = threadIdx.x;
    for (int r = 0; r < 64; ++r) Lb[r][c] = A[(long)(b*64+r)*d + b*64+c];
    for (int r = 0; r < 64; ++r) Yb[r][c] = 0.0;
    __syncthreads();
    for (int i = 0; i < 64; ++i) {
        double s = (i==c) ? 1.0 : 0.0;
        for (int k = 0; k < i; ++k) s -= Lb[i][k]*Yb[k][c];
        Yb[i][c] = s / Lb[i][i];
    }
    __syncthreads();
    for (int r = 0; r < 64; ++r) X[(long)(b*64+r)*d + b*64+c] = Yb[r][c];
}

// X_{ij} = -X_{ii} * sum_{k=j}^{i-1} L_{ik} X_{kj},  i = j + lev.
__global__ __launch_bounds__(256)
void k_xoff(const double* __restrict__ A, double* __restrict__ X, int d, int lev) {
    __shared__ double Lb[64][65];
    __shared__ double Xb[64][65];
    __shared__ double Sb[64][65];
    int j = blockIdx.x, i = j + lev;
    int tid = threadIdx.x, tx = tid&15, ty = tid>>4;
    double acc[4][4];
    #pragma unroll
    for (int m=0;m<4;++m)
        #pragma unroll
        for (int n=0;n<4;++n) acc[m][n]=0.0;
    for (int k = j; k < i; ++k) {
        __syncthreads();
        for (int idx = tid; idx < 64*64; idx += 256) {
            int r = idx>>6, cc = idx&63;
            Lb[r][cc] = A[(long)(i*64+r)*d + k*64+cc];
            Xb[r][cc] = X[(long)(k*64+r)*d + j*64+cc];
        }
        __syncthreads();
        for (int kk = 0; kk < 64; ++kk) {
            double a_[4], b_[4];
            #pragma unroll
            for (int m=0;m<4;++m) a_[m] = Lb[ty*4+m][kk];
            #pragma unroll
            for (int n=0;n<4;++n) b_[n] = Xb[kk][tx*4+n];
            #pragma unroll
            for (int m=0;m<4;++m)
                #pragma unroll
                for (int n=0;n<4;++n) acc[m][n] += a_[m]*b_[n];
        }
    }
    __syncthreads();
    #pragma unroll
    for (int m=0;m<4;++m)
        #pragma unroll
        for (int n=0;n<4;++n) Sb[ty*4+m][tx*4+n] = acc[m][n];
    for (int idx = tid; idx < 64*64; idx += 256) {
        int r = idx>>6, cc = idx&63;
        Lb[r][cc] = X[(long)(i*64+r)*d + i*64+cc];   // X_{ii}
    }
    __syncthreads();
    #pragma unroll
    for (int m=0;m<4;++m)
        #pragma unroll
        for (int n=0;n<4;++n) acc[m][n]=0.0;
    for (int kk = 0; kk < 64; ++kk) {
        double a_[4], b_[4];
        #pragma unroll
        for (int m=0;m<4;++m) a_[m] = Lb[ty*4+m][kk];
        #pragma unroll
        for (int n=0;n<4;++n) b_[n] = Sb[kk][tx*4+n];
        #pragma unroll
        for (int m=0;m<4;++m)
            #pragma unroll
            for (int n=0;n<4;++n) acc[m][n] += a_[m]*b_[n];
    }
    #pragma unroll
    for (int m=0;m<4;++m)
        #pragma unroll
        for (int n=0;n<4;++n)
            X[(long)(i*64+ty*4+m)*d + j*64+tx*4+n] = -acc[m][n];
}

// W = X^T with upper-of-X forced to zero.
__global__ __launch_bounds__(256)
void k_wtr(const double* __restrict__ X, double* __restrict__ W, int d, int shift) {
    int idx = blockIdx.x*256 + threadIdx.x;
    int k = idx >> shift, c = idx & (d-1);
    W[idx] = (k <= c) ? X[(long)c*d + k] : 0.0;
}

// Z = H @ W  (f32 in, f64 W, f64 accumulate, f32 out)
__global__ __launch_bounds__(256)
void k_hw(const float* __restrict__ H, const double* __restrict__ W,
          float* __restrict__ Z, int d) {
    __shared__ __align__(16) float Ht[32][68];
    __shared__ double Wt[32][66];
    int tid = threadIdx.x, tx = tid&15, ty = tid>>4;
    int r0 = blockIdx.y*64, c0 = blockIdx.x*64;
    double acc[4][4];
    #pragma unroll
    for (int i=0;i<4;++i)
        #pragma unroll
        for (int j=0;j<4;++j) acc[i][j]=0.0;
    for (int k0 = 0; k0 < d; k0 += 32) {
        {
            int row = tid>>2, koff = (tid&3)*8;
            const float* src = &H[(long)(r0+row)*d + k0+koff];
            float4 v0 = *(const float4*)src, v1 = *(const float4*)(src+4);
            Ht[koff+0][row]=v0.x; Ht[koff+1][row]=v0.y; Ht[koff+2][row]=v0.z; Ht[koff+3][row]=v0.w;
            Ht[koff+4][row]=v1.x; Ht[koff+5][row]=v1.y; Ht[koff+6][row]=v1.z; Ht[koff+7][row]=v1.w;
        }
        {
            int k = tid>>3, coff = (tid&7)*8;
            const double* src = &W[(long)(k0+k)*d + c0+coff];
            #pragma unroll
            for (int q=0;q<8;++q) Wt[k][coff+q] = src[q];
        }
        __syncthreads();
        #pragma unroll
        for (int k = 0; k < 32; ++k) {
            float4 av = *(const float4*)&Ht[k][ty*4];
            double a0=av.x, a1=av.y, a2=av.z, a3=av.w;
            double b[4];
            #pragma unroll
            for (int j=0;j<4;++j) b[j] = Wt[k][tx*4+j];
            #pragma unroll
            for (int j=0;j<4;++j) {
                acc[0][j] += a0*b[j]; acc[1][j] += a1*b[j];
                acc[2][j] += a2*b[j]; acc[3][j] += a3*b[j];
            }
        }
        __syncthreads();
    }
    #pragma unroll
    for (int i=0;i<4;++i)
        #pragma unroll
        for (int j=0;j<4;++j)
            Z[(long)(r0+ty*4+i)*d + c0+tx*4+j] = (float)acc[i][j];
}

__global__ __launch_bounds__(256)
void k_sq(const float* __restrict__ Z, float* __restrict__ sq, int d) {
    int row = blockIdx.x*4 + (threadIdx.x>>6);
    int lane = threadIdx.x&63;
    const float* z = &Z[(long)row*d];
    double s = 0.0;
    for (int c = lane; c < d; c += 64) { float v = z[c]; s += (double)v*v; }
    #pragma unroll
    for (int off=32; off>0; off>>=1) s += __shfl_down(s, off);
    if (lane==0) sq[row] = (float)s;
}

// f32 -> bf16 (round-to-nearest), single output
__global__ __launch_bounds__(256)
void k_bf16(const float* __restrict__ Z, unsigned short* __restrict__ Zh, long n) {
    long i = ((long)blockIdx.x*256 + threadIdx.x)*8;
    if (i >= n) return;
    float4 v0 = *(const float4*)&Z[i], v1 = *(const float4*)&Z[i+4];
    float z[8] = {v0.x,v0.y,v0.z,v0.w,v1.x,v1.y,v1.z,v1.w};
    __align__(16) unsigned short h[8];
    #pragma unroll
    for (int j=0;j<8;++j) h[j] = f2bf(z[j]);
    *(uint4*)&Zh[i] = *(const uint4*)h;
}

// f32 -> bf16 h + l split (linear layout)
__global__ __launch_bounds__(256)
void k_split(const float* __restrict__ in, unsigned short* __restrict__ ho,
             unsigned short* __restrict__ lo, long n) {
    long i = ((long)blockIdx.x*256 + threadIdx.x)*8;
    if (i >= n) return;
    float4 v0 = *(const float4*)&in[i], v1 = *(const float4*)&in[i+4];
    float z[8] = {v0.x,v0.y,v0.z,v0.w,v1.x,v1.y,v1.z,v1.w};
    __align__(16) unsigned short h[8], l[8];
    #pragma unroll
    for (int j=0;j<8;++j) {
        h[j] = f2bf(z[j]);
        l[j] = f2bf(z[j] - bf2f(h[j]));
    }
    *(uint4*)&ho[i] = *(const uint4*)h;
    *(uint4*)&lo[i] = *(const uint4*)l;
}

// ---------------------------------------------------------------------------
// d2 panel GEMM: d2[r - prow0][c] = sq_r + sq_c - 2*(Zh_r . Zh_c), bf16 MFMA.
__global__ __launch_bounds__(256)
void k_gram(const unsigned short* __restrict__ Zh, const float* __restrict__ sq,
            float* __restrict__ d2, int d, int prow0) {
    __shared__ unsigned short At[128*64], Bt[128*64];
    int tid = threadIdx.x, w = tid>>6, lane = tid&63;
    int lr = lane&15, kg = lane>>4;
    int wr = w>>1, wc = w&1;
    int r0 = prow0 + blockIdx.y*128;
    int c0 = blockIdx.x*128;
    f32x4 acc[4][4];
    #pragma unroll
    for (int m=0;m<4;++m)
        #pragma unroll
        for (int n=0;n<4;++n) acc[m][n] = (f32x4){0.f,0.f,0.f,0.f};

    for (int k0 = 0; k0 < d; k0 += 64) {
        __syncthreads();
        #pragma unroll
        for (int ii=0; ii<4; ++ii) {
            int rbase = w*32 + ii*8;
            int grow = rbase + (lane>>3);
            int gg = (lane&7) ^ (grow&7);
            __builtin_amdgcn_global_load_lds((const void*)&Zh[(long)(r0+grow)*d + k0 + gg*8],
                                             (void*)&At[rbase*64], 16, 0, 0);
            __builtin_amdgcn_global_load_lds((const void*)&Zh[(long)(c0+grow)*d + k0 + gg*8],
                                             (void*)&Bt[rbase*64], 16, 0, 0);
        }
        __syncthreads();
        #pragma unroll
        for (int ks=0; ks<2; ++ks) {
            int gsw = ((ks<<2)|kg) ^ (lr&7);
            bf16x8 a_[4];
            #pragma unroll
            for (int m=0;m<4;++m) a_[m] = *(const bf16x8*)&At[(wr*64+m*16+lr)*64 + gsw*8];
            #pragma unroll
            for (int n=0;n<4;++n) {
                bf16x8 b_ = *(const bf16x8*)&Bt[(wc*64+n*16+lr)*64 + gsw*8];
                #pragma unroll
                for (int m=0;m<4;++m)
                    acc[m][n] = __builtin_amdgcn_mfma_f32_16x16x32_bf16(a_[m], b_, acc[m][n], 0,0,0);
            }
        }
    }
    float sr[4][4];
    #pragma unroll
    for (int m=0;m<4;++m)
        #pragma unroll
        for (int q=0;q<4;++q) sr[m][q] = sq[r0 + wr*64 + m*16 + kg*4 + q];
    #pragma unroll
    for (int n=0;n<4;++n) {
        int col = c0 + wc*64 + n*16 + lr;
        float sc = sq[col];
        #pragma unroll
        for (int m=0;m<4;++m) {
            int rloc = (r0 - prow0) + wr*64 + m*16 + kg*4;
            #pragma unroll
            for (int q=0;q<4;++q)
                d2[(long)(rloc+q)*N_TOT + col] = sr[m][q] + sc - 2.f*acc[m][n][q];
        }
    }
}

// Per-row exact top-32: per-wave zero-barrier radix select (shfl-only),
// then wave-0 REGISTER merge (radix + prefix-sum writes, no serial sort).
__global__ __launch_bounds__(512)
void k_sel(const float* __restrict__ d2, int* __restrict__ tI32, int prow0) {
    __shared__ int   wcnt[8];
    __shared__ float cbv[8][96];   // monotone-uint bits stored as float
    __shared__ int   cbi[8][96];
    __shared__ int   tieIdx[64];
    int tid = threadIdx.x, w = tid>>6, lane = tid&63;
    int row = blockIdx.x;
    const float* rp = &d2[(long)row*N_TOT];
    unsigned u[16];
    #pragma unroll
    for (int j=0;j<4;++j) {
        float4 q = *(const float4*)&rp[j*2048 + tid*4];
        float z[4] = {q.x, q.y, q.z, q.w};
        #pragma unroll
        for (int e=0;e<4;++e) {
            unsigned b = __float_as_uint(z[e]);
            u[j*4+e] = (b & 0x80000000u) ? ~b : (b | 0x80000000u);
        }
    }
    if (lane == 0) wcnt[w] = 0;
    // wave-local radix: rank-32 threshold among this wave's 1024 values
    unsigned p = 0;
    for (int b = 31; b >= 0; --b) {
        unsigned t = p | (1u<<b);
        int c = 0;
        #pragma unroll
        for (int i=0;i<16;++i) c += (u[i] < t) ? 1 : 0;
        #pragma unroll
        for (int off=32; off>0; off>>=1) c += __shfl_xor(c, off);
        if (c < 32) p = t;
    }
    #pragma unroll
    for (int i=0;i<16;++i) {
        if (u[i] <= p) {
            int pos = atomicAdd(&wcnt[w], 1);
            if (pos < 96) {
                cbv[w][pos] = __uint_as_float(u[i]);
                cbi[w][pos] = (i>>2)*2048 + tid*4 + (i&3);
            }
        }
    }
    __syncthreads();
    if (w == 0) {
        int wb[9];
        wb[0] = 0;
        #pragma unroll
        for (int ww=0; ww<8; ++ww) {
            int c = wcnt[ww]; if (c > 96) c = 96;
            wb[ww+1] = wb[ww] + c;
        }
        int Mtot = wb[8];
        unsigned mu[12]; int mi[12];
        #pragma unroll
        for (int j=0;j<12;++j) {
            int cidx = lane + j*64;
            unsigned val = 0xFFFFFFFFu; int idx = 0x7fffffff;
            if (cidx < Mtot) {
                int ww = 0;
                #pragma unroll
                for (int q=1;q<8;++q) if (cidx >= wb[q]) ww = q;
                int off = cidx - wb[ww];
                val = __float_as_uint(cbv[ww][off]);
                idx = cbi[ww][off];
            }
            mu[j] = val; mi[j] = idx;
        }
        // exact global rank-32 value over candidates (== row rank-32)
        unsigned p32 = 0;
        for (int b = 31; b >= 0; --b) {
            unsigned t = p32 | (1u<<b);
            int c = 0;
            #pragma unroll
            for (int j=0;j<12;++j) c += (mu[j] < t) ? 1 : 0;
            #pragma unroll
            for (int off=32; off>0; off>>=1) c += __shfl_xor(c, off);
            if (c < 32) p32 = t;
        }
        long rg = (long)(prow0 + row);
        // prefix-sum write positions for strict-less members
        int myA = 0, myT = 0;
        #pragma unroll
        for (int j=0;j<12;++j) {
            myA += (mu[j] < p32) ? 1 : 0;
            myT += (mu[j] == p32) ? 1 : 0;
        }
        int incA = myA;
        #pragma unroll
        for (int off=1; off<64; off<<=1) {
            int t = __shfl_up(incA, off);
            if (lane >= off) incA += t;
        }
        int preA = incA - myA;
        int m1 = __shfl(incA, 63);
        int incT = myT;
        #pragma unroll
        for (int off=1; off<64; off<<=1) {
            int t = __shfl_up(incT, off);
            if (lane >= off) incT += t;
        }
        int preT = incT - myT;
        int tn = __shfl(incT, 63); if (tn > 64) tn = 64;
        int ka = 0, kt = 0;
        #pragma unroll
        for (int j=0;j<12;++j) {
            if (mu[j] < p32) {
                tI32[rg*32 + preA + ka] = mi[j]; ++ka;
            } else if (mu[j] == p32) {
                if (preT + kt < 64) tieIdx[preT + kt] = mi[j];
                ++kt;
            }
        }
        __builtin_amdgcn_wave_barrier();
        if (lane == 0) {
            int need = 32 - m1;
            for (int s = 0; s < need; ++s) {
                int best = 0x7fffffff, bj = -1;
                for (int t = 0; t < tn; ++t) {
                    int v = tieIdx[t];
                    if (v < best) { best = v; bj = t; }
                }
                tI32[rg*32 + m1 + s] = best;
                if (bj >= 0) tieIdx[bj] = 0x7fffffff;
            }
        }
    }
}

// Phase 2: exact f32 d2 for the 32 global candidates; exact top-16 + sigma.
// 2-way ILP across candidates.
template<int D>
__global__ __launch_bounds__(256)
void k_refine(const float* __restrict__ Z, const float* __restrict__ sq,
              const int* __restrict__ tI32,
              float* __restrict__ tD, int* __restrict__ tI, double* sig_accum) {
    __shared__ float rD[4][32];
    __shared__ int   rI[4][32];
    __shared__ float bD[4][17];
    __shared__ int   bI[4][17];
    int wv = threadIdx.x>>6, lane = threadIdx.x&63;
    long row = (long)blockIdx.x*4 + wv;
    float zi[D/64];
    #pragma unroll
    for (int t=0;t<D/64;++t) zi[t] = Z[row*D + t*64 + lane];
    float sqi = sq[row];
    for (int c = 0; c < 32; c += 2) {
        int j0 = tI32[row*32 + c], j1 = tI32[row*32 + c + 1];
        float dot0 = 0.f, dot1 = 0.f;
        #pragma unroll
        for (int t=0;t<D/64;++t) {
            dot0 = fmaf(zi[t], Z[(long)j0*D + t*64 + lane], dot0);
            dot1 = fmaf(zi[t], Z[(long)j1*D + t*64 + lane], dot1);
        }
        #pragma unroll
        for (int off=32; off>0; off>>=1) {
            dot0 += __shfl_xor(dot0, off);
            dot1 += __shfl_xor(dot1, off);
        }
        if (lane == 0) {
            rD[wv][c]   = sqi + sq[j0] - 2.f*dot0; rI[wv][c]   = j0;
            rD[wv][c+1] = sqi + sq[j1] - 2.f*dot1; rI[wv][c+1] = j1;
        }
    }
    if (lane == 0) {
        #pragma unroll
        for (int k=0;k<16;++k){ bD[wv][k]=FLT_MAX; bI[wv][k]=0x7fffffff; }
        for (int c = 0; c < 32; ++c) {
            float dv = rD[wv][c]; int ci = rI[wv][c];
            float wd = bD[wv][15]; int wi = bI[wv][15];
            if (dv < wd || (dv == wd && ci < wi)) {
                int pos = 15;
                while (pos > 0) {
                    float pd_ = bD[wv][pos-1]; int pi_ = bI[wv][pos-1];
                    if (dv < pd_ || (dv == pd_ && ci < pi_)) {
                        bD[wv][pos]=pd_; bI[wv][pos]=pi_; --pos;
                    } else break;
                }
                bD[wv][pos]=dv; bI[wv][pos]=ci;
            }
        }
        double ps = 0.0;
        #pragma unroll
        for (int k=0;k<16;++k) {
            float dv = bD[wv][k];
            tD[row*16+k] = dv; tI[row*16+k] = bI[wv][k];
            ps += sqrt((double)fmaxf(dv, 0.f));
        }
        atomicAdd(sig_accum, ps);
    }
}

__global__ void k_sigfin(const double* __restrict__ sig_accum, float* __restrict__ inv2s2) {
    double s = sig_accum[0] / (double)(N_TOT*KNB);
    inv2s2[0] = (float)(1.0/(2.0*s*s));
}

__global__ __launch_bounds__(256)
void k_kern(const float* __restrict__ tD, const int* __restrict__ tI,
            const float* __restrict__ inv2s2,
            float* __restrict__ kern, float* __restrict__ deg) {
    int e = blockIdx.x*256 + threadIdx.x;
    int i = e>>4;
    float d2 = fmaxf(tD[e], 0.f);
    float kv = expf(-d2 * inv2s2[0]);
    kern[e] = kv;
    atomicAdd(&deg[i], 0.5f*kv);
    atomicAdd(&deg[tI[e]], 0.5f*kv);
}

__global__ __launch_bounds__(256)
void k_dis(const float* __restrict__ deg, float* __restrict__ dis) {
    int i = blockIdx.x*256 + threadIdx.x;
    float v = deg[i];
    dis[i] = (v > 0.f) ? (1.0f/sqrtf(v)) : 0.f;
}

// wout[e] = 0.5 * kern[e] * dis[tI[e]]
__global__ __launch_bounds__(256)
void k_wedge(const float* __restrict__ kern, const int* __restrict__ tI,
             const float* __restrict__ dis, float* __restrict__ wout) {
    int e = blockIdx.x*256 + threadIdx.x;
    wout[e] = 0.5f * kern[e] * dis[tI[e]];
}

__global__ __launch_bounds__(256)
void k_count(const int* __restrict__ tI, int* __restrict__ cnt) {
    int e = blockIdx.x*256 + threadIdx.x;
    atomicAdd(&cnt[tI[e]], 1);
}

__global__ __launch_bounds__(1024)
void k_scan(const int* __restrict__ cnt, int* __restrict__ rowstart) {
    __shared__ int buf[1024];
    __shared__ int carry;
    int tid = threadIdx.x;
    if (tid==0) carry = 0;
    __syncthreads();
    for (int base = 0; base < N_TOT; base += 1024) {
        int v = cnt[base+tid];
        buf[tid]=v; __syncthreads();
        for (int off=1; off<1024; off<<=1) {
            int t = (tid>=off)? buf[tid-off] : 0; __syncthreads();
            buf[tid]+=t; __syncthreads();
        }
        rowstart[base+tid] = carry + buf[tid] - v;
        __syncthreads();
        if (tid==1023) carry += buf[1023];
        __syncthreads();
    }
    if (tid==0) rowstart[N_TOT] = carry;
}

// in-edge weights premultiplied: in_w[dst] = 0.5*kern[e]*dis[src_row]
__global__ __launch_bounds__(256)
void k_fill(const int* __restrict__ tI, const float* __restrict__ kern,
            const float* __restrict__ dis,
            const int* __restrict__ rowstart, int* __restrict__ c2,
            int* __restrict__ in_src, float* __restrict__ in_w) {
    int e = blockIdx.x*256 + threadIdx.x;
    int i = e>>4;
    int j = tI[e];
    int pos = atomicAdd(&c2[j], 1);
    int dst = rowstart[j] + pos;
    in_src[dst] = i; in_w[dst] = 0.5f*kern[e]*dis[i];
}

// src[rows up to 8192][256] f32 -> Th/Tl [256][outStride] bf16 split,
// transposed AND pre-swizzled within each 64-chunk of the out row.
__global__ __launch_bounds__(256)
void k_prepT(const float* __restrict__ S, unsigned short* __restrict__ Th,
             unsigned short* __restrict__ Tl, int outStride) {
    __shared__ float tile[64][65];
    int r0 = blockIdx.y*64;   // S rows (k-dim), 64-aligned chunk
    int c0 = blockIdx.x*64;   // S cols
    int t = threadIdx.x;
    {
        int row = t>>2, cseg = t&3;
        #pragma unroll
        for (int i=0;i<4;++i) {
            float4 v = *(const float4*)&S[(long)(r0+row)*256 + c0 + cseg*16 + i*4];
            tile[row][cseg*16+i*4+0]=v.x; tile[row][cseg*16+i*4+1]=v.y;
            tile[row][cseg*16+i*4+2]=v.z; tile[row][cseg*16+i*4+3]=v.w;
        }
    }
    __syncthreads();
    {
        int col = t>>2, rseg = t&3;
        int c = c0 + col;
        __align__(16) unsigned short hs[16], ls[16];
        #pragma unroll
        for (int i=0;i<16;++i) {
            float z = tile[rseg*16+i][col];
            hs[i] = f2bf(z);
            ls[i] = f2bf(z - bf2f(hs[i]));
        }
        #pragma unroll
        for (int half=0; half<2; ++half) {
            int gl = rseg*2 + half;
            int gs = gl ^ (c&7);
            long dst = (long)c*outStride + r0 + gs*8;
            *(uint4*)&Th[dst] = *(const uint4*)&hs[half*8];
            *(uint4*)&Tl[dst] = *(const uint4*)&ls[half*8];
        }
    }
}

// P = H @ Bmat via split-bf16 MFMA. A = Hh/Hl [8192][d] linear (source-XOR
// staged); B = BTh/BTl [256][d] pre-swizzled. grid (2, 64), 4 waves.
__global__ __launch_bounds__(256)
void k_hb(const unsigned short* __restrict__ Hh, const unsigned short* __restrict__ Hl,
          const unsigned short* __restrict__ BTh, const unsigned short* __restrict__ BTl,
          float* __restrict__ C, int d) {
    __shared__ unsigned short Ah[128*64], Al[128*64], Bh[128*64], Bl[128*64];
    int tid = threadIdx.x, w = tid>>6, lane = tid&63;
    int lr = lane&15, kg = lane>>4;
    int wr = w>>1, wc = w&1;
    int r0 = blockIdx.y*128;
    int c0 = blockIdx.x*128;
    f32x4 acc[4][4];
    #pragma unroll
    for (int m=0;m<4;++m)
        #pragma unroll
        for (int n=0;n<4;++n) acc[m][n] = (f32x4){0.f,0.f,0.f,0.f};

    for (int k0 = 0; k0 < d; k0 += 64) {
        __syncthreads();
        #pragma unroll
        for (int ii=0; ii<4; ++ii) {
            int rbase = w*32 + ii*8;
            int grow = rbase + (lane>>3);
            int gg = (lane&7) ^ (grow&7);
            long asrc = (long)(r0+grow)*d + k0 + gg*8;
            __builtin_amdgcn_global_load_lds((const void*)&Hh[asrc], (void*)&Ah[rbase*64], 16, 0, 0);
            __builtin_amdgcn_global_load_lds((const void*)&Hl[asrc], (void*)&Al[rbase*64], 16, 0, 0);
            long bsrc = (long)(c0+grow)*d + k0 + (lane&7)*8;
            __builtin_amdgcn_global_load_lds((const void*)&BTh[bsrc], (void*)&Bh[rbase*64], 16, 0, 0);
            __builtin_amdgcn_global_load_lds((const void*)&BTl[bsrc], (void*)&Bl[rbase*64], 16, 0, 0);
        }
        __syncthreads();
        #pragma unroll
        for (int ks=0; ks<2; ++ks) {
            int gsw = ((ks<<2)|kg) ^ (lr&7);
            bf16x8 ah[4], al[4];
            #pragma unroll
            for (int m=0;m<4;++m) {
                ah[m] = *(const bf16x8*)&Ah[(wr*64+m*16+lr)*64 + gsw*8];
                al[m] = *(const bf16x8*)&Al[(wr*64+m*16+lr)*64 + gsw*8];
            }
            #pragma unroll
            for (int n=0;n<4;++n) {
                bf16x8 bh = *(const bf16x8*)&Bh[(wc*64+n*16+lr)*64 + gsw*8];
                bf16x8 bl = *(const bf16x8*)&Bl[(wc*64+n*16+lr)*64 + gsw*8];
                #pragma unroll
                for (int m=0;m<4;++m) {
                    acc[m][n] = __builtin_amdgcn_mfma_f32_16x16x32_bf16(ah[m], bh, acc[m][n], 0,0,0);
                    acc[m][n] = __builtin_amdgcn_mfma_f32_16x16x32_bf16(ah[m], bl, acc[m][n], 0,0,0);
                    acc[m][n] = __builtin_amdgcn_mfma_f32_16x16x32_bf16(al[m], bh, acc[m][n], 0,0,0);
                }
            }
        }
    }
    #pragma unroll
    for (int n=0;n<4;++n) {
        int col = c0 + wc*64 + n*16 + lr;
        #pragma unroll
        for (int m=0;m<4;++m) {
            int rg = r0 + wr*64 + m*16 + kg*4;
            #pragma unroll
            for (int q=0;q<4;++q)
                C[(long)(rg+q)*256 + col] = acc[m][n][q];
        }
    }
}

// part[ks] = adj[:, slab] @ P[slab, :]  (split-bf16 MFMA, K-split, T14
// reg-prefetch of adj). grid (2, 128, KS), block 256 (4 waves x 16 rows).
__global__ __launch_bounds__(256)
void k_adjP3(const float* __restrict__ adj, const unsigned short* __restrict__ PTsh,
             const unsigned short* __restrict__ PTsl, float* __restrict__ part) {
    __shared__ unsigned short Ah[64*64], Al[64*64];
    __shared__ unsigned short Bh[128*64], Bl[128*64];
    int tid = threadIdx.x, w = tid>>6, lane = tid&63;
    int lr = lane&15, kg = lane>>4;
    int r0 = blockIdx.y*64;
    int c0 = blockIdx.x*128;
    int kbeg = blockIdx.z*(N_TOT/KS), kend = kbeg + N_TOT/KS;
    f32x4 acc[8];
    #pragma unroll
    for (int fc=0; fc<8; ++fc) acc[fc] = (f32x4){0.f,0.f,0.f,0.f};

    int arow = tid>>2, aseg = tid&3;
    float4 va[4];
    {
        const float* asrc = &adj[(long)(r0+arow)*N_TOT + kbeg + aseg*16];
        #pragma unroll
        for (int i=0;i<4;++i) va[i] = *(const float4*)&asrc[i*4];
    }
    for (int k0 = kbeg; k0 < kend; k0 += 64) {
        __syncthreads();
        #pragma unroll
        for (int i=0;i<4;++i) {
            float z[4] = {va[i].x, va[i].y, va[i].z, va[i].w};
            __align__(8) unsigned short h[4], l[4];
            #pragma unroll
            for (int j=0;j<4;++j) {
                h[j] = f2bf(z[j]);
                l[j] = f2bf(z[j] - bf2f(h[j]));
            }
            int col = aseg*16 + i*4;
            int g = col>>3, sub = col&7;
            int off = arow*128 + ((g ^ (arow&7))*16) + sub*2;
            *(ushort4*)((char*)Ah + off) = *(const ushort4*)h;
            *(ushort4*)((char*)Al + off) = *(const ushort4*)l;
        }
        #pragma unroll
        for (int ii=0; ii<4; ++ii) {
            int rbase = w*32 + ii*8;
            int grow = rbase + (lane>>3);
            long src = (long)(c0+grow)*N_TOT + k0 + (lane&7)*8;
            __builtin_amdgcn_global_load_lds((const void*)&PTsh[src], (void*)&Bh[rbase*64], 16, 0, 0);
            __builtin_amdgcn_global_load_lds((const void*)&PTsl[src], (void*)&Bl[rbase*64], 16, 0, 0);
        }
        __syncthreads();
        if (k0 + 64 < kend) {
            const float* asrc = &adj[(long)(r0+arow)*N_TOT + k0 + 64 + aseg*16];
            #pragma unroll
            for (int i=0;i<4;++i) va[i] = *(const float4*)&asrc[i*4];
        }
        #pragma unroll
        for (int ks=0; ks<2; ++ks) {
            int gsw = ((ks<<2)|kg) ^ (lr&7);
            bf16x8 ah = *(const bf16x8*)&Ah[(w*16+lr)*64 + gsw*8];
            bf16x8 al = *(const bf16x8*)&Al[(w*16+lr)*64 + gsw*8];
            #pragma unroll
            for (int fc=0; fc<8; ++fc) {
                bf16x8 bh = *(const bf16x8*)&Bh[(fc*16+lr)*64 + gsw*8];
                bf16x8 bl = *(const bf16x8*)&Bl[(fc*16+lr)*64 + gsw*8];
                acc[fc] = __builtin_amdgcn_mfma_f32_16x16x32_bf16(ah, bh, acc[fc], 0,0,0);
                acc[fc] = __builtin_amdgcn_mfma_f32_16x16x32_bf16(ah, bl, acc[fc], 0,0,0);
                acc[fc] = __builtin_amdgcn_mfma_f32_16x16x32_bf16(al, bh, acc[fc], 0,0,0);
            }
        }
    }
    long base = (long)blockIdx.z*N_TOT*256;
    #pragma unroll
    for (int fc=0; fc<8; ++fc)
        #pragma unroll
        for (int q=0; q<4; ++q) {
            int rg = r0 + w*16 + kg*4 + q;
            int cg = c0 + fc*16 + lr;
            part[base + (long)rg*256 + cg] = acc[fc][q];
        }
}

// preS = scale * sum_ks part[ks]  (deterministic order)
__global__ __launch_bounds__(256)
void k_adjred(const float* __restrict__ part, float* __restrict__ preS, float scale) {
    long i4 = ((long)blockIdx.x*256 + threadIdx.x)*4;
    long n = (long)N_TOT*256;
    float sx=0.f, sy=0.f, sz=0.f, sw=0.f;
    for (int ch = 0; ch < KS; ++ch) {
        float4 a = *(const float4*)&part[(long)ch*n + i4];
        sx += a.x; sy += a.y; sz += a.z; sw += a.w;
    }
    float4 o; o.x = scale*sx; o.y = scale*sy; o.z = scale*sz; o.w = scale*sw;
    *(float4*)&preS[i4] = o;
}

__global__ __launch_bounds__(256)
void k_wsym(const float* __restrict__ w2, float* __restrict__ w2s) {
    int i = blockIdx.x, j = threadIdx.x;
    w2s[i*256+j] = 0.5f*(w2[i*256+j] + w2[j*256+i]);
}

// out[i][c] = tanh(preS + dis_i * (sum_out + sum_in)); 4-way ILP gather.
__global__ __launch_bounds__(256)
void k_spmm_tanh(const float* __restrict__ P, const float* __restrict__ preS,
                 const float* __restrict__ wout, const int* __restrict__ tI,
                 const float* __restrict__ dis, const int* __restrict__ rowstart,
                 const int* __restrict__ in_src, const float* __restrict__ in_w,
                 float* __restrict__ out) {
    int i = blockIdx.x, c = threadIdx.x;
    float a0=0.f, a1=0.f, a2=0.f, a3=0.f;
    #pragma unroll
    for (int k = 0; k < 16; k += 4) {
        int e = i*16+k;
        int j0 = tI[e+0], j1 = tI[e+1], j2 = tI[e+2], j3 = tI[e+3];
        float w0 = wout[e+0], w1 = wout[e+1], w2 = wout[e+2], w3 = wout[e+3];
        a0 = fmaf(w0, P[(long)j0*256 + c], a0);
        a1 = fmaf(w1, P[(long)j1*256 + c], a1);
        a2 = fmaf(w2, P[(long)j2*256 + c], a2);
        a3 = fmaf(w3, P[(long)j3*256 + c], a3);
    }
    int s0 = rowstart[i], s1 = rowstart[i+1];
    int t = s0;
    for (; t + 4 <= s1; t += 4) {
        int j0 = in_src[t+0], j1 = in_src[t+1], j2 = in_src[t+2], j3 = in_src[t+3];
        float w0 = in_w[t+0], w1 = in_w[t+1], w2 = in_w[t+2], w3 = in_w[t+3];
        a0 = fmaf(w0, P[(long)j0*256 + c], a0);
        a1 = fmaf(w1, P[(long)j1*256 + c], a1);
        a2 = fmaf(w2, P[(long)j2*256 + c], a2);
        a3 = fmaf(w3, P[(long)j3*256 + c], a3);
    }
    for (; t < s1; ++t)
        a0 = fmaf(in_w[t], P[(long)in_src[t]*256 + c], a0);
    float acc = (a0 + a1) + (a2 + a3);
    float pre = preS[(long)i*256+c] + dis[i]*acc;
    out[(long)i*256+c] = tanhf(pre);
}

// ---------------------------------------------------------------------------
extern "C" void kernel_launch(void* const* d_in, const int* in_sizes, int n_in,
                              void* d_out, int out_size, void* d_ws, size_t ws_size,
                              hipStream_t stream) {
    const float* x   = (const float*)d_in[0];
    const float* adj = (const float*)d_in[1];
    const float* w1  = (const float*)d_in[2];
    const float* w2  = (const float*)d_in[3];

    char* ws = (char*)d_ws;
    size_t off = 0;
    auto alloc = [&](size_t bytes){ size_t o = off; off += (bytes+255)&~(size_t)255; return o; };
    double* A      = (double*)(ws + alloc((size_t)512*512*8));
    double* W      = (double*)(ws + alloc((size_t)512*512*8));
    double* Xb     = (double*)(ws + alloc((size_t)512*512*8));
    double* Apart  = (double*)(ws + alloc((size_t)NCH*512*512*8));
    double* sigacc = (double*)(ws + alloc(256));
    float*  inv2s2 = (float*)(ws + alloc(256));
    float*  bigZ   = (float*)(ws + alloc((size_t)N_TOT*512*4));  // Z, then P/preS
    unsigned short* Zh   = (unsigned short*)(ws + alloc((size_t)N_TOT*512*2));
    unsigned short* Hh   = (unsigned short*)(ws + alloc((size_t)N_TOT*512*2));
    unsigned short* Hl   = (unsigned short*)(ws + alloc((size_t)N_TOT*512*2));
    unsigned short* BTh  = (unsigned short*)(ws + alloc((size_t)256*512*2));
    unsigned short* BTl  = (unsigned short*)(ws + alloc((size_t)256*512*2));
    unsigned short* PTsh = (unsigned short*)(ws + alloc((size_t)256*N_TOT*2));
    unsigned short* PTsl = (unsigned short*)(ws + alloc((size_t)256*N_TOT*2));
    float*  d2buf  = (float*)(ws + alloc((size_t)PROWS*N_TOT*4));   // 64 MB panel
    float*  part   = (float*)(ws + alloc((size_t)KS*N_TOT*256*4));  // 64 MB
    float*  sq     = (float*)(ws + alloc((size_t)N_TOT*4));
    int*    tI32   = (int*)  (ws + alloc((size_t)N_TOT*32*4));
    float*  tD     = (float*)(ws + alloc((size_t)N_TOT*16*4));
    int*    tI     = (int*)  (ws + alloc((size_t)N_TOT*16*4));
    float*  kern   = (float*)(ws + alloc((size_t)N_TOT*16*4));
    float*  wout   = (float*)(ws + alloc((size_t)N_TOT*16*4));
    float*  deg    = (float*)(ws + alloc((size_t)N_TOT*4));
    float*  dis    = (float*)(ws + alloc((size_t)N_TOT*4));
    int*    cnt    = (int*)  (ws + alloc((size_t)N_TOT*4));
    int*    rowstart=(int*)  (ws + alloc((size_t)(N_TOT+1)*4));
    int*    c2     = (int*)  (ws + alloc((size_t)N_TOT*4));
    int*    in_src = (int*)  (ws + alloc((size_t)N_TOT*16*4));
    float*  in_w   = (float*)(ws + alloc((size_t)N_TOT*16*4));
    float*  out1   = (float*)(ws + alloc((size_t)N_TOT*256*4));
    float*  w2s    = (float*)(ws + alloc((size_t)256*256*4));
    float*  P      = bigZ;                       // overlays Z after Z is dead
    float*  preS   = bigZ + (size_t)N_TOT*256;

    auto run_stage = [&](const float* H, int d, const float* Bmat, float* outBuf) {
        int nb = d/64;
        int shift = (d == 512) ? 9 : 8;
        k_ata2<<<dim3(d/32, d/32, NCH), 256, 0, stream>>>(H, Apart, d);
        k_atared<<<d*d/256, 256, 0, stream>>>(Apart, A, d, 1.0);
        for (int p0 = 0; p0 < d; p0 += 64) {
            k_chol_diag<<<1, 64, 0, stream>>>(A, d, p0);
            int rem = d - p0 - 64;
            if (rem > 0) {
                k_trsm<<<(rem+255)/256, 256, 0, stream>>>(A, d, p0);
                k_syrk<<<dim3(rem/64, rem/64), 256, 0, stream>>>(A, d, p0);
            }
        }
        // X = L^{-1} via blocked inversion; W = X^T
        k_dinv<<<nb, 64, 0, stream>>>(A, Xb, d);
        for (int lev = 1; lev < nb; ++lev)
            k_xoff<<<nb - lev, 256, 0, stream>>>(A, Xb, d, lev);
        k_wtr<<<d*d/256, 256, 0, stream>>>(Xb, W, d, shift);
        k_hw<<<dim3(d/64, N_TOT/64), 256, 0, stream>>>(H, W, bigZ, d);
        k_sq<<<N_TOT/4, 256, 0, stream>>>(bigZ, sq, d);
        k_bf16<<<(int)(((long)N_TOT*d)/(256*8)), 256, 0, stream>>>(bigZ, Zh, (long)N_TOT*d);
        for (int pr = 0; pr < N_TOT; pr += PROWS) {
            k_gram<<<dim3(N_TOT/128, PROWS/128), 256, 0, stream>>>(Zh, sq, d2buf, d, pr);
            k_sel<<<PROWS, 512, 0, stream>>>(d2buf, tI32, pr);
        }
        hipMemsetAsync(sigacc, 0, 8, stream);
        if (d == 512)
            k_refine<512><<<N_TOT/4, 256, 0, stream>>>(bigZ, sq, tI32, tD, tI, sigacc);
        else
            k_refine<256><<<N_TOT/4, 256, 0, stream>>>(bigZ, sq, tI32, tD, tI, sigacc);
        k_sigfin<<<1, 1, 0, stream>>>(sigacc, inv2s2);
        hipMemsetAsync(deg, 0, N_TOT*4, stream);
        k_kern<<<N_TOT*16/256, 256, 0, stream>>>(tD, tI, inv2s2, kern, deg);
        k_dis<<<N_TOT/256, 256, 0, stream>>>(deg, dis);
        k_wedge<<<N_TOT*16/256, 256, 0, stream>>>(kern, tI, dis, wout);
        hipMemsetAsync(cnt, 0, N_TOT*4, stream);
        k_count<<<N_TOT*16/256, 256, 0, stream>>>(tI, cnt);
        k_scan<<<1, 1024, 0, stream>>>(cnt, rowstart);
        hipMemsetAsync(c2, 0, N_TOT*4, stream);
        k_fill<<<N_TOT*16/256, 256, 0, stream>>>(tI, kern, dis, rowstart, c2, in_src, in_w);
        // P = H @ Bmat via split-bf16 MFMA (Z dead now; P/preS overlay Z)
        k_split<<<(int)(((long)N_TOT*d)/(256*8)), 256, 0, stream>>>(H, Hh, Hl, (long)N_TOT*d);
        k_prepT<<<dim3(4, d/64), 256, 0, stream>>>(Bmat, BTh, BTl, d);
        k_hb<<<dim3(2, N_TOT/128), 256, 0, stream>>>(Hh, Hl, BTh, BTl, P, d);
        // preS = ALPHA * adj @ P via tiled split-bf16 MFMA (K-split + reduce)
        k_prepT<<<dim3(4, N_TOT/64), 256, 0, stream>>>(P, PTsh, PTsl, N_TOT);
        k_adjP3<<<dim3(2, N_TOT/64, KS), 256, 0, stream>>>(adj, PTsh, PTsl, part);
        k_adjred<<<(N_TOT*256)/(256*4), 256, 0, stream>>>(part, preS, ALPHA);
        k_spmm_tanh<<<N_TOT, 256, 0, stream>>>(P, preS, wout, tI, dis, rowstart,
                                               in_src, in_w, outBuf);
    };

    run_stage(x, 512, w1, out1);
    k_wsym<<<256, 256, 0, stream>>>(w2, w2s);
    run_stage(out1, 256, w2s, (float*)d_out);
}

// Round 16
// 4841.851 us; speedup vs baseline: 1.4597x; 1.0020x over previous
//
#include <hip/hip_runtime.h>
#include <math.h>
#include <float.h>

#define N_TOT 8192
#define KNB 16
#define ALPHA 0.5f
#define PROWS 2048           // d2 panel rows
#define NCH 8                // split-K chunks for A = H^T H
#define KS 8                 // split-K slabs for adj @ P

typedef short bf16x8 __attribute__((ext_vector_type(8)));
typedef float f32x4 __attribute__((ext_vector_type(4)));

__device__ inline unsigned short f2bf(float f) {
    unsigned u = __float_as_uint(f);
    u += 0x7fffu + ((u >> 16) & 1u);
    return (unsigned short)(u >> 16);
}
__device__ inline float bf2f(unsigned short h) {
    return __uint_as_float(((unsigned)h) << 16);
}

// ---------------------------------------------------------------------------
// Apart[ch] = H[ch-slice]^T H[ch-slice]  (f64 partials, f32 32-row inner)
__global__ __launch_bounds__(256)
void k_ata2(const float* __restrict__ H, double* __restrict__ Apart, int d) {
    __shared__ float Ha[32][33], Hb[32][33];
    int tid = threadIdx.x, tx = tid&15, ty = tid>>4;
    int a0 = blockIdx.y*32, b0 = blockIdx.x*32;
    int n0b = blockIdx.z*(N_TOT/NCH);
    int lrow = tid>>3, lseg = tid&7;
    double acc[2][2];
    acc[0][0]=acc[0][1]=acc[1][0]=acc[1][1]=0.0;
    for (int n0 = n0b; n0 < n0b + N_TOT/NCH; n0 += 32) {
        float4 va = *(const float4*)&H[(long)(n0+lrow)*d + a0 + lseg*4];
        float4 vb = *(const float4*)&H[(long)(n0+lrow)*d + b0 + lseg*4];
        __syncthreads();
        Ha[lrow][lseg*4+0]=va.x; Ha[lrow][lseg*4+1]=va.y;
        Ha[lrow][lseg*4+2]=va.z; Ha[lrow][lseg*4+3]=va.w;
        Hb[lrow][lseg*4+0]=vb.x; Hb[lrow][lseg*4+1]=vb.y;
        Hb[lrow][lseg*4+2]=vb.z; Hb[lrow][lseg*4+3]=vb.w;
        __syncthreads();
        float f00=0.f,f01=0.f,f10=0.f,f11=0.f;
        #pragma unroll
        for (int nn = 0; nn < 32; ++nn) {
            float a0v = Ha[nn][ty*2], a1v = Ha[nn][ty*2+1];
            float b0v = Hb[nn][tx*2], b1v = Hb[nn][tx*2+1];
            f00 = fmaf(a0v,b0v,f00); f01 = fmaf(a0v,b1v,f01);
            f10 = fmaf(a1v,b0v,f10); f11 = fmaf(a1v,b1v,f11);
        }
        acc[0][0]+= (double)f00; acc[0][1]+= (double)f01;
        acc[1][0]+= (double)f10; acc[1][1]+= (double)f11;
    }
    long base = (long)blockIdx.z*d*d;
    #pragma unroll
    for (int i=0;i<2;++i)
        #pragma unroll
        for (int j=0;j<2;++j)
            Apart[base + (long)(a0+ty*2+i)*d + b0+tx*2+j] = acc[i][j];
}

// A = beta*I + sum_ch Apart[ch]   (deterministic in-order reduce)
__global__ __launch_bounds__(256)
void k_atared(const double* __restrict__ Apart, double* __restrict__ A,
              int d, double beta) {
    long idx = (long)blockIdx.x*256 + threadIdx.x;
    long dd = (long)d*d;
    double s = 0.0;
    for (int ch = 0; ch < NCH; ++ch) s += Apart[ch*dd + idx];
    int r = (int)(idx / d), c = (int)(idx % d);
    A[idx] = s + ((r==c) ? beta : 0.0);
}

// ---------------------------------------------------------------------------
// Single-wave Cholesky of the 64x64 diagonal panel.
__global__ __launch_bounds__(64)
void k_chol_diag(double* __restrict__ A, int d, int p0) {
    __shared__ double Ad[64][65];
    int r = threadIdx.x;
    for (int idx = r; idx < 64*64; idx += 64)
        Ad[idx>>6][idx&63] = A[(long)(p0+(idx>>6))*d + p0+(idx&63)];
    __syncthreads();
    for (int j = 0; j < 64; ++j) {
        double pj = sqrt(Ad[j][j]);
        double lrj = Ad[r][j] / pj;
        __syncthreads();
        if (r > j) Ad[r][j] = lrj;
        else if (r == j) Ad[j][j] = pj;
        __syncthreads();
        if (r > j)
            for (int k = j+1; k <= r; ++k)
                Ad[r][k] -= lrj * Ad[k][j];
        __syncthreads();
    }
    for (int idx = r; idx < 64*64; idx += 64) {
        int i = idx>>6, c = idx&63;
        A[(long)(p0+i)*d + p0+c] = (c <= i) ? Ad[i][c] : 0.0;
    }
}

__global__ __launch_bounds__(256)
void k_trsm(double* __restrict__ A, int d, int p0) {
    __shared__ double Lp[64][65];
    __shared__ double dg[64];
    int tid = threadIdx.x;
    for (int idx = tid; idx < 64*64; idx += 256) {
        int j = idx>>6, k = idx&63;
        double v = A[(long)(p0+j)*d + p0+k];
        Lp[j][k] = (j > k) ? v : 0.0;
        if (j == k) dg[j] = v;
    }
    __syncthreads();
    int r = p0 + 64 + blockIdx.x*256 + tid;
    if (r >= d) return;
    double* Ar = &A[(long)r*d + p0];
    double v[64];
    #pragma unroll
    for (int j = 0; j < 64; ++j) v[j] = Ar[j];
    #pragma unroll
    for (int k = 0; k < 64; ++k) {
        double lr = v[k] / dg[k];
        Ar[k] = lr;
        #pragma unroll
        for (int j = 0; j < 64; ++j) v[j] -= lr * Lp[j][k];
    }
}

__global__ __launch_bounds__(256)
void k_syrk(double* __restrict__ A, int d, int p0) {
    int t0 = p0 + 64;
    int r0 = t0 + blockIdx.y*64, c0 = t0 + blockIdx.x*64;
    __shared__ double Lr[64][33], Lc[64][33];
    int tid = threadIdx.x, tx = tid&15, ty = tid>>4;
    double acc[16];
    #pragma unroll
    for (int i=0;i<16;++i) acc[i]=0.0;
    for (int kc = 0; kc < 64; kc += 32) {
        for (int idx = tid; idx < 64*32; idx += 256) {
            int i = idx>>5, k = idx&31;
            Lr[i][k] = A[(long)(r0+i)*d + p0+kc+k];
            Lc[i][k] = A[(long)(c0+i)*d + p0+kc+k];
        }
        __syncthreads();
        for (int k = 0; k < 32; ++k) {
            double a[4], b[4];
            #pragma unroll
            for (int i=0;i<4;++i){ a[i]=Lr[ty*4+i][k]; b[i]=Lc[tx*4+i][k]; }
            #pragma unroll
            for (int i=0;i<4;++i)
                #pragma unroll
                for (int j=0;j<4;++j) acc[i*4+j] += a[i]*b[j];
        }
        __syncthreads();
    }
    #pragma unroll
    for (int i=0;i<4;++i)
        #pragma unroll
        for (int j=0;j<4;++j)
            A[(long)(r0+ty*4+i)*d + (c0+tx*4+j)] -= acc[i*4+j];
}

// ---------------------------------------------------------------------------
__global__ __launch_bounds__(64)
void k_dinv(const double* __restrict__ A, double* __restrict__ X, int d) {
    __shared__ double Lb[64][65];
    __shared__ double Yb[64][65];
    int b = blockIdx.x, c = threadIdx.x;
    for (int r = 0; r < 64; ++r) Lb[r][c] = A[(long)(b*64+r)*d + b*64+c];
    for (int r = 0; r < 64; ++r) Yb[r][c] = 0.0;
    __syncthreads();
    for (int i = 0; i < 64; ++i) {
        double s = (i==c) ? 1.0 : 0.0;
        for (int k = 0; k < i; ++k) s -= Lb[i][k]*Yb[k][c];
        Yb[i][c] = s / Lb[i][i];
    }
    __syncthreads();
    for (int r = 0; r < 64; ++r) X[(long)(b*64+r)*d + b*64+c] = Yb[r][c];
}

// X_{ij} = -X_{ii} * sum_{k=j}^{i-1} L_{ik} X_{kj},  i = j + lev.
__global__ __launch_bounds__(256)
void k_xoff(const double* __restrict__ A, double* __restrict__ X, int d, int lev) {
    __shared__ double Lb[64][65];
    __shared__ double Xb[64][65];
    __shared__ double Sb[64][65];
    int j = blockIdx.x, i = j + lev;
    int tid = threadIdx.x, tx = tid&15, ty = tid>>4;
    double acc[4][4];
    #pragma unroll
    for (int m=0;m<4;++m)
        #pragma unroll
        for (int n=0;n<4;++n) acc[m][n]=0.0;
    for (int k = j; k < i; ++k) {
        __syncthreads();
        for (int idx = tid; idx < 64*64; idx += 256) {
            int r = idx>>6, cc = idx&63;
            Lb[r][cc] = A[(long)(i*64+r)*d + k*64+cc];
            Xb[r][cc] = X[(long)(k*64+r)*d + j*64+cc];
        }
        __syncthreads();
        for (int kk = 0; kk < 64; ++kk) {
            double a_[4], b_[4];
            #pragma unroll
            for (int m=0;m<4;++m) a_[m] = Lb[ty*4+m][kk];
            #pragma unroll
            for (int n=0;n<4;++n) b_[n] = Xb[kk][tx*4+n];
            #pragma unroll
            for (int m=0;m<4;++m)
                #pragma unroll
                for (int n=0;n<4;++n) acc[m][n] += a_[m]*b_[n];
        }
    }
    __syncthreads();
    #pragma unroll
    for (int m=0;m<4;++m)
        #pragma unroll
        for (int n=0;n<4;++n) Sb[ty*4+m][tx*4+n] = acc[m][n];
    for (int idx = tid; idx < 64*64; idx += 256) {
        int r = idx>>6, cc = idx&63;
        Lb[r][cc] = X[(long)(i*64+r)*d + i*64+cc];   // X_{ii}
    }
    __syncthreads();
    #pragma unroll
    for (int m=0;m<4;++m)
        #pragma unroll
        for (int n=0;n<4;++n) acc[m][n]=0.0;
    for (int kk = 0; kk < 64; ++kk) {
        double a_[4], b_[4];
        #pragma unroll
        for (int m=0;m<4;++m) a_[m] = Lb[ty*4+m][kk];
        #pragma unroll
        for (int n=0;n<4;++n) b_[n] = Sb[kk][tx*4+n];
        #pragma unroll
        for (int m=0;m<4;++m)
            #pragma unroll
            for (int n=0;n<4;++n) acc[m][n] += a_[m]*b_[n];
    }
    #pragma unroll
    for (int m=0;m<4;++m)
        #pragma unroll
        for (int n=0;n<4;++n)
            X[(long)(i*64+ty*4+m)*d + j*64+tx*4+n] = -acc[m][n];
}

// W = X^T with upper-of-X forced to zero.
__global__ __launch_bounds__(256)
void k_wtr(const double* __restrict__ X, double* __restrict__ W, int d, int shift) {
    int idx = blockIdx.x*256 + threadIdx.x;
    int k = idx >> shift, c = idx & (d-1);
    W[idx] = (k <= c) ? X[(long)c*d + k] : 0.0;
}

// Z = H @ W  (f32 in, f64 W, f64 accumulate, f32 out)
__global__ __launch_bounds__(256)
void k_hw(const float* __restrict__ H, const double* __restrict__ W,
          float* __restrict__ Z, int d) {
    __shared__ __align__(16) float Ht[32][68];
    __shared__ double Wt[32][66];
    int tid = threadIdx.x, tx = tid&15, ty = tid>>4;
    int r0 = blockIdx.y*64, c0 = blockIdx.x*64;
    double acc[4][4];
    #pragma unroll
    for (int i=0;i<4;++i)
        #pragma unroll
        for (int j=0;j<4;++j) acc[i][j]=0.0;
    for (int k0 = 0; k0 < d; k0 += 32) {
        {
            int row = tid>>2, koff = (tid&3)*8;
            const float* src = &H[(long)(r0+row)*d + k0+koff];
            float4 v0 = *(const float4*)src, v1 = *(const float4*)(src+4);
            Ht[koff+0][row]=v0.x; Ht[koff+1][row]=v0.y; Ht[koff+2][row]=v0.z; Ht[koff+3][row]=v0.w;
            Ht[koff+4][row]=v1.x; Ht[koff+5][row]=v1.y; Ht[koff+6][row]=v1.z; Ht[koff+7][row]=v1.w;
        }
        {
            int k = tid>>3, coff = (tid&7)*8;
            const double* src = &W[(long)(k0+k)*d + c0+coff];
            #pragma unroll
            for (int q=0;q<8;++q) Wt[k][coff+q] = src[q];
        }
        __syncthreads();
        #pragma unroll
        for (int k = 0; k < 32; ++k) {
            float4 av = *(const float4*)&Ht[k][ty*4];
            double a0=av.x, a1=av.y, a2=av.z, a3=av.w;
            double b[4];
            #pragma unroll
            for (int j=0;j<4;++j) b[j] = Wt[k][tx*4+j];
            #pragma unroll
            for (int j=0;j<4;++j) {
                acc[0][j] += a0*b[j]; acc[1][j] += a1*b[j];
                acc[2][j] += a2*b[j]; acc[3][j] += a3*b[j];
            }
        }
        __syncthreads();
    }
    #pragma unroll
    for (int i=0;i<4;++i)
        #pragma unroll
        for (int j=0;j<4;++j)
            Z[(long)(r0+ty*4+i)*d + c0+tx*4+j] = (float)acc[i][j];
}

__global__ __launch_bounds__(256)
void k_sq(const float* __restrict__ Z, float* __restrict__ sq, int d) {
    int row = blockIdx.x*4 + (threadIdx.x>>6);
    int lane = threadIdx.x&63;
    const float* z = &Z[(long)row*d];
    double s = 0.0;
    for (int c = lane; c < d; c += 64) { float v = z[c]; s += (double)v*v; }
    #pragma unroll
    for (int off=32; off>0; off>>=1) s += __shfl_down(s, off);
    if (lane==0) sq[row] = (float)s;
}

// f32 -> bf16 (round-to-nearest), single output
__global__ __launch_bounds__(256)
void k_bf16(const float* __restrict__ Z, unsigned short* __restrict__ Zh, long n) {
    long i = ((long)blockIdx.x*256 + threadIdx.x)*8;
    if (i >= n) return;
    float4 v0 = *(const float4*)&Z[i], v1 = *(const float4*)&Z[i+4];
    float z[8] = {v0.x,v0.y,v0.z,v0.w,v1.x,v1.y,v1.z,v1.w};
    __align__(16) unsigned short h[8];
    #pragma unroll
    for (int j=0;j<8;++j) h[j] = f2bf(z[j]);
    *(uint4*)&Zh[i] = *(const uint4*)h;
}

// f32 -> bf16 h + l split (linear layout)
__global__ __launch_bounds__(256)
void k_split(const float* __restrict__ in, unsigned short* __restrict__ ho,
             unsigned short* __restrict__ lo, long n) {
    long i = ((long)blockIdx.x*256 + threadIdx.x)*8;
    if (i >= n) return;
    float4 v0 = *(const float4*)&in[i], v1 = *(const float4*)&in[i+4];
    float z[8] = {v0.x,v0.y,v0.z,v0.w,v1.x,v1.y,v1.z,v1.w};
    __align__(16) unsigned short h[8], l[8];
    #pragma unroll
    for (int j=0;j<8;++j) {
        h[j] = f2bf(z[j]);
        l[j] = f2bf(z[j] - bf2f(h[j]));
    }
    *(uint4*)&ho[i] = *(const uint4*)h;
    *(uint4*)&lo[i] = *(const uint4*)l;
}

// ---------------------------------------------------------------------------
// d2 panel GEMM: d2[r - prow0][c] = sq_r + sq_c - 2*(Zh_r . Zh_c), bf16 MFMA.
__global__ __launch_bounds__(256)
void k_gram(const unsigned short* __restrict__ Zh, const float* __restrict__ sq,
            float* __restrict__ d2, int d, int prow0) {
    __shared__ unsigned short At[128*64], Bt[128*64];
    int tid = threadIdx.x, w = tid>>6, lane = tid&63;
    int lr = lane&15, kg = lane>>4;
    int wr = w>>1, wc = w&1;
    int r0 = prow0 + blockIdx.y*128;
    int c0 = blockIdx.x*128;
    f32x4 acc[4][4];
    #pragma unroll
    for (int m=0;m<4;++m)
        #pragma unroll
        for (int n=0;n<4;++n) acc[m][n] = (f32x4){0.f,0.f,0.f,0.f};

    for (int k0 = 0; k0 < d; k0 += 64) {
        __syncthreads();
        #pragma unroll
        for (int ii=0; ii<4; ++ii) {
            int rbase = w*32 + ii*8;
            int grow = rbase + (lane>>3);
            int gg = (lane&7) ^ (grow&7);
            __builtin_amdgcn_global_load_lds((const void*)&Zh[(long)(r0+grow)*d + k0 + gg*8],
                                             (void*)&At[rbase*64], 16, 0, 0);
            __builtin_amdgcn_global_load_lds((const void*)&Zh[(long)(c0+grow)*d + k0 + gg*8],
                                             (void*)&Bt[rbase*64], 16, 0, 0);
        }
        __syncthreads();
        #pragma unroll
        for (int ks=0; ks<2; ++ks) {
            int gsw = ((ks<<2)|kg) ^ (lr&7);
            bf16x8 a_[4];
            #pragma unroll
            for (int m=0;m<4;++m) a_[m] = *(const bf16x8*)&At[(wr*64+m*16+lr)*64 + gsw*8];
            #pragma unroll
            for (int n=0;n<4;++n) {
                bf16x8 b_ = *(const bf16x8*)&Bt[(wc*64+n*16+lr)*64 + gsw*8];
                #pragma unroll
                for (int m=0;m<4;++m)
                    acc[m][n] = __builtin_amdgcn_mfma_f32_16x16x32_bf16(a_[m], b_, acc[m][n], 0,0,0);
            }
        }
    }
    float sr[4][4];
    #pragma unroll
    for (int m=0;m<4;++m)
        #pragma unroll
        for (int q=0;q<4;++q) sr[m][q] = sq[r0 + wr*64 + m*16 + kg*4 + q];
    #pragma unroll
    for (int n=0;n<4;++n) {
        int col = c0 + wc*64 + n*16 + lr;
        float sc = sq[col];
        #pragma unroll
        for (int m=0;m<4;++m) {
            int rloc = (r0 - prow0) + wr*64 + m*16 + kg*4;
            #pragma unroll
            for (int q=0;q<4;++q)
                d2[(long)(rloc+q)*N_TOT + col] = sr[m][q] + sc - 2.f*acc[m][n][q];
        }
    }
}

// Per-row exact top-32: per-wave zero-barrier radix select (shfl-only),
// then wave-0 REGISTER merge (radix + prefix-sum writes, no serial sort).
__global__ __launch_bounds__(512)
void k_sel(const float* __restrict__ d2, int* __restrict__ tI32, int prow0) {
    __shared__ int   wcnt[8];
    __shared__ float cbv[8][96];   // monotone-uint bits stored as float
    __shared__ int   cbi[8][96];
    __shared__ int   tieIdx[64];
    int tid = threadIdx.x, w = tid>>6, lane = tid&63;
    int row = blockIdx.x;
    const float* rp = &d2[(long)row*N_TOT];
    unsigned u[16];
    #pragma unroll
    for (int j=0;j<4;++j) {
        float4 q = *(const float4*)&rp[j*2048 + tid*4];
        float z[4] = {q.x, q.y, q.z, q.w};
        #pragma unroll
        for (int e=0;e<4;++e) {
            unsigned b = __float_as_uint(z[e]);
            u[j*4+e] = (b & 0x80000000u) ? ~b : (b | 0x80000000u);
        }
    }
    if (lane == 0) wcnt[w] = 0;
    unsigned p = 0;
    for (int b = 31; b >= 0; --b) {
        unsigned t = p | (1u<<b);
        int c = 0;
        #pragma unroll
        for (int i=0;i<16;++i) c += (u[i] < t) ? 1 : 0;
        #pragma unroll
        for (int off=32; off>0; off>>=1) c += __shfl_xor(c, off);
        if (c < 32) p = t;
    }
    #pragma unroll
    for (int i=0;i<16;++i) {
        if (u[i] <= p) {
            int pos = atomicAdd(&wcnt[w], 1);
            if (pos < 96) {
                cbv[w][pos] = __uint_as_float(u[i]);
                cbi[w][pos] = (i>>2)*2048 + tid*4 + (i&3);
            }
        }
    }
    __syncthreads();
    if (w == 0) {
        int wb[9];
        wb[0] = 0;
        #pragma unroll
        for (int ww=0; ww<8; ++ww) {
            int c = wcnt[ww]; if (c > 96) c = 96;
            wb[ww+1] = wb[ww] + c;
        }
        int Mtot = wb[8];
        unsigned mu[12]; int mi[12];
        #pragma unroll
        for (int j=0;j<12;++j) {
            int cidx = lane + j*64;
            unsigned val = 0xFFFFFFFFu; int idx = 0x7fffffff;
            if (cidx < Mtot) {
                int ww = 0;
                #pragma unroll
                for (int q=1;q<8;++q) if (cidx >= wb[q]) ww = q;
                int off = cidx - wb[ww];
                val = __float_as_uint(cbv[ww][off]);
                idx = cbi[ww][off];
            }
            mu[j] = val; mi[j] = idx;
        }
        unsigned p32 = 0;
        for (int b = 31; b >= 0; --b) {
            unsigned t = p32 | (1u<<b);
            int c = 0;
            #pragma unroll
            for (int j=0;j<12;++j) c += (mu[j] < t) ? 1 : 0;
            #pragma unroll
            for (int off=32; off>0; off>>=1) c += __shfl_xor(c, off);
            if (c < 32) p32 = t;
        }
        long rg = (long)(prow0 + row);
        int myA = 0, myT = 0;
        #pragma unroll
        for (int j=0;j<12;++j) {
            myA += (mu[j] < p32) ? 1 : 0;
            myT += (mu[j] == p32) ? 1 : 0;
        }
        int incA = myA;
        #pragma unroll
        for (int off=1; off<64; off<<=1) {
            int t = __shfl_up(incA, off);
            if (lane >= off) incA += t;
        }
        int preA = incA - myA;
        int m1 = __shfl(incA, 63);
        int incT = myT;
        #pragma unroll
        for (int off=1; off<64; off<<=1) {
            int t = __shfl_up(incT, off);
            if (lane >= off) incT += t;
        }
        int preT = incT - myT;
        int tn = __shfl(incT, 63); if (tn > 64) tn = 64;
        int ka = 0, kt = 0;
        #pragma unroll
        for (int j=0;j<12;++j) {
            if (mu[j] < p32) {
                tI32[rg*32 + preA + ka] = mi[j]; ++ka;
            } else if (mu[j] == p32) {
                if (preT + kt < 64) tieIdx[preT + kt] = mi[j];
                ++kt;
            }
        }
        __builtin_amdgcn_wave_barrier();
        if (lane == 0) {
            int need = 32 - m1;
            for (int s = 0; s < need; ++s) {
                int best = 0x7fffffff, bj = -1;
                for (int t = 0; t < tn; ++t) {
                    int v = tieIdx[t];
                    if (v < best) { best = v; bj = t; }
                }
                tI32[rg*32 + m1 + s] = best;
                if (bj >= 0) tieIdx[bj] = 0x7fffffff;
            }
        }
    }
}

// Phase 2: exact f32 d2 for the 32 global candidates; exact top-16 + sigma.
// One block per row; wave wv handles candidates 8wv..8wv+7 with 4-way ILP.
template<int D>
__global__ __launch_bounds__(256)
void k_refine(const float* __restrict__ Z, const float* __restrict__ sq,
              const int* __restrict__ tI32,
              float* __restrict__ tD, int* __restrict__ tI, double* sig_accum) {
    __shared__ float rD[32];
    __shared__ int   rI[32];
    __shared__ float bD[17];
    __shared__ int   bI[17];
    int wv = threadIdx.x>>6, lane = threadIdx.x&63;
    long row = blockIdx.x;
    float zi[D/64];
    #pragma unroll
    for (int t=0;t<D/64;++t) zi[t] = Z[row*D + t*64 + lane];
    float sqi = sq[row];
    #pragma unroll
    for (int cg = 0; cg < 8; cg += 4) {
        int cbase = wv*8 + cg;
        int j0 = tI32[row*32 + cbase + 0];
        int j1 = tI32[row*32 + cbase + 1];
        int j2 = tI32[row*32 + cbase + 2];
        int j3 = tI32[row*32 + cbase + 3];
        float d0 = 0.f, d1 = 0.f, d2v = 0.f, d3 = 0.f;
        #pragma unroll
        for (int t=0;t<D/64;++t) {
            d0  = fmaf(zi[t], Z[(long)j0*D + t*64 + lane], d0);
            d1  = fmaf(zi[t], Z[(long)j1*D + t*64 + lane], d1);
            d2v = fmaf(zi[t], Z[(long)j2*D + t*64 + lane], d2v);
            d3  = fmaf(zi[t], Z[(long)j3*D + t*64 + lane], d3);
        }
        #pragma unroll
        for (int off=32; off>0; off>>=1) {
            d0  += __shfl_xor(d0, off);
            d1  += __shfl_xor(d1, off);
            d2v += __shfl_xor(d2v, off);
            d3  += __shfl_xor(d3, off);
        }
        if (lane == 0) {
            rD[cbase+0] = sqi + sq[j0] - 2.f*d0;  rI[cbase+0] = j0;
            rD[cbase+1] = sqi + sq[j1] - 2.f*d1;  rI[cbase+1] = j1;
            rD[cbase+2] = sqi + sq[j2] - 2.f*d2v; rI[cbase+2] = j2;
            rD[cbase+3] = sqi + sq[j3] - 2.f*d3;  rI[cbase+3] = j3;
        }
    }
    __syncthreads();
    if (threadIdx.x == 0) {
        #pragma unroll
        for (int k=0;k<16;++k){ bD[k]=FLT_MAX; bI[k]=0x7fffffff; }
        for (int c = 0; c < 32; ++c) {
            float dv = rD[c]; int ci = rI[c];
            float wd = bD[15]; int wi = bI[15];
            if (dv < wd || (dv == wd && ci < wi)) {
                int pos = 15;
                while (pos > 0) {
                    float pd_ = bD[pos-1]; int pi_ = bI[pos-1];
                    if (dv < pd_ || (dv == pd_ && ci < pi_)) {
                        bD[pos]=pd_; bI[pos]=pi_; --pos;
                    } else break;
                }
                bD[pos]=dv; bI[pos]=ci;
            }
        }
        double ps = 0.0;
        #pragma unroll
        for (int k=0;k<16;++k) {
            float dv = bD[k];
            tD[row*16+k] = dv; tI[row*16+k] = bI[k];
            ps += sqrt((double)fmaxf(dv, 0.f));
        }
        atomicAdd(sig_accum, ps);
    }
}

__global__ void k_sigfin(const double* __restrict__ sig_accum, float* __restrict__ inv2s2) {
    double s = sig_accum[0] / (double)(N_TOT*KNB);
    inv2s2[0] = (float)(1.0/(2.0*s*s));
}

__global__ __launch_bounds__(256)
void k_kern(const float* __restrict__ tD, const int* __restrict__ tI,
            const float* __restrict__ inv2s2,
            float* __restrict__ kern, float* __restrict__ deg) {
    int e = blockIdx.x*256 + threadIdx.x;
    int i = e>>4;
    float d2 = fmaxf(tD[e], 0.f);
    float kv = expf(-d2 * inv2s2[0]);
    kern[e] = kv;
    atomicAdd(&deg[i], 0.5f*kv);
    atomicAdd(&deg[tI[e]], 0.5f*kv);
}

__global__ __launch_bounds__(256)
void k_dis(const float* __restrict__ deg, float* __restrict__ dis) {
    int i = blockIdx.x*256 + threadIdx.x;
    float v = deg[i];
    dis[i] = (v > 0.f) ? (1.0f/sqrtf(v)) : 0.f;
}

// wout[e] = 0.5 * kern[e] * dis[tI[e]]
__global__ __launch_bounds__(256)
void k_wedge(const float* __restrict__ kern, const int* __restrict__ tI,
             const float* __restrict__ dis, float* __restrict__ wout) {
    int e = blockIdx.x*256 + threadIdx.x;
    wout[e] = 0.5f * kern[e] * dis[tI[e]];
}

__global__ __launch_bounds__(256)
void k_count(const int* __restrict__ tI, int* __restrict__ cnt) {
    int e = blockIdx.x*256 + threadIdx.x;
    atomicAdd(&cnt[tI[e]], 1);
}

__global__ __launch_bounds__(1024)
void k_scan(const int* __restrict__ cnt, int* __restrict__ rowstart) {
    __shared__ int buf[1024];
    __shared__ int carry;
    int tid = threadIdx.x;
    if (tid==0) carry = 0;
    __syncthreads();
    for (int base = 0; base < N_TOT; base += 1024) {
        int v = cnt[base+tid];
        buf[tid]=v; __syncthreads();
        for (int off=1; off<1024; off<<=1) {
            int t = (tid>=off)? buf[tid-off] : 0; __syncthreads();
            buf[tid]+=t; __syncthreads();
        }
        rowstart[base+tid] = carry + buf[tid] - v;
        __syncthreads();
        if (tid==1023) carry += buf[1023];
        __syncthreads();
    }
    if (tid==0) rowstart[N_TOT] = carry;
}

// in-edge weights premultiplied: in_w[dst] = 0.5*kern[e]*dis[src_row]
__global__ __launch_bounds__(256)
void k_fill(const int* __restrict__ tI, const float* __restrict__ kern,
            const float* __restrict__ dis,
            const int* __restrict__ rowstart, int* __restrict__ c2,
            int* __restrict__ in_src, float* __restrict__ in_w) {
    int e = blockIdx.x*256 + threadIdx.x;
    int i = e>>4;
    int j = tI[e];
    int pos = atomicAdd(&c2[j], 1);
    int dst = rowstart[j] + pos;
    in_src[dst] = i; in_w[dst] = 0.5f*kern[e]*dis[i];
}

// src[rows up to 8192][256] f32 -> Th/Tl [256][outStride] bf16 split,
// transposed AND pre-swizzled within each 64-chunk of the out row.
__global__ __launch_bounds__(256)
void k_prepT(const float* __restrict__ S, unsigned short* __restrict__ Th,
             unsigned short* __restrict__ Tl, int outStride) {
    __shared__ float tile[64][65];
    int r0 = blockIdx.y*64;   // S rows (k-dim), 64-aligned chunk
    int c0 = blockIdx.x*64;   // S cols
    int t = threadIdx.x;
    {
        int row = t>>2, cseg = t&3;
        #pragma unroll
        for (int i=0;i<4;++i) {
            float4 v = *(const float4*)&S[(long)(r0+row)*256 + c0 + cseg*16 + i*4];
            tile[row][cseg*16+i*4+0]=v.x; tile[row][cseg*16+i*4+1]=v.y;
            tile[row][cseg*16+i*4+2]=v.z; tile[row][cseg*16+i*4+3]=v.w;
        }
    }
    __syncthreads();
    {
        int col = t>>2, rseg = t&3;
        int c = c0 + col;
        __align__(16) unsigned short hs[16], ls[16];
        #pragma unroll
        for (int i=0;i<16;++i) {
            float z = tile[rseg*16+i][col];
            hs[i] = f2bf(z);
            ls[i] = f2bf(z - bf2f(hs[i]));
        }
        #pragma unroll
        for (int half=0; half<2; ++half) {
            int gl = rseg*2 + half;
            int gs = gl ^ (c&7);
            long dst = (long)c*outStride + r0 + gs*8;
            *(uint4*)&Th[dst] = *(const uint4*)&hs[half*8];
            *(uint4*)&Tl[dst] = *(const uint4*)&ls[half*8];
        }
    }
}

// P = H @ Bmat via split-bf16 MFMA. A = Hh/Hl [8192][d] linear (source-XOR
// staged); B = BTh/BTl [256][d] pre-swizzled. grid (2, 64), 4 waves.
__global__ __launch_bounds__(256)
void k_hb(const unsigned short* __restrict__ Hh, const unsigned short* __restrict__ Hl,
          const unsigned short* __restrict__ BTh, const unsigned short* __restrict__ BTl,
          float* __restrict__ C, int d) {
    __shared__ unsigned short Ah[128*64], Al[128*64], Bh[128*64], Bl[128*64];
    int tid = threadIdx.x, w = tid>>6, lane = tid&63;
    int lr = lane&15, kg = lane>>4;
    int wr = w>>1, wc = w&1;
    int r0 = blockIdx.y*128;
    int c0 = blockIdx.x*128;
    f32x4 acc[4][4];
    #pragma unroll
    for (int m=0;m<4;++m)
        #pragma unroll
        for (int n=0;n<4;++n) acc[m][n] = (f32x4){0.f,0.f,0.f,0.f};

    for (int k0 = 0; k0 < d; k0 += 64) {
        __syncthreads();
        #pragma unroll
        for (int ii=0; ii<4; ++ii) {
            int rbase = w*32 + ii*8;
            int grow = rbase + (lane>>3);
            int gg = (lane&7) ^ (grow&7);
            long asrc = (long)(r0+grow)*d + k0 + gg*8;
            __builtin_amdgcn_global_load_lds((const void*)&Hh[asrc], (void*)&Ah[rbase*64], 16, 0, 0);
            __builtin_amdgcn_global_load_lds((const void*)&Hl[asrc], (void*)&Al[rbase*64], 16, 0, 0);
            long bsrc = (long)(c0+grow)*d + k0 + (lane&7)*8;
            __builtin_amdgcn_global_load_lds((const void*)&BTh[bsrc], (void*)&Bh[rbase*64], 16, 0, 0);
            __builtin_amdgcn_global_load_lds((const void*)&BTl[bsrc], (void*)&Bl[rbase*64], 16, 0, 0);
        }
        __syncthreads();
        #pragma unroll
        for (int ks=0; ks<2; ++ks) {
            int gsw = ((ks<<2)|kg) ^ (lr&7);
            bf16x8 ah[4], al[4];
            #pragma unroll
            for (int m=0;m<4;++m) {
                ah[m] = *(const bf16x8*)&Ah[(wr*64+m*16+lr)*64 + gsw*8];
                al[m] = *(const bf16x8*)&Al[(wr*64+m*16+lr)*64 + gsw*8];
            }
            #pragma unroll
            for (int n=0;n<4;++n) {
                bf16x8 bh = *(const bf16x8*)&Bh[(wc*64+n*16+lr)*64 + gsw*8];
                bf16x8 bl = *(const bf16x8*)&Bl[(wc*64+n*16+lr)*64 + gsw*8];
                #pragma unroll
                for (int m=0;m<4;++m) {
                    acc[m][n] = __builtin_amdgcn_mfma_f32_16x16x32_bf16(ah[m], bh, acc[m][n], 0,0,0);
                    acc[m][n] = __builtin_amdgcn_mfma_f32_16x16x32_bf16(ah[m], bl, acc[m][n], 0,0,0);
                    acc[m][n] = __builtin_amdgcn_mfma_f32_16x16x32_bf16(al[m], bh, acc[m][n], 0,0,0);
                }
            }
        }
    }
    #pragma unroll
    for (int n=0;n<4;++n) {
        int col = c0 + wc*64 + n*16 + lr;
        #pragma unroll
        for (int m=0;m<4;++m) {
            int rg = r0 + wr*64 + m*16 + kg*4;
            #pragma unroll
            for (int q=0;q<4;++q)
                C[(long)(rg+q)*256 + col] = acc[m][n][q];
        }
    }
}

// part[ks] = adj[:, slab] @ P[slab, :]  (split-bf16 MFMA, K-split, T14
// reg-prefetch of adj). grid (2, 128, KS), block 256 (4 waves x 16 rows).
__global__ __launch_bounds__(256)
void k_adjP3(const float* __restrict__ adj, const unsigned short* __restrict__ PTsh,
             const unsigned short* __restrict__ PTsl, float* __restrict__ part) {
    __shared__ unsigned short Ah[64*64], Al[64*64];
    __shared__ unsigned short Bh[128*64], Bl[128*64];
    int tid = threadIdx.x, w = tid>>6, lane = tid&63;
    int lr = lane&15, kg = lane>>4;
    int r0 = blockIdx.y*64;
    int c0 = blockIdx.x*128;
    int kbeg = blockIdx.z*(N_TOT/KS), kend = kbeg + N_TOT/KS;
    f32x4 acc[8];
    #pragma unroll
    for (int fc=0; fc<8; ++fc) acc[fc] = (f32x4){0.f,0.f,0.f,0.f};

    int arow = tid>>2, aseg = tid&3;
    float4 va[4];
    {
        const float* asrc = &adj[(long)(r0+arow)*N_TOT + kbeg + aseg*16];
        #pragma unroll
        for (int i=0;i<4;++i) va[i] = *(const float4*)&asrc[i*4];
    }
    for (int k0 = kbeg; k0 < kend; k0 += 64) {
        __syncthreads();
        #pragma unroll
        for (int i=0;i<4;++i) {
            float z[4] = {va[i].x, va[i].y, va[i].z, va[i].w};
            __align__(8) unsigned short h[4], l[4];
            #pragma unroll
            for (int j=0;j<4;++j) {
                h[j] = f2bf(z[j]);
                l[j] = f2bf(z[j] - bf2f(h[j]));
            }
            int col = aseg*16 + i*4;
            int g = col>>3, sub = col&7;
            int off = arow*128 + ((g ^ (arow&7))*16) + sub*2;
            *(ushort4*)((char*)Ah + off) = *(const ushort4*)h;
            *(ushort4*)((char*)Al + off) = *(const ushort4*)l;
        }
        #pragma unroll
        for (int ii=0; ii<4; ++ii) {
            int rbase = w*32 + ii*8;
            int grow = rbase + (lane>>3);
            long src = (long)(c0+grow)*N_TOT + k0 + (lane&7)*8;
            __builtin_amdgcn_global_load_lds((const void*)&PTsh[src], (void*)&Bh[rbase*64], 16, 0, 0);
            __builtin_amdgcn_global_load_lds((const void*)&PTsl[src], (void*)&Bl[rbase*64], 16, 0, 0);
        }
        __syncthreads();
        if (k0 + 64 < kend) {
            const float* asrc = &adj[(long)(r0+arow)*N_TOT + k0 + 64 + aseg*16];
            #pragma unroll
            for (int i=0;i<4;++i) va[i] = *(const float4*)&asrc[i*4];
        }
        #pragma unroll
        for (int ks=0; ks<2; ++ks) {
            int gsw = ((ks<<2)|kg) ^ (lr&7);
            bf16x8 ah = *(const bf16x8*)&Ah[(w*16+lr)*64 + gsw*8];
            bf16x8 al = *(const bf16x8*)&Al[(w*16+lr)*64 + gsw*8];
            #pragma unroll
            for (int fc=0; fc<8; ++fc) {
                bf16x8 bh = *(const bf16x8*)&Bh[(fc*16+lr)*64 + gsw*8];
                bf16x8 bl = *(const bf16x8*)&Bl[(fc*16+lr)*64 + gsw*8];
                acc[fc] = __builtin_amdgcn_mfma_f32_16x16x32_bf16(ah, bh, acc[fc], 0,0,0);
                acc[fc] = __builtin_amdgcn_mfma_f32_16x16x32_bf16(ah, bl, acc[fc], 0,0,0);
                acc[fc] = __builtin_amdgcn_mfma_f32_16x16x32_bf16(al, bh, acc[fc], 0,0,0);
            }
        }
    }
    long base = (long)blockIdx.z*N_TOT*256;
    #pragma unroll
    for (int fc=0; fc<8; ++fc)
        #pragma unroll
        for (int q=0; q<4; ++q) {
            int rg = r0 + w*16 + kg*4 + q;
            int cg = c0 + fc*16 + lr;
            part[base + (long)rg*256 + cg] = acc[fc][q];
        }
}

// preS = scale * sum_ks part[ks]  (deterministic order)
__global__ __launch_bounds__(256)
void k_adjred(const float* __restrict__ part, float* __restrict__ preS, float scale) {
    long i4 = ((long)blockIdx.x*256 + threadIdx.x)*4;
    long n = (long)N_TOT*256;
    float sx=0.f, sy=0.f, sz=0.f, sw=0.f;
    for (int ch = 0; ch < KS; ++ch) {
        float4 a = *(const float4*)&part[(long)ch*n + i4];
        sx += a.x; sy += a.y; sz += a.z; sw += a.w;
    }
    float4 o; o.x = scale*sx; o.y = scale*sy; o.z = scale*sz; o.w = scale*sw;
    *(float4*)&preS[i4] = o;
}

__global__ __launch_bounds__(256)
void k_wsym(const float* __restrict__ w2, float* __restrict__ w2s) {
    int i = blockIdx.x, j = threadIdx.x;
    w2s[i*256+j] = 0.5f*(w2[i*256+j] + w2[j*256+i]);
}

// out[i][c] = tanh(preS + dis_i * (sum_out + sum_in)); 4-way ILP gather.
__global__ __launch_bounds__(256)
void k_spmm_tanh(const float* __restrict__ P, const float* __restrict__ preS,
                 const float* __restrict__ wout, const int* __restrict__ tI,
                 const float* __restrict__ dis, const int* __restrict__ rowstart,
                 const int* __restrict__ in_src, const float* __restrict__ in_w,
                 float* __restrict__ out) {
    int i = blockIdx.x, c = threadIdx.x;
    float a0=0.f, a1=0.f, a2=0.f, a3=0.f;
    #pragma unroll
    for (int k = 0; k < 16; k += 4) {
        int e = i*16+k;
        int j0 = tI[e+0], j1 = tI[e+1], j2 = tI[e+2], j3 = tI[e+3];
        float w0 = wout[e+0], w1 = wout[e+1], w2 = wout[e+2], w3 = wout[e+3];
        a0 = fmaf(w0, P[(long)j0*256 + c], a0);
        a1 = fmaf(w1, P[(long)j1*256 + c], a1);
        a2 = fmaf(w2, P[(long)j2*256 + c], a2);
        a3 = fmaf(w3, P[(long)j3*256 + c], a3);
    }
    int s0 = rowstart[i], s1 = rowstart[i+1];
    int t = s0;
    for (; t + 4 <= s1; t += 4) {
        int j0 = in_src[t+0], j1 = in_src[t+1], j2 = in_src[t+2], j3 = in_src[t+3];
        float w0 = in_w[t+0], w1 = in_w[t+1], w2 = in_w[t+2], w3 = in_w[t+3];
        a0 = fmaf(w0, P[(long)j0*256 + c], a0);
        a1 = fmaf(w1, P[(long)j1*256 + c], a1);
        a2 = fmaf(w2, P[(long)j2*256 + c], a2);
        a3 = fmaf(w3, P[(long)j3*256 + c], a3);
    }
    for (; t < s1; ++t)
        a0 = fmaf(in_w[t], P[(long)in_src[t]*256 + c], a0);
    float acc = (a0 + a1) + (a2 + a3);
    float pre = preS[(long)i*256+c] + dis[i]*acc;
    out[(long)i*256+c] = tanhf(pre);
}

// ---------------------------------------------------------------------------
extern "C" void kernel_launch(void* const* d_in, const int* in_sizes, int n_in,
                              void* d_out, int out_size, void* d_ws, size_t ws_size,
                              hipStream_t stream) {
    const float* x   = (const float*)d_in[0];
    const float* adj = (const float*)d_in[1];
    const float* w1  = (const float*)d_in[2];
    const float* w2  = (const float*)d_in[3];

    char* ws = (char*)d_ws;
    size_t off = 0;
    auto alloc = [&](size_t bytes){ size_t o = off; off += (bytes+255)&~(size_t)255; return o; };
    double* A      = (double*)(ws + alloc((size_t)512*512*8));
    double* W      = (double*)(ws + alloc((size_t)512*512*8));
    double* Xb     = (double*)(ws + alloc((size_t)512*512*8));
    double* Apart  = (double*)(ws + alloc((size_t)NCH*512*512*8));
    double* sigacc = (double*)(ws + alloc(256));
    float*  inv2s2 = (float*)(ws + alloc(256));
    float*  bigZ   = (float*)(ws + alloc((size_t)N_TOT*512*4));  // Z, then P/preS
    unsigned short* Zh   = (unsigned short*)(ws + alloc((size_t)N_TOT*512*2));
    unsigned short* Hh   = (unsigned short*)(ws + alloc((size_t)N_TOT*512*2));
    unsigned short* Hl   = (unsigned short*)(ws + alloc((size_t)N_TOT*512*2));
    unsigned short* BTh  = (unsigned short*)(ws + alloc((size_t)256*512*2));
    unsigned short* BTl  = (unsigned short*)(ws + alloc((size_t)256*512*2));
    unsigned short* PTsh = (unsigned short*)(ws + alloc((size_t)256*N_TOT*2));
    unsigned short* PTsl = (unsigned short*)(ws + alloc((size_t)256*N_TOT*2));
    float*  d2buf  = (float*)(ws + alloc((size_t)PROWS*N_TOT*4));   // 64 MB panel
    float*  part   = (float*)(ws + alloc((size_t)KS*N_TOT*256*4));  // 64 MB
    float*  sq     = (float*)(ws + alloc((size_t)N_TOT*4));
    int*    tI32   = (int*)  (ws + alloc((size_t)N_TOT*32*4));
    float*  tD     = (float*)(ws + alloc((size_t)N_TOT*16*4));
    int*    tI     = (int*)  (ws + alloc((size_t)N_TOT*16*4));
    float*  kern   = (float*)(ws + alloc((size_t)N_TOT*16*4));
    float*  wout   = (float*)(ws + alloc((size_t)N_TOT*16*4));
    float*  deg    = (float*)(ws + alloc((size_t)N_TOT*4));
    float*  dis    = (float*)(ws + alloc((size_t)N_TOT*4));
    int*    cnt    = (int*)  (ws + alloc((size_t)N_TOT*4));
    int*    rowstart=(int*)  (ws + alloc((size_t)(N_TOT+1)*4));
    int*    c2     = (int*)  (ws + alloc((size_t)N_TOT*4));
    int*    in_src = (int*)  (ws + alloc((size_t)N_TOT*16*4));
    float*  in_w   = (float*)(ws + alloc((size_t)N_TOT*16*4));
    float*  out1   = (float*)(ws + alloc((size_t)N_TOT*256*4));
    float*  w2s    = (float*)(ws + alloc((size_t)256*256*4));
    float*  P      = bigZ;                       // overlays Z after Z is dead
    float*  preS   = bigZ + (size_t)N_TOT*256;

    auto run_stage = [&](const float* H, int d, const float* Bmat, float* outBuf) {
        int nb = d/64;
        int shift = (d == 512) ? 9 : 8;
        k_ata2<<<dim3(d/32, d/32, NCH), 256, 0, stream>>>(H, Apart, d);
        k_atared<<<d*d/256, 256, 0, stream>>>(Apart, A, d, 1.0);
        for (int p0 = 0; p0 < d; p0 += 64) {
            k_chol_diag<<<1, 64, 0, stream>>>(A, d, p0);
            int rem = d - p0 - 64;
            if (rem > 0) {
                k_trsm<<<(rem+255)/256, 256, 0, stream>>>(A, d, p0);
                k_syrk<<<dim3(rem/64, rem/64), 256, 0, stream>>>(A, d, p0);
            }
        }
        // X = L^{-1} via blocked inversion; W = X^T
        k_dinv<<<nb, 64, 0, stream>>>(A, Xb, d);
        for (int lev = 1; lev < nb; ++lev)
            k_xoff<<<nb - lev, 256, 0, stream>>>(A, Xb, d, lev);
        k_wtr<<<d*d/256, 256, 0, stream>>>(Xb, W, d, shift);
        k_hw<<<dim3(d/64, N_TOT/64), 256, 0, stream>>>(H, W, bigZ, d);
        k_sq<<<N_TOT/4, 256, 0, stream>>>(bigZ, sq, d);
        k_bf16<<<(int)(((long)N_TOT*d)/(256*8)), 256, 0, stream>>>(bigZ, Zh, (long)N_TOT*d);
        for (int pr = 0; pr < N_TOT; pr += PROWS) {
            k_gram<<<dim3(N_TOT/128, PROWS/128), 256, 0, stream>>>(Zh, sq, d2buf, d, pr);
            k_sel<<<PROWS, 512, 0, stream>>>(d2buf, tI32, pr);
        }
        hipMemsetAsync(sigacc, 0, 8, stream);
        if (d == 512)
            k_refine<512><<<N_TOT, 256, 0, stream>>>(bigZ, sq, tI32, tD, tI, sigacc);
        else
            k_refine<256><<<N_TOT, 256, 0, stream>>>(bigZ, sq, tI32, tD, tI, sigacc);
        k_sigfin<<<1, 1, 0, stream>>>(sigacc, inv2s2);
        hipMemsetAsync(deg, 0, N_TOT*4, stream);
        k_kern<<<N_TOT*16/256, 256, 0, stream>>>(tD, tI, inv2s2, kern, deg);
        k_dis<<<N_TOT/256, 256, 0, stream>>>(deg, dis);
        k_wedge<<<N_TOT*16/256, 256, 0, stream>>>(kern, tI, dis, wout);
        hipMemsetAsync(cnt, 0, N_TOT*4, stream);
        k_count<<<N_TOT*16/256, 256, 0, stream>>>(tI, cnt);
        k_scan<<<1, 1024, 0, stream>>>(cnt, rowstart);
        hipMemsetAsync(c2, 0, N_TOT*4, stream);
        k_fill<<<N_TOT*16/256, 256, 0, stream>>>(tI, kern, dis, rowstart, c2, in_src, in_w);
        // P = H @ Bmat via split-bf16 MFMA (Z dead now; P/preS overlay Z)
        k_split<<<(int)(((long)N_TOT*d)/(256*8)), 256, 0, stream>>>(H, Hh, Hl, (long)N_TOT*d);
        k_prepT<<<dim3(4, d/64), 256, 0, stream>>>(Bmat, BTh, BTl, d);
        k_hb<<<dim3(2, N_TOT/128), 256, 0, stream>>>(Hh, Hl, BTh, BTl, P, d);
        // preS = ALPHA * adj @ P via tiled split-bf16 MFMA (K-split + reduce)
        k_prepT<<<dim3(4, N_TOT/64), 256, 0, stream>>>(P, PTsh, PTsl, N_TOT);
        k_adjP3<<<dim3(2, N_TOT/64, KS), 256, 0, stream>>>(adj, PTsh, PTsl, part);
        k_adjred<<<(N_TOT*256)/(256*4), 256, 0, stream>>>(part, preS, ALPHA);
        k_spmm_tanh<<<N_TOT, 256, 0, stream>>>(P, preS, wout, tI, dis, rowstart,
                                               in_src, in_w, outBuf);
    };

    run_stage(x, 512, w1, out1);
    k_wsym<<<256, 256, 0, stream>>>(w2, w2s);
    run_stage(out1, 256, w2s, (float*)d_out);
}

// Round 17
// 4748.891 us; speedup vs baseline: 1.4883x; 1.0196x over previous
//
#include <hip/hip_runtime.h>
#include <math.h>
#include <float.h>

#define N_TOT 8192
#define KNB 16
#define ALPHA 0.5f
#define PROWS 2048           // d2 panel rows
#define NCH 8                // split-K chunks for A = H^T H
#define KS 8                 // split-K slabs for adj @ P

typedef short bf16x8 __attribute__((ext_vector_type(8)));
typedef float f32x4 __attribute__((ext_vector_type(4)));

__device__ inline unsigned short f2bf(float f) {
    unsigned u = __float_as_uint(f);
    u += 0x7fffu + ((u >> 16) & 1u);
    return (unsigned short)(u >> 16);
}
__device__ inline float bf2f(unsigned short h) {
    return __uint_as_float(((unsigned)h) << 16);
}

// ---------------------------------------------------------------------------
// Apart[ch] = H[ch-slice]^T H[ch-slice]  (f64 partials, f32 32-row inner)
__global__ __launch_bounds__(256)
void k_ata2(const float* __restrict__ H, double* __restrict__ Apart, int d) {
    __shared__ float Ha[32][33], Hb[32][33];
    int tid = threadIdx.x, tx = tid&15, ty = tid>>4;
    int a0 = blockIdx.y*32, b0 = blockIdx.x*32;
    int n0b = blockIdx.z*(N_TOT/NCH);
    int lrow = tid>>3, lseg = tid&7;
    double acc[2][2];
    acc[0][0]=acc[0][1]=acc[1][0]=acc[1][1]=0.0;
    for (int n0 = n0b; n0 < n0b + N_TOT/NCH; n0 += 32) {
        float4 va = *(const float4*)&H[(long)(n0+lrow)*d + a0 + lseg*4];
        float4 vb = *(const float4*)&H[(long)(n0+lrow)*d + b0 + lseg*4];
        __syncthreads();
        Ha[lrow][lseg*4+0]=va.x; Ha[lrow][lseg*4+1]=va.y;
        Ha[lrow][lseg*4+2]=va.z; Ha[lrow][lseg*4+3]=va.w;
        Hb[lrow][lseg*4+0]=vb.x; Hb[lrow][lseg*4+1]=vb.y;
        Hb[lrow][lseg*4+2]=vb.z; Hb[lrow][lseg*4+3]=vb.w;
        __syncthreads();
        float f00=0.f,f01=0.f,f10=0.f,f11=0.f;
        #pragma unroll
        for (int nn = 0; nn < 32; ++nn) {
            float a0v = Ha[nn][ty*2], a1v = Ha[nn][ty*2+1];
            float b0v = Hb[nn][tx*2], b1v = Hb[nn][tx*2+1];
            f00 = fmaf(a0v,b0v,f00); f01 = fmaf(a0v,b1v,f01);
            f10 = fmaf(a1v,b0v,f10); f11 = fmaf(a1v,b1v,f11);
        }
        acc[0][0]+= (double)f00; acc[0][1]+= (double)f01;
        acc[1][0]+= (double)f10; acc[1][1]+= (double)f11;
    }
    long base = (long)blockIdx.z*d*d;
    #pragma unroll
    for (int i=0;i<2;++i)
        #pragma unroll
        for (int j=0;j<2;++j)
            Apart[base + (long)(a0+ty*2+i)*d + b0+tx*2+j] = acc[i][j];
}

// A = beta*I + sum_ch Apart[ch]   (deterministic in-order reduce)
__global__ __launch_bounds__(256)
void k_atared(const double* __restrict__ Apart, double* __restrict__ A,
              int d, double beta) {
    long idx = (long)blockIdx.x*256 + threadIdx.x;
    long dd = (long)d*d;
    double s = 0.0;
    for (int ch = 0; ch < NCH; ++ch) s += Apart[ch*dd + idx];
    int r = (int)(idx / d), c = (int)(idx % d);
    A[idx] = s + ((r==c) ? beta : 0.0);
}

// ---------------------------------------------------------------------------
// Single-wave Cholesky of the 64x64 diagonal panel.
__global__ __launch_bounds__(64)
void k_chol_diag(double* __restrict__ A, int d, int p0) {
    __shared__ double Ad[64][65];
    int r = threadIdx.x;
    for (int idx = r; idx < 64*64; idx += 64)
        Ad[idx>>6][idx&63] = A[(long)(p0+(idx>>6))*d + p0+(idx&63)];
    __syncthreads();
    for (int j = 0; j < 64; ++j) {
        double pj = sqrt(Ad[j][j]);
        double lrj = Ad[r][j] / pj;
        __syncthreads();
        if (r > j) Ad[r][j] = lrj;
        else if (r == j) Ad[j][j] = pj;
        __syncthreads();
        if (r > j)
            for (int k = j+1; k <= r; ++k)
                Ad[r][k] -= lrj * Ad[k][j];
        __syncthreads();
    }
    for (int idx = r; idx < 64*64; idx += 64) {
        int i = idx>>6, c = idx&63;
        A[(long)(p0+i)*d + p0+c] = (c <= i) ? Ad[i][c] : 0.0;
    }
}

__global__ __launch_bounds__(256)
void k_trsm(double* __restrict__ A, int d, int p0) {
    __shared__ double Lp[64][65];
    __shared__ double dg[64];
    int tid = threadIdx.x;
    for (int idx = tid; idx < 64*64; idx += 256) {
        int j = idx>>6, k = idx&63;
        double v = A[(long)(p0+j)*d + p0+k];
        Lp[j][k] = (j > k) ? v : 0.0;
        if (j == k) dg[j] = v;
    }
    __syncthreads();
    int r = p0 + 64 + blockIdx.x*256 + tid;
    if (r >= d) return;
    double* Ar = &A[(long)r*d + p0];
    double v[64];
    #pragma unroll
    for (int j = 0; j < 64; ++j) v[j] = Ar[j];
    #pragma unroll
    for (int k = 0; k < 64; ++k) {
        double lr = v[k] / dg[k];
        Ar[k] = lr;
        #pragma unroll
        for (int j = 0; j < 64; ++j) v[j] -= lr * Lp[j][k];
    }
}

__global__ __launch_bounds__(256)
void k_syrk(double* __restrict__ A, int d, int p0) {
    int t0 = p0 + 64;
    int r0 = t0 + blockIdx.y*64, c0 = t0 + blockIdx.x*64;
    __shared__ double Lr[64][33], Lc[64][33];
    int tid = threadIdx.x, tx = tid&15, ty = tid>>4;
    double acc[16];
    #pragma unroll
    for (int i=0;i<16;++i) acc[i]=0.0;
    for (int kc = 0; kc < 64; kc += 32) {
        for (int idx = tid; idx < 64*32; idx += 256) {
            int i = idx>>5, k = idx&31;
            Lr[i][k] = A[(long)(r0+i)*d + p0+kc+k];
            Lc[i][k] = A[(long)(c0+i)*d + p0+kc+k];
        }
        __syncthreads();
        for (int k = 0; k < 32; ++k) {
            double a[4], b[4];
            #pragma unroll
            for (int i=0;i<4;++i){ a[i]=Lr[ty*4+i][k]; b[i]=Lc[tx*4+i][k]; }
            #pragma unroll
            for (int i=0;i<4;++i)
                #pragma unroll
                for (int j=0;j<4;++j) acc[i*4+j] += a[i]*b[j];
        }
        __syncthreads();
    }
    #pragma unroll
    for (int i=0;i<4;++i)
        #pragma unroll
        for (int j=0;j<4;++j)
            A[(long)(r0+ty*4+i)*d + (c0+tx*4+j)] -= acc[i*4+j];
}

// ---------------------------------------------------------------------------
__global__ __launch_bounds__(64)
void k_dinv(const double* __restrict__ A, double* __restrict__ X, int d) {
    __shared__ double Lb[64][65];
    __shared__ double Yb[64][65];
    int b = blockIdx.x, c = threadIdx.x;
    for (int r = 0; r < 64; ++r) Lb[r][c] = A[(long)(b*64+r)*d + b*64+c];
    for (int r = 0; r < 64; ++r) Yb[r][c] = 0.0;
    __syncthreads();
    for (int i = 0; i < 64; ++i) {
        double s = (i==c) ? 1.0 : 0.0;
        for (int k = 0; k < i; ++k) s -= Lb[i][k]*Yb[k][c];
        Yb[i][c] = s / Lb[i][i];
    }
    __syncthreads();
    for (int r = 0; r < 64; ++r) X[(long)(b*64+r)*d + b*64+c] = Yb[r][c];
}

// X_{ij} = -X_{ii} * sum_{k=j}^{i-1} L_{ik} X_{kj},  i = j + lev.
__global__ __launch_bounds__(256)
void k_xoff(const double* __restrict__ A, double* __restrict__ X, int d, int lev) {
    __shared__ double Lb[64][65];
    __shared__ double Xb[64][65];
    __shared__ double Sb[64][65];
    int j = blockIdx.x, i = j + lev;
    int tid = threadIdx.x, tx = tid&15, ty = tid>>4;
    double acc[4][4];
    #pragma unroll
    for (int m=0;m<4;++m)
        #pragma unroll
        for (int n=0;n<4;++n) acc[m][n]=0.0;
    for (int k = j; k < i; ++k) {
        __syncthreads();
        for (int idx = tid; idx < 64*64; idx += 256) {
            int r = idx>>6, cc = idx&63;
            Lb[r][cc] = A[(long)(i*64+r)*d + k*64+cc];
            Xb[r][cc] = X[(long)(k*64+r)*d + j*64+cc];
        }
        __syncthreads();
        for (int kk = 0; kk < 64; ++kk) {
            double a_[4], b_[4];
            #pragma unroll
            for (int m=0;m<4;++m) a_[m] = Lb[ty*4+m][kk];
            #pragma unroll
            for (int n=0;n<4;++n) b_[n] = Xb[kk][tx*4+n];
            #pragma unroll
            for (int m=0;m<4;++m)
                #pragma unroll
                for (int n=0;n<4;++n) acc[m][n] += a_[m]*b_[n];
        }
    }
    __syncthreads();
    #pragma unroll
    for (int m=0;m<4;++m)
        #pragma unroll
        for (int n=0;n<4;++n) Sb[ty*4+m][tx*4+n] = acc[m][n];
    for (int idx = tid; idx < 64*64; idx += 256) {
        int r = idx>>6, cc = idx&63;
        Lb[r][cc] = X[(long)(i*64+r)*d + i*64+cc];   // X_{ii}
    }
    __syncthreads();
    #pragma unroll
    for (int m=0;m<4;++m)
        #pragma unroll
        for (int n=0;n<4;++n) acc[m][n]=0.0;
    for (int kk = 0; kk < 64; ++kk) {
        double a_[4], b_[4];
        #pragma unroll
        for (int m=0;m<4;++m) a_[m] = Lb[ty*4+m][kk];
        #pragma unroll
        for (int n=0;n<4;++n) b_[n] = Sb[kk][tx*4+n];
        #pragma unroll
        for (int m=0;m<4;++m)
            #pragma unroll
            for (int n=0;n<4;++n) acc[m][n] += a_[m]*b_[n];
    }
    #pragma unroll
    for (int m=0;m<4;++m)
        #pragma unroll
        for (int n=0;n<4;++n)
            X[(long)(i*64+ty*4+m)*d + j*64+tx*4+n] = -acc[m][n];
}

// W = X^T with upper-of-X forced to zero.
__global__ __launch_bounds__(256)
void k_wtr(const double* __restrict__ X, double* __restrict__ W, int d, int shift) {
    int idx = blockIdx.x*256 + threadIdx.x;
    int k = idx >> shift, c = idx & (d-1);
    W[idx] = (k <= c) ? X[(long)c*d + k] : 0.0;
}

// Z = H @ W  (f32 in, f64 W, f64 accumulate, f32 out)
__global__ __launch_bounds__(256)
void k_hw(const float* __restrict__ H, const double* __restrict__ W,
          float* __restrict__ Z, int d) {
    __shared__ __align__(16) float Ht[32][68];
    __shared__ double Wt[32][66];
    int tid = threadIdx.x, tx = tid&15, ty = tid>>4;
    int r0 = blockIdx.y*64, c0 = blockIdx.x*64;
    double acc[4][4];
    #pragma unroll
    for (int i=0;i<4;++i)
        #pragma unroll
        for (int j=0;j<4;++j) acc[i][j]=0.0;
    for (int k0 = 0; k0 < d; k0 += 32) {
        {
            int row = tid>>2, koff = (tid&3)*8;
            const float* src = &H[(long)(r0+row)*d + k0+koff];
            float4 v0 = *(const float4*)src, v1 = *(const float4*)(src+4);
            Ht[koff+0][row]=v0.x; Ht[koff+1][row]=v0.y; Ht[koff+2][row]=v0.z; Ht[koff+3][row]=v0.w;
            Ht[koff+4][row]=v1.x; Ht[koff+5][row]=v1.y; Ht[koff+6][row]=v1.z; Ht[koff+7][row]=v1.w;
        }
        {
            int k = tid>>3, coff = (tid&7)*8;
            const double* src = &W[(long)(k0+k)*d + c0+coff];
            #pragma unroll
            for (int q=0;q<8;++q) Wt[k][coff+q] = src[q];
        }
        __syncthreads();
        #pragma unroll
        for (int k = 0; k < 32; ++k) {
            float4 av = *(const float4*)&Ht[k][ty*4];
            double a0=av.x, a1=av.y, a2=av.z, a3=av.w;
            double b[4];
            #pragma unroll
            for (int j=0;j<4;++j) b[j] = Wt[k][tx*4+j];
            #pragma unroll
            for (int j=0;j<4;++j) {
                acc[0][j] += a0*b[j]; acc[1][j] += a1*b[j];
                acc[2][j] += a2*b[j]; acc[3][j] += a3*b[j];
            }
        }
        __syncthreads();
    }
    #pragma unroll
    for (int i=0;i<4;++i)
        #pragma unroll
        for (int j=0;j<4;++j)
            Z[(long)(r0+ty*4+i)*d + c0+tx*4+j] = (float)acc[i][j];
}

__global__ __launch_bounds__(256)
void k_sq(const float* __restrict__ Z, float* __restrict__ sq, int d) {
    int row = blockIdx.x*4 + (threadIdx.x>>6);
    int lane = threadIdx.x&63;
    const float* z = &Z[(long)row*d];
    double s = 0.0;
    for (int c = lane; c < d; c += 64) { float v = z[c]; s += (double)v*v; }
    #pragma unroll
    for (int off=32; off>0; off>>=1) s += __shfl_down(s, off);
    if (lane==0) sq[row] = (float)s;
}

// f32 -> bf16 (round-to-nearest), single output
__global__ __launch_bounds__(256)
void k_bf16(const float* __restrict__ Z, unsigned short* __restrict__ Zh, long n) {
    long i = ((long)blockIdx.x*256 + threadIdx.x)*8;
    if (i >= n) return;
    float4 v0 = *(const float4*)&Z[i], v1 = *(const float4*)&Z[i+4];
    float z[8] = {v0.x,v0.y,v0.z,v0.w,v1.x,v1.y,v1.z,v1.w};
    __align__(16) unsigned short h[8];
    #pragma unroll
    for (int j=0;j<8;++j) h[j] = f2bf(z[j]);
    *(uint4*)&Zh[i] = *(const uint4*)h;
}

// f32 -> bf16 h + l split (linear layout)
__global__ __launch_bounds__(256)
void k_split(const float* __restrict__ in, unsigned short* __restrict__ ho,
             unsigned short* __restrict__ lo, long n) {
    long i = ((long)blockIdx.x*256 + threadIdx.x)*8;
    if (i >= n) return;
    float4 v0 = *(const float4*)&in[i], v1 = *(const float4*)&in[i+4];
    float z[8] = {v0.x,v0.y,v0.z,v0.w,v1.x,v1.y,v1.z,v1.w};
    __align__(16) unsigned short h[8], l[8];
    #pragma unroll
    for (int j=0;j<8;++j) {
        h[j] = f2bf(z[j]);
        l[j] = f2bf(z[j] - bf2f(h[j]));
    }
    *(uint4*)&ho[i] = *(const uint4*)h;
    *(uint4*)&lo[i] = *(const uint4*)l;
}

// ---------------------------------------------------------------------------
// d2 panel GEMM: d2[r - prow0][c] = sq_r + sq_c - 2*(Zh_r . Zh_c), bf16 MFMA.
__global__ __launch_bounds__(256)
void k_gram(const unsigned short* __restrict__ Zh, const float* __restrict__ sq,
            float* __restrict__ d2, int d, int prow0) {
    __shared__ unsigned short At[128*64], Bt[128*64];
    int tid = threadIdx.x, w = tid>>6, lane = tid&63;
    int lr = lane&15, kg = lane>>4;
    int wr = w>>1, wc = w&1;
    int r0 = prow0 + blockIdx.y*128;
    int c0 = blockIdx.x*128;
    f32x4 acc[4][4];
    #pragma unroll
    for (int m=0;m<4;++m)
        #pragma unroll
        for (int n=0;n<4;++n) acc[m][n] = (f32x4){0.f,0.f,0.f,0.f};

    for (int k0 = 0; k0 < d; k0 += 64) {
        __syncthreads();
        #pragma unroll
        for (int ii=0; ii<4; ++ii) {
            int rbase = w*32 + ii*8;
            int grow = rbase + (lane>>3);
            int gg = (lane&7) ^ (grow&7);
            __builtin_amdgcn_global_load_lds((const void*)&Zh[(long)(r0+grow)*d + k0 + gg*8],
                                             (void*)&At[rbase*64], 16, 0, 0);
            __builtin_amdgcn_global_load_lds((const void*)&Zh[(long)(c0+grow)*d + k0 + gg*8],
                                             (void*)&Bt[rbase*64], 16, 0, 0);
        }
        __syncthreads();
        #pragma unroll
        for (int ks=0; ks<2; ++ks) {
            int gsw = ((ks<<2)|kg) ^ (lr&7);
            bf16x8 a_[4];
            #pragma unroll
            for (int m=0;m<4;++m) a_[m] = *(const bf16x8*)&At[(wr*64+m*16+lr)*64 + gsw*8];
            #pragma unroll
            for (int n=0;n<4;++n) {
                bf16x8 b_ = *(const bf16x8*)&Bt[(wc*64+n*16+lr)*64 + gsw*8];
                #pragma unroll
                for (int m=0;m<4;++m)
                    acc[m][n] = __builtin_amdgcn_mfma_f32_16x16x32_bf16(a_[m], b_, acc[m][n], 0,0,0);
            }
        }
    }
    float sr[4][4];
    #pragma unroll
    for (int m=0;m<4;++m)
        #pragma unroll
        for (int q=0;q<4;++q) sr[m][q] = sq[r0 + wr*64 + m*16 + kg*4 + q];
    #pragma unroll
    for (int n=0;n<4;++n) {
        int col = c0 + wc*64 + n*16 + lr;
        float sc = sq[col];
        #pragma unroll
        for (int m=0;m<4;++m) {
            int rloc = (r0 - prow0) + wr*64 + m*16 + kg*4;
            #pragma unroll
            for (int q=0;q<4;++q)
                d2[(long)(rloc+q)*N_TOT + col] = sr[m][q] + sc - 2.f*acc[m][n][q];
        }
    }
}

// Per-row exact top-32: per-wave zero-barrier radix select (shfl-only),
// then wave-0 REGISTER merge (radix + prefix-sum writes, no serial sort).
__global__ __launch_bounds__(512)
void k_sel(const float* __restrict__ d2, int* __restrict__ tI32, int prow0) {
    __shared__ int   wcnt[8];
    __shared__ float cbv[8][96];   // monotone-uint bits stored as float
    __shared__ int   cbi[8][96];
    __shared__ int   tieIdx[64];
    int tid = threadIdx.x, w = tid>>6, lane = tid&63;
    int row = blockIdx.x;
    const float* rp = &d2[(long)row*N_TOT];
    unsigned u[16];
    #pragma unroll
    for (int j=0;j<4;++j) {
        float4 q = *(const float4*)&rp[j*2048 + tid*4];
        float z[4] = {q.x, q.y, q.z, q.w};
        #pragma unroll
        for (int e=0;e<4;++e) {
            unsigned b = __float_as_uint(z[e]);
            u[j*4+e] = (b & 0x80000000u) ? ~b : (b | 0x80000000u);
        }
    }
    if (lane == 0) wcnt[w] = 0;
    unsigned p = 0;
    for (int b = 31; b >= 0; --b) {
        unsigned t = p | (1u<<b);
        int c = 0;
        #pragma unroll
        for (int i=0;i<16;++i) c += (u[i] < t) ? 1 : 0;
        #pragma unroll
        for (int off=32; off>0; off>>=1) c += __shfl_xor(c, off);
        if (c < 32) p = t;
    }
    #pragma unroll
    for (int i=0;i<16;++i) {
        if (u[i] <= p) {
            int pos = atomicAdd(&wcnt[w], 1);
            if (pos < 96) {
                cbv[w][pos] = __uint_as_float(u[i]);
                cbi[w][pos] = (i>>2)*2048 + tid*4 + (i&3);
            }
        }
    }
    __syncthreads();
    if (w == 0) {
        int wb[9];
        wb[0] = 0;
        #pragma unroll
        for (int ww=0; ww<8; ++ww) {
            int c = wcnt[ww]; if (c > 96) c = 96;
            wb[ww+1] = wb[ww] + c;
        }
        int Mtot = wb[8];
        unsigned mu[12]; int mi[12];
        #pragma unroll
        for (int j=0;j<12;++j) {
            int cidx = lane + j*64;
            unsigned val = 0xFFFFFFFFu; int idx = 0x7fffffff;
            if (cidx < Mtot) {
                int ww = 0;
                #pragma unroll
                for (int q=1;q<8;++q) if (cidx >= wb[q]) ww = q;
                int off = cidx - wb[ww];
                val = __float_as_uint(cbv[ww][off]);
                idx = cbi[ww][off];
            }
            mu[j] = val; mi[j] = idx;
        }
        unsigned p32 = 0;
        for (int b = 31; b >= 0; --b) {
            unsigned t = p32 | (1u<<b);
            int c = 0;
            #pragma unroll
            for (int j=0;j<12;++j) c += (mu[j] < t) ? 1 : 0;
            #pragma unroll
            for (int off=32; off>0; off>>=1) c += __shfl_xor(c, off);
            if (c < 32) p32 = t;
        }
        long rg = (long)(prow0 + row);
        int myA = 0, myT = 0;
        #pragma unroll
        for (int j=0;j<12;++j) {
            myA += (mu[j] < p32) ? 1 : 0;
            myT += (mu[j] == p32) ? 1 : 0;
        }
        int incA = myA;
        #pragma unroll
        for (int off=1; off<64; off<<=1) {
            int t = __shfl_up(incA, off);
            if (lane >= off) incA += t;
        }
        int preA = incA - myA;
        int m1 = __shfl(incA, 63);
        int incT = myT;
        #pragma unroll
        for (int off=1; off<64; off<<=1) {
            int t = __shfl_up(incT, off);
            if (lane >= off) incT += t;
        }
        int preT = incT - myT;
        int tn = __shfl(incT, 63); if (tn > 64) tn = 64;
        int ka = 0, kt = 0;
        #pragma unroll
        for (int j=0;j<12;++j) {
            if (mu[j] < p32) {
                tI32[rg*32 + preA + ka] = mi[j]; ++ka;
            } else if (mu[j] == p32) {
                if (preT + kt < 64) tieIdx[preT + kt] = mi[j];
                ++kt;
            }
        }
        __builtin_amdgcn_wave_barrier();
        if (lane == 0) {
            int need = 32 - m1;
            for (int s = 0; s < need; ++s) {
                int best = 0x7fffffff, bj = -1;
                for (int t = 0; t < tn; ++t) {
                    int v = tieIdx[t];
                    if (v < best) { best = v; bj = t; }
                }
                tI32[rg*32 + m1 + s] = best;
                if (bj >= 0) tieIdx[bj] = 0x7fffffff;
            }
        }
    }
}

// Phase 2: exact f32 d2 for the 32 global candidates; exact top-16 (no sigma
// atomic — sigma reduced separately from tD).
template<int D>
__global__ __launch_bounds__(256)
void k_refine(const float* __restrict__ Z, const float* __restrict__ sq,
              const int* __restrict__ tI32,
              float* __restrict__ tD, int* __restrict__ tI) {
    __shared__ float rD[32];
    __shared__ int   rI[32];
    __shared__ float bD[17];
    __shared__ int   bI[17];
    int wv = threadIdx.x>>6, lane = threadIdx.x&63;
    long row = blockIdx.x;
    float zi[D/64];
    #pragma unroll
    for (int t=0;t<D/64;++t) zi[t] = Z[row*D + t*64 + lane];
    float sqi = sq[row];
    #pragma unroll
    for (int cg = 0; cg < 8; cg += 4) {
        int cbase = wv*8 + cg;
        int j0 = tI32[row*32 + cbase + 0];
        int j1 = tI32[row*32 + cbase + 1];
        int j2 = tI32[row*32 + cbase + 2];
        int j3 = tI32[row*32 + cbase + 3];
        float d0 = 0.f, d1 = 0.f, d2v = 0.f, d3 = 0.f;
        #pragma unroll
        for (int t=0;t<D/64;++t) {
            d0  = fmaf(zi[t], Z[(long)j0*D + t*64 + lane], d0);
            d1  = fmaf(zi[t], Z[(long)j1*D + t*64 + lane], d1);
            d2v = fmaf(zi[t], Z[(long)j2*D + t*64 + lane], d2v);
            d3  = fmaf(zi[t], Z[(long)j3*D + t*64 + lane], d3);
        }
        #pragma unroll
        for (int off=32; off>0; off>>=1) {
            d0  += __shfl_xor(d0, off);
            d1  += __shfl_xor(d1, off);
            d2v += __shfl_xor(d2v, off);
            d3  += __shfl_xor(d3, off);
        }
        if (lane == 0) {
            rD[cbase+0] = sqi + sq[j0] - 2.f*d0;  rI[cbase+0] = j0;
            rD[cbase+1] = sqi + sq[j1] - 2.f*d1;  rI[cbase+1] = j1;
            rD[cbase+2] = sqi + sq[j2] - 2.f*d2v; rI[cbase+2] = j2;
            rD[cbase+3] = sqi + sq[j3] - 2.f*d3;  rI[cbase+3] = j3;
        }
    }
    __syncthreads();
    if (threadIdx.x == 0) {
        #pragma unroll
        for (int k=0;k<16;++k){ bD[k]=FLT_MAX; bI[k]=0x7fffffff; }
        for (int c = 0; c < 32; ++c) {
            float dv = rD[c]; int ci = rI[c];
            float wd = bD[15]; int wi = bI[15];
            if (dv < wd || (dv == wd && ci < wi)) {
                int pos = 15;
                while (pos > 0) {
                    float pd_ = bD[pos-1]; int pi_ = bI[pos-1];
                    if (dv < pd_ || (dv == pd_ && ci < pi_)) {
                        bD[pos]=pd_; bI[pos]=pi_; --pos;
                    } else break;
                }
                bD[pos]=dv; bI[pos]=ci;
            }
        }
        #pragma unroll
        for (int k=0;k<16;++k) {
            tD[row*16+k] = bD[k]; tI[row*16+k] = bI[k];
        }
    }
}

// deterministic sigma reduction: sigpart[b] = sum_{e in block} sqrt(max(tD,0))
__global__ __launch_bounds__(256)
void k_sigred(const float* __restrict__ tD, double* __restrict__ sigpart) {
    __shared__ double wsum[4];
    int tid = threadIdx.x, w = tid>>6, lane = tid&63;
    int idx = blockIdx.x*256 + tid;
    double s = sqrt((double)fmaxf(tD[idx], 0.f));
    #pragma unroll
    for (int off=32; off>0; off>>=1) s += __shfl_xor(s, off);
    if (lane == 0) wsum[w] = s;
    __syncthreads();
    if (tid == 0)
        sigpart[blockIdx.x] = ((wsum[0]+wsum[1])+(wsum[2]+wsum[3]));
}

__global__ void k_sigfin(const double* __restrict__ sigpart, float* __restrict__ inv2s2) {
    double acc = 0.0;
    for (int b = 0; b < (N_TOT*KNB)/256; ++b) acc += sigpart[b];
    double s = acc / (double)(N_TOT*KNB);
    inv2s2[0] = (float)(1.0/(2.0*s*s));
}

__global__ __launch_bounds__(256)
void k_kern(const float* __restrict__ tD, const int* __restrict__ tI,
            const float* __restrict__ inv2s2,
            float* __restrict__ kern, float* __restrict__ deg) {
    int e = blockIdx.x*256 + threadIdx.x;
    int i = e>>4;
    float d2 = fmaxf(tD[e], 0.f);
    float kv = expf(-d2 * inv2s2[0]);
    kern[e] = kv;
    atomicAdd(&deg[i], 0.5f*kv);
    atomicAdd(&deg[tI[e]], 0.5f*kv);
}

__global__ __launch_bounds__(256)
void k_dis(const float* __restrict__ deg, float* __restrict__ dis) {
    int i = blockIdx.x*256 + threadIdx.x;
    float v = deg[i];
    dis[i] = (v > 0.f) ? (1.0f/sqrtf(v)) : 0.f;
}

// wout[e] = 0.5 * kern[e] * dis[tI[e]]
__global__ __launch_bounds__(256)
void k_wedge(const float* __restrict__ kern, const int* __restrict__ tI,
             const float* __restrict__ dis, float* __restrict__ wout) {
    int e = blockIdx.x*256 + threadIdx.x;
    wout[e] = 0.5f * kern[e] * dis[tI[e]];
}

__global__ __launch_bounds__(256)
void k_count(const int* __restrict__ tI, int* __restrict__ cnt) {
    int e = blockIdx.x*256 + threadIdx.x;
    atomicAdd(&cnt[tI[e]], 1);
}

__global__ __launch_bounds__(1024)
void k_scan(const int* __restrict__ cnt, int* __restrict__ rowstart) {
    __shared__ int buf[1024];
    __shared__ int carry;
    int tid = threadIdx.x;
    if (tid==0) carry = 0;
    __syncthreads();
    for (int base = 0; base < N_TOT; base += 1024) {
        int v = cnt[base+tid];
        buf[tid]=v; __syncthreads();
        for (int off=1; off<1024; off<<=1) {
            int t = (tid>=off)? buf[tid-off] : 0; __syncthreads();
            buf[tid]+=t; __syncthreads();
        }
        rowstart[base+tid] = carry + buf[tid] - v;
        __syncthreads();
        if (tid==1023) carry += buf[1023];
        __syncthreads();
    }
    if (tid==0) rowstart[N_TOT] = carry;
}

// in-edge weights premultiplied: in_w[dst] = 0.5*kern[e]*dis[src_row]
__global__ __launch_bounds__(256)
void k_fill(const int* __restrict__ tI, const float* __restrict__ kern,
            const float* __restrict__ dis,
            const int* __restrict__ rowstart, int* __restrict__ c2,
            int* __restrict__ in_src, float* __restrict__ in_w) {
    int e = blockIdx.x*256 + threadIdx.x;
    int i = e>>4;
    int j = tI[e];
    int pos = atomicAdd(&c2[j], 1);
    int dst = rowstart[j] + pos;
    in_src[dst] = i; in_w[dst] = 0.5f*kern[e]*dis[i];
}

// src[rows up to 8192][256] f32 -> Th/Tl [256][outStride] bf16 split,
// transposed AND pre-swizzled within each 64-chunk of the out row.
__global__ __launch_bounds__(256)
void k_prepT(const float* __restrict__ S, unsigned short* __restrict__ Th,
             unsigned short* __restrict__ Tl, int outStride) {
    __shared__ float tile[64][65];
    int r0 = blockIdx.y*64;   // S rows (k-dim), 64-aligned chunk
    int c0 = blockIdx.x*64;   // S cols
    int t = threadIdx.x;
    {
        int row = t>>2, cseg = t&3;
        #pragma unroll
        for (int i=0;i<4;++i) {
            float4 v = *(const float4*)&S[(long)(r0+row)*256 + c0 + cseg*16 + i*4];
            tile[row][cseg*16+i*4+0]=v.x; tile[row][cseg*16+i*4+1]=v.y;
            tile[row][cseg*16+i*4+2]=v.z; tile[row][cseg*16+i*4+3]=v.w;
        }
    }
    __syncthreads();
    {
        int col = t>>2, rseg = t&3;
        int c = c0 + col;
        __align__(16) unsigned short hs[16], ls[16];
        #pragma unroll
        for (int i=0;i<16;++i) {
            float z = tile[rseg*16+i][col];
            hs[i] = f2bf(z);
            ls[i] = f2bf(z - bf2f(hs[i]));
        }
        #pragma unroll
        for (int half=0; half<2; ++half) {
            int gl = rseg*2 + half;
            int gs = gl ^ (c&7);
            long dst = (long)c*outStride + r0 + gs*8;
            *(uint4*)&Th[dst] = *(const uint4*)&hs[half*8];
            *(uint4*)&Tl[dst] = *(const uint4*)&ls[half*8];
        }
    }
}

// P = H @ Bmat via split-bf16 MFMA. A = Hh/Hl [8192][d] linear (source-XOR
// staged); B = BTh/BTl [256][d] pre-swizzled. grid (2, 64), 4 waves.
__global__ __launch_bounds__(256)
void k_hb(const unsigned short* __restrict__ Hh, const unsigned short* __restrict__ Hl,
          const unsigned short* __restrict__ BTh, const unsigned short* __restrict__ BTl,
          float* __restrict__ C, int d) {
    __shared__ unsigned short Ah[128*64], Al[128*64], Bh[128*64], Bl[128*64];
    int tid = threadIdx.x, w = tid>>6, lane = tid&63;
    int lr = lane&15, kg = lane>>4;
    int wr = w>>1, wc = w&1;
    int r0 = blockIdx.y*128;
    int c0 = blockIdx.x*128;
    f32x4 acc[4][4];
    #pragma unroll
    for (int m=0;m<4;++m)
        #pragma unroll
        for (int n=0;n<4;++n) acc[m][n] = (f32x4){0.f,0.f,0.f,0.f};

    for (int k0 = 0; k0 < d; k0 += 64) {
        __syncthreads();
        #pragma unroll
        for (int ii=0; ii<4; ++ii) {
            int rbase = w*32 + ii*8;
            int grow = rbase + (lane>>3);
            int gg = (lane&7) ^ (grow&7);
            long asrc = (long)(r0+grow)*d + k0 + gg*8;
            __builtin_amdgcn_global_load_lds((const void*)&Hh[asrc], (void*)&Ah[rbase*64], 16, 0, 0);
            __builtin_amdgcn_global_load_lds((const void*)&Hl[asrc], (void*)&Al[rbase*64], 16, 0, 0);
            long bsrc = (long)(c0+grow)*d + k0 + (lane&7)*8;
            __builtin_amdgcn_global_load_lds((const void*)&BTh[bsrc], (void*)&Bh[rbase*64], 16, 0, 0);
            __builtin_amdgcn_global_load_lds((const void*)&BTl[bsrc], (void*)&Bl[rbase*64], 16, 0, 0);
        }
        __syncthreads();
        #pragma unroll
        for (int ks=0; ks<2; ++ks) {
            int gsw = ((ks<<2)|kg) ^ (lr&7);
            bf16x8 ah[4], al[4];
            #pragma unroll
            for (int m=0;m<4;++m) {
                ah[m] = *(const bf16x8*)&Ah[(wr*64+m*16+lr)*64 + gsw*8];
                al[m] = *(const bf16x8*)&Al[(wr*64+m*16+lr)*64 + gsw*8];
            }
            #pragma unroll
            for (int n=0;n<4;++n) {
                bf16x8 bh = *(const bf16x8*)&Bh[(wc*64+n*16+lr)*64 + gsw*8];
                bf16x8 bl = *(const bf16x8*)&Bl[(wc*64+n*16+lr)*64 + gsw*8];
                #pragma unroll
                for (int m=0;m<4;++m) {
                    acc[m][n] = __builtin_amdgcn_mfma_f32_16x16x32_bf16(ah[m], bh, acc[m][n], 0,0,0);
                    acc[m][n] = __builtin_amdgcn_mfma_f32_16x16x32_bf16(ah[m], bl, acc[m][n], 0,0,0);
                    acc[m][n] = __builtin_amdgcn_mfma_f32_16x16x32_bf16(al[m], bh, acc[m][n], 0,0,0);
                }
            }
        }
    }
    #pragma unroll
    for (int n=0;n<4;++n) {
        int col = c0 + wc*64 + n*16 + lr;
        #pragma unroll
        for (int m=0;m<4;++m) {
            int rg = r0 + wr*64 + m*16 + kg*4;
            #pragma unroll
            for (int q=0;q<4;++q)
                C[(long)(rg+q)*256 + col] = acc[m][n][q];
        }
    }
}

// part[ks] = adj[:, slab] @ P[slab, :]  (split-bf16 MFMA, K-split, T14
// reg-prefetch of adj). grid (2, 128, KS), block 256 (4 waves x 16 rows).
__global__ __launch_bounds__(256)
void k_adjP3(const float* __restrict__ adj, const unsigned short* __restrict__ PTsh,
             const unsigned short* __restrict__ PTsl, float* __restrict__ part) {
    __shared__ unsigned short Ah[64*64], Al[64*64];
    __shared__ unsigned short Bh[128*64], Bl[128*64];
    int tid = threadIdx.x, w = tid>>6, lane = tid&63;
    int lr = lane&15, kg = lane>>4;
    int r0 = blockIdx.y*64;
    int c0 = blockIdx.x*128;
    int kbeg = blockIdx.z*(N_TOT/KS), kend = kbeg + N_TOT/KS;
    f32x4 acc[8];
    #pragma unroll
    for (int fc=0; fc<8; ++fc) acc[fc] = (f32x4){0.f,0.f,0.f,0.f};

    int arow = tid>>2, aseg = tid&3;
    float4 va[4];
    {
        const float* asrc = &adj[(long)(r0+arow)*N_TOT + kbeg + aseg*16];
        #pragma unroll
        for (int i=0;i<4;++i) va[i] = *(const float4*)&asrc[i*4];
    }
    for (int k0 = kbeg; k0 < kend; k0 += 64) {
        __syncthreads();
        #pragma unroll
        for (int i=0;i<4;++i) {
            float z[4] = {va[i].x, va[i].y, va[i].z, va[i].w};
            __align__(8) unsigned short h[4], l[4];
            #pragma unroll
            for (int j=0;j<4;++j) {
                h[j] = f2bf(z[j]);
                l[j] = f2bf(z[j] - bf2f(h[j]));
            }
            int col = aseg*16 + i*4;
            int g = col>>3, sub = col&7;
            int off = arow*128 + ((g ^ (arow&7))*16) + sub*2;
            *(ushort4*)((char*)Ah + off) = *(const ushort4*)h;
            *(ushort4*)((char*)Al + off) = *(const ushort4*)l;
        }
        #pragma unroll
        for (int ii=0; ii<4; ++ii) {
            int rbase = w*32 + ii*8;
            int grow = rbase + (lane>>3);
            long src = (long)(c0+grow)*N_TOT + k0 + (lane&7)*8;
            __builtin_amdgcn_global_load_lds((const void*)&PTsh[src], (void*)&Bh[rbase*64], 16, 0, 0);
            __builtin_amdgcn_global_load_lds((const void*)&PTsl[src], (void*)&Bl[rbase*64], 16, 0, 0);
        }
        __syncthreads();
        if (k0 + 64 < kend) {
            const float* asrc = &adj[(long)(r0+arow)*N_TOT + k0 + 64 + aseg*16];
            #pragma unroll
            for (int i=0;i<4;++i) va[i] = *(const float4*)&asrc[i*4];
        }
        #pragma unroll
        for (int ks=0; ks<2; ++ks) {
            int gsw = ((ks<<2)|kg) ^ (lr&7);
            bf16x8 ah = *(const bf16x8*)&Ah[(w*16+lr)*64 + gsw*8];
            bf16x8 al = *(const bf16x8*)&Al[(w*16+lr)*64 + gsw*8];
            #pragma unroll
            for (int fc=0; fc<8; ++fc) {
                bf16x8 bh = *(const bf16x8*)&Bh[(fc*16+lr)*64 + gsw*8];
                bf16x8 bl = *(const bf16x8*)&Bl[(fc*16+lr)*64 + gsw*8];
                acc[fc] = __builtin_amdgcn_mfma_f32_16x16x32_bf16(ah, bh, acc[fc], 0,0,0);
                acc[fc] = __builtin_amdgcn_mfma_f32_16x16x32_bf16(ah, bl, acc[fc], 0,0,0);
                acc[fc] = __builtin_amdgcn_mfma_f32_16x16x32_bf16(al, bh, acc[fc], 0,0,0);
            }
        }
    }
    long base = (long)blockIdx.z*N_TOT*256;
    #pragma unroll
    for (int fc=0; fc<8; ++fc)
        #pragma unroll
        for (int q=0; q<4; ++q) {
            int rg = r0 + w*16 + kg*4 + q;
            int cg = c0 + fc*16 + lr;
            part[base + (long)rg*256 + cg] = acc[fc][q];
        }
}

// preS = scale * sum_ks part[ks]  (deterministic order)
__global__ __launch_bounds__(256)
void k_adjred(const float* __restrict__ part, float* __restrict__ preS, float scale) {
    long i4 = ((long)blockIdx.x*256 + threadIdx.x)*4;
    long n = (long)N_TOT*256;
    float sx=0.f, sy=0.f, sz=0.f, sw=0.f;
    for (int ch = 0; ch < KS; ++ch) {
        float4 a = *(const float4*)&part[(long)ch*n + i4];
        sx += a.x; sy += a.y; sz += a.z; sw += a.w;
    }
    float4 o; o.x = scale*sx; o.y = scale*sy; o.z = scale*sz; o.w = scale*sw;
    *(float4*)&preS[i4] = o;
}

__global__ __launch_bounds__(256)
void k_wsym(const float* __restrict__ w2, float* __restrict__ w2s) {
    int i = blockIdx.x, j = threadIdx.x;
    w2s[i*256+j] = 0.5f*(w2[i*256+j] + w2[j*256+i]);
}

// out[i][c] = tanh(preS + dis_i * (sum_out + sum_in)); 4-way ILP gather.
__global__ __launch_bounds__(256)
void k_spmm_tanh(const float* __restrict__ P, const float* __restrict__ preS,
                 const float* __restrict__ wout, const int* __restrict__ tI,
                 const float* __restrict__ dis, const int* __restrict__ rowstart,
                 const int* __restrict__ in_src, const float* __restrict__ in_w,
                 float* __restrict__ out) {
    int i = blockIdx.x, c = threadIdx.x;
    float a0=0.f, a1=0.f, a2=0.f, a3=0.f;
    #pragma unroll
    for (int k = 0; k < 16; k += 4) {
        int e = i*16+k;
        int j0 = tI[e+0], j1 = tI[e+1], j2 = tI[e+2], j3 = tI[e+3];
        float w0 = wout[e+0], w1 = wout[e+1], w2 = wout[e+2], w3 = wout[e+3];
        a0 = fmaf(w0, P[(long)j0*256 + c], a0);
        a1 = fmaf(w1, P[(long)j1*256 + c], a1);
        a2 = fmaf(w2, P[(long)j2*256 + c], a2);
        a3 = fmaf(w3, P[(long)j3*256 + c], a3);
    }
    int s0 = rowstart[i], s1 = rowstart[i+1];
    int t = s0;
    for (; t + 4 <= s1; t += 4) {
        int j0 = in_src[t+0], j1 = in_src[t+1], j2 = in_src[t+2], j3 = in_src[t+3];
        float w0 = in_w[t+0], w1 = in_w[t+1], w2 = in_w[t+2], w3 = in_w[t+3];
        a0 = fmaf(w0, P[(long)j0*256 + c], a0);
        a1 = fmaf(w1, P[(long)j1*256 + c], a1);
        a2 = fmaf(w2, P[(long)j2*256 + c], a2);
        a3 = fmaf(w3, P[(long)j3*256 + c], a3);
    }
    for (; t < s1; ++t)
        a0 = fmaf(in_w[t], P[(long)in_src[t]*256 + c], a0);
    float acc = (a0 + a1) + (a2 + a3);
    float pre = preS[(long)i*256+c] + dis[i]*acc;
    out[(long)i*256+c] = tanhf(pre);
}

// ---------------------------------------------------------------------------
extern "C" void kernel_launch(void* const* d_in, const int* in_sizes, int n_in,
                              void* d_out, int out_size, void* d_ws, size_t ws_size,
                              hipStream_t stream) {
    const float* x   = (const float*)d_in[0];
    const float* adj = (const float*)d_in[1];
    const float* w1  = (const float*)d_in[2];
    const float* w2  = (const float*)d_in[3];

    char* ws = (char*)d_ws;
    size_t off = 0;
    auto alloc = [&](size_t bytes){ size_t o = off; off += (bytes+255)&~(size_t)255; return o; };
    double* A      = (double*)(ws + alloc((size_t)512*512*8));
    double* W      = (double*)(ws + alloc((size_t)512*512*8));
    double* Xb     = (double*)(ws + alloc((size_t)512*512*8));
    double* Apart  = (double*)(ws + alloc((size_t)NCH*512*512*8));
    double* sigpart= (double*)(ws + alloc((size_t)((N_TOT*KNB)/256)*8));
    float*  inv2s2 = (float*)(ws + alloc(256));
    float*  bigZ   = (float*)(ws + alloc((size_t)N_TOT*512*4));  // Z, then P/preS
    unsigned short* Zh   = (unsigned short*)(ws + alloc((size_t)N_TOT*512*2));
    unsigned short* Hh   = (unsigned short*)(ws + alloc((size_t)N_TOT*512*2));
    unsigned short* Hl   = (unsigned short*)(ws + alloc((size_t)N_TOT*512*2));
    unsigned short* BTh  = (unsigned short*)(ws + alloc((size_t)256*512*2));
    unsigned short* BTl  = (unsigned short*)(ws + alloc((size_t)256*512*2));
    unsigned short* PTsh = (unsigned short*)(ws + alloc((size_t)256*N_TOT*2));
    unsigned short* PTsl = (unsigned short*)(ws + alloc((size_t)256*N_TOT*2));
    float*  d2buf  = (float*)(ws + alloc((size_t)PROWS*N_TOT*4));   // 64 MB panel
    float*  part   = (float*)(ws + alloc((size_t)KS*N_TOT*256*4));  // 64 MB
    float*  sq     = (float*)(ws + alloc((size_t)N_TOT*4));
    int*    tI32   = (int*)  (ws + alloc((size_t)N_TOT*32*4));
    float*  tD     = (float*)(ws + alloc((size_t)N_TOT*16*4));
    int*    tI     = (int*)  (ws + alloc((size_t)N_TOT*16*4));
    float*  kern   = (float*)(ws + alloc((size_t)N_TOT*16*4));
    float*  wout   = (float*)(ws + alloc((size_t)N_TOT*16*4));
    float*  deg    = (float*)(ws + alloc((size_t)N_TOT*4));
    float*  dis    = (float*)(ws + alloc((size_t)N_TOT*4));
    int*    cnt    = (int*)  (ws + alloc((size_t)N_TOT*4));
    int*    rowstart=(int*)  (ws + alloc((size_t)(N_TOT+1)*4));
    int*    c2     = (int*)  (ws + alloc((size_t)N_TOT*4));
    int*    in_src = (int*)  (ws + alloc((size_t)N_TOT*16*4));
    float*  in_w   = (float*)(ws + alloc((size_t)N_TOT*16*4));
    float*  out1   = (float*)(ws + alloc((size_t)N_TOT*256*4));
    float*  w2s    = (float*)(ws + alloc((size_t)256*256*4));
    float*  P      = bigZ;                       // overlays Z after Z is dead
    float*  preS   = bigZ + (size_t)N_TOT*256;

    auto run_stage = [&](const float* H, int d, const float* Bmat, float* outBuf) {
        int nb = d/64;
        int shift = (d == 512) ? 9 : 8;
        k_ata2<<<dim3(d/32, d/32, NCH), 256, 0, stream>>>(H, Apart, d);
        k_atared<<<d*d/256, 256, 0, stream>>>(Apart, A, d, 1.0);
        for (int p0 = 0; p0 < d; p0 += 64) {
            k_chol_diag<<<1, 64, 0, stream>>>(A, d, p0);
            int rem = d - p0 - 64;
            if (rem > 0) {
                k_trsm<<<(rem+255)/256, 256, 0, stream>>>(A, d, p0);
                k_syrk<<<dim3(rem/64, rem/64), 256, 0, stream>>>(A, d, p0);
            }
        }
        // X = L^{-1} via blocked inversion; W = X^T
        k_dinv<<<nb, 64, 0, stream>>>(A, Xb, d);
        for (int lev = 1; lev < nb; ++lev)
            k_xoff<<<nb - lev, 256, 0, stream>>>(A, Xb, d, lev);
        k_wtr<<<d*d/256, 256, 0, stream>>>(Xb, W, d, shift);
        k_hw<<<dim3(d/64, N_TOT/64), 256, 0, stream>>>(H, W, bigZ, d);
        k_sq<<<N_TOT/4, 256, 0, stream>>>(bigZ, sq, d);
        k_bf16<<<(int)(((long)N_TOT*d)/(256*8)), 256, 0, stream>>>(bigZ, Zh, (long)N_TOT*d);
        for (int pr = 0; pr < N_TOT; pr += PROWS) {
            k_gram<<<dim3(N_TOT/128, PROWS/128), 256, 0, stream>>>(Zh, sq, d2buf, d, pr);
            k_sel<<<PROWS, 512, 0, stream>>>(d2buf, tI32, pr);
        }
        if (d == 512)
            k_refine<512><<<N_TOT, 256, 0, stream>>>(bigZ, sq, tI32, tD, tI);
        else
            k_refine<256><<<N_TOT, 256, 0, stream>>>(bigZ, sq, tI32, tD, tI);
        k_sigred<<<(N_TOT*KNB)/256, 256, 0, stream>>>(tD, sigpart);
        k_sigfin<<<1, 1, 0, stream>>>(sigpart, inv2s2);
        hipMemsetAsync(deg, 0, N_TOT*4, stream);
        k_kern<<<N_TOT*16/256, 256, 0, stream>>>(tD, tI, inv2s2, kern, deg);
        k_dis<<<N_TOT/256, 256, 0, stream>>>(deg, dis);
        k_wedge<<<N_TOT*16/256, 256, 0, stream>>>(kern, tI, dis, wout);
        hipMemsetAsync(cnt, 0, N_TOT*4, stream);
        k_count<<<N_TOT*16/256, 256, 0, stream>>>(tI, cnt);
        k_scan<<<1, 1024, 0, stream>>>(cnt, rowstart);
        hipMemsetAsync(c2, 0, N_TOT*4, stream);
        k_fill<<<N_TOT*16/256, 256, 0, stream>>>(tI, kern, dis, rowstart, c2, in_src, in_w);
        // P = H @ Bmat via split-bf16 MFMA (Z dead now; P/preS overlay Z)
        k_split<<<(int)(((long)N_TOT*d)/(256*8)), 256, 0, stream>>>(H, Hh, Hl, (long)N_TOT*d);
        k_prepT<<<dim3(4, d/64), 256, 0, stream>>>(Bmat, BTh, BTl, d);
        k_hb<<<dim3(2, N_TOT/128), 256, 0, stream>>>(Hh, Hl, BTh, BTl, P, d);
        // preS = ALPHA * adj @ P via tiled split-bf16 MFMA (K-split + reduce)
        k_prepT<<<dim3(4, N_TOT/64), 256, 0, stream>>>(P, PTsh, PTsl, N_TOT);
        k_adjP3<<<dim3(2, N_TOT/64, KS), 256, 0, stream>>>(adj, PTsh, PTsl, part);
        k_adjred<<<(N_TOT*256)/(256*4), 256, 0, stream>>>(part, preS, ALPHA);
        k_spmm_tanh<<<N_TOT, 256, 0, stream>>>(P, preS, wout, tI, dis, rowstart,
                                               in_src, in_w, outBuf);
    };

    run_stage(x, 512, w1, out1);
    k_wsym<<<256, 256, 0, stream>>>(w2, w2s);
    run_stage(out1, 256, w2s, (float*)d_out);
}